// Round 9
// baseline (5796.202 us; speedup 1.0000x reference)
//
#include <hip/hip_runtime.h>

// ============================================================================
// AFAR: channel-attention -> per-channel truncated-SVD recon -> spatial attn.
// A_k = P*A, P = step(G - t), G = A*A^T. t from mixed-precision Householder
// tridiag + fp64 Sturm multisection. Projector via polar-express schedule;
// late iterations (certified margin l >= 0.02) run as f16 MFMA GEMMs.
// R14: fix R13's numerics bug. Y = ca*X - cb*X*S is NOT bitwise symmetric in
// FP; the passing k_nsh enforced symmetry by computing the lower off-diag
// block and mirroring. k_nsf now reproduces that write policy exactly:
// same-128-block entries -> direct write; gr>=128>gc -> write + mirror;
// upper off-diag -> skipped (wave-uniform 3-way specialization; the 2 waves
// owning upper-off-diag tiles skip their MFMA entirely, -25% compute).
// Output is bitwise-identical to the R12 k_nsh path. Structure otherwise =
// R13: one channel per 512-thread block, X staged once to LDS, S -> f16
// bufC alias, threadfence+syncthreads, Y from S via L2. Tridiag = R12.
// ============================================================================

#define NCH 256
#define N 256
#define NN 65536
#define NS_MAX 22

// small-region float offsets inside d_ws (double regions 8B-aligned)
#define OFF_K 0          // int[256]
#define OFF_MODE 256     // int[256]: 0 -> A_k=0, 1 -> A_k=A, 2 -> project
#define OFF_MC 512       // int[256]
#define OFF_COEF 768     // float[256][2*NS_MAX]
#define OFF_SUM 12032    // float[65536]
#define OFF_MAXHW 77568  // float[65536]
#define OFF_MEAND 143104 // double[256]
#define OFF_MAXD 143616  // double[256]
#define OFF_T 144128     // double[256]
#define OFF_ALPHA 144640 // double[256]
#define OFF_AQ 145152    // double[256][256]
#define OFF_BQ 276224    // double[256][256]
#define OFF_ITSW 407296  // int[256]: first iteration index safe for f16 MFMA
#define SMALL_FLOATS 407552

#define NSF_LDS 135168   // 256 rows x 264 f16 (8-elem pad per row)

static const float EPSF = 2.220446049250313e-16f;

typedef unsigned short u16;
typedef _Float16 h8 __attribute__((ext_vector_type(8)));
typedef float f32x4 __attribute__((ext_vector_type(4)));

__device__ __forceinline__ float rdlane(float v, int l) {
  return __uint_as_float(__builtin_amdgcn_readlane(__float_as_uint(v), l));
}

__device__ __forceinline__ u16 f2h(float v) {
  _Float16 h = (_Float16)v;
  u16 u;
  __builtin_memcpy(&u, &h, 2);
  return u;
}
__device__ __forceinline__ float h2f(u16 u) {
  _Float16 h;
  __builtin_memcpy(&h, &u, 2);
  return (float)h;
}

// ---------------------------------------------------------------------------
// 1) per-channel mean & max over H*W (fp64 sum)
// ---------------------------------------------------------------------------
__global__ __launch_bounds__(256) void k_chan_stats(const float* __restrict__ x,
                                                    float* __restrict__ small) {
  int c = blockIdx.x, tid = threadIdx.x;
  const float4* xc = (const float4*)(x + (size_t)c * NN);
  double s = 0.0;
  float m = -1e30f;
  for (int i = tid; i < NN / 4; i += 256) {
    float4 v = xc[i];
    s += (double)v.x + (double)v.y + (double)v.z + (double)v.w;
    m = fmaxf(m, fmaxf(fmaxf(v.x, v.y), fmaxf(v.z, v.w)));
  }
  __shared__ double rs[4];
  __shared__ float rm[4];
  for (int off = 32; off; off >>= 1) {
    s += __shfl_down(s, off, 64);
    m = fmaxf(m, __shfl_down(m, off, 64));
  }
  if ((tid & 63) == 0) { rs[tid >> 6] = s; rm[tid >> 6] = m; }
  __syncthreads();
  if (tid == 0) {
    ((double*)(small + OFF_MEAND))[c] = (rs[0] + rs[1] + rs[2] + rs[3]) / (double)NN;
    ((double*)(small + OFF_MAXD))[c] =
        (double)fmaxf(fmaxf(rm[0], rm[1]), fmaxf(rm[2], rm[3]));
  }
}

// ---------------------------------------------------------------------------
// 2) shared-MLP channel attention (fp64) -> gates yc -> k_c, mode_c
// ---------------------------------------------------------------------------
__global__ __launch_bounds__(256) void k_attention(const float* __restrict__ w1,
                                                   const float* __restrict__ w2,
                                                   const int* __restrict__ kvp,
                                                   float* __restrict__ small) {
  int tid = threadIdx.x;
  __shared__ double ha[16], hm[16], redd[8], ymn[256], ymx[256];
  double va = ((const double*)(small + OFF_MEAND))[tid];
  double vm = ((const double*)(small + OFF_MAXD))[tid];
  for (int r = 0; r < 16; ++r) {
    double wv = (double)w1[r * 256 + tid];
    double pa = wv * va, pm = wv * vm;
    for (int off = 32; off; off >>= 1) {
      pa += __shfl_down(pa, off, 64);
      pm += __shfl_down(pm, off, 64);
    }
    if ((tid & 63) == 0) { redd[tid >> 6] = pa; redd[4 + (tid >> 6)] = pm; }
    __syncthreads();
    if (tid == 0) {
      ha[r] = fmax(redd[0] + redd[1] + redd[2] + redd[3], 0.0);
      hm[r] = fmax(redd[4] + redd[5] + redd[6] + redd[7], 0.0);
    }
    __syncthreads();
  }
  double ya = 0.0, ym = 0.0;
  for (int r = 0; r < 16; ++r) {
    double wv = (double)w2[tid * 16 + r];
    ya += ha[r] * wv;
    ym += hm[r] * wv;
  }
  double y = 1.0 / (1.0 + exp(-(ya + ym)));
  ymn[tid] = y; ymx[tid] = y;
  __syncthreads();
  for (int off = 128; off; off >>= 1) {
    if (tid < off) {
      ymn[tid] = fmin(ymn[tid], ymn[tid + off]);
      ymx[tid] = fmax(ymx[tid], ymx[tid + off]);
    }
    __syncthreads();
  }
  double yc = (y - ymn[0]) / (ymx[0] - ymn[0] + 1e-20);
  int kv = kvp[0];
  int k = (int)floor(256.0 * (double)kv * yc);
  int mode = (k <= 0) ? 0 : ((k >= 256) ? 1 : 2);
  int* ip = (int*)small;
  ip[OFF_K + tid] = k;
  ip[OFF_MODE + tid] = mode;
}

// ---------------------------------------------------------------------------
// GEMM core: 128x128 tile, 256 threads, 8x8 micro-tile (2x2 quadrants of 4)
// ---------------------------------------------------------------------------
#define GEMM128_VARS                                                           \
  int tid = threadIdx.x;                                                       \
  int tx4 = (tid & 15) * 4, ty4 = (tid >> 4) * 4;                              \
  int lm = tid >> 1, lq = (tid & 1) * 2;                                       \
  int lk = tid >> 4, lc = (tid & 15) * 2;                                      \
  (void)lk; (void)lc;

#define STORE_T128(Ls, v0, v1)                                                 \
  Ls[lq * 4 + 0][lm] = v0.x; Ls[lq * 4 + 1][lm] = v0.y;                        \
  Ls[lq * 4 + 2][lm] = v0.z; Ls[lq * 4 + 3][lm] = v0.w;                        \
  Ls[lq * 4 + 4][lm] = v1.x; Ls[lq * 4 + 5][lm] = v1.y;                        \
  Ls[lq * 4 + 6][lm] = v1.z; Ls[lq * 4 + 7][lm] = v1.w;

#define GEMM128_INNER(AsM, BsM)                                                \
  _Pragma("unroll") for (int kk = 0; kk < 16; ++kk) {                          \
    float4 a0 = *(const float4*)&AsM[kk][ty4];                                 \
    float4 a1 = *(const float4*)&AsM[kk][64 + ty4];                            \
    float4 b0 = *(const float4*)&BsM[kk][tx4];                                 \
    float4 b1 = *(const float4*)&BsM[kk][64 + tx4];                            \
    float av[8] = {a0.x, a0.y, a0.z, a0.w, a1.x, a1.y, a1.z, a1.w};            \
    float bv[8] = {b0.x, b0.y, b0.z, b0.w, b1.x, b1.y, b1.z, b1.w};            \
    _Pragma("unroll") for (int rr = 0; rr < 8; ++rr)                           \
      _Pragma("unroll") for (int cc2 = 0; cc2 < 8; ++cc2)                      \
        acc[rr][cc2] += av[rr] * bv[cc2];                                      \
  }

#define WRITE_TILE_NORM(Cc)                                                    \
  _Pragma("unroll") for (int rh = 0; rh < 2; ++rh)                             \
  _Pragma("unroll") for (int rr = 0; rr < 4; ++rr) {                           \
    int rI = rh * 4 + rr;                                                      \
    float* rowp = (Cc) + (size_t)(i0 + rh * 64 + ty4 + rr) * N + j0;           \
    *(float4*)(rowp + tx4) =                                                   \
        make_float4(acc[rI][0], acc[rI][1], acc[rI][2], acc[rI][3]);           \
    *(float4*)(rowp + 64 + tx4) =                                              \
        make_float4(acc[rI][4], acc[rI][5], acc[rI][6], acc[rI][7]);           \
  }

#define WRITE_TILE_MIRROR(Cc)                                                  \
  _Pragma("unroll") for (int ch = 0; ch < 2; ++ch)                             \
  _Pragma("unroll") for (int cc2 = 0; cc2 < 4; ++cc2) {                        \
    int cI = ch * 4 + cc2;                                                     \
    float* rowp = (Cc) + (size_t)(j0 + ch * 64 + tx4 + cc2) * N + i0;          \
    *(float4*)(rowp + ty4) =                                                   \
        make_float4(acc[0][cI], acc[1][cI], acc[2][cI], acc[3][cI]);           \
    *(float4*)(rowp + 64 + ty4) =                                              \
        make_float4(acc[4][cI], acc[5][cI], acc[6][cI], acc[7][cI]);           \
  }

// sym block map: bx 0,1,2 -> (0,0),(1,0),(1,1)
#define SYM_MAP                                                                \
  int bx = blockIdx.x;                                                         \
  int i0 = (bx >= 1) ? 128 : 0, j0 = (bx == 2) ? 128 : 0;

// 3) G = A*A^T per channel (lower tiles + mirror)
__global__ __launch_bounds__(256) void k_gram(const float* __restrict__ x,
                                              float* __restrict__ bufA, int base) {
  __shared__ float As[16][132], Bs[16][132];
  GEMM128_VARS; SYM_MAP;
  const float* A = x + (size_t)(base + blockIdx.z) * NN;
  float acc[8][8] = {};
  const float* Ap = A + (size_t)(i0 + lm) * N + lq * 4;
  const float* Bp = A + (size_t)(j0 + lm) * N + lq * 4;
  float4 va0 = *(const float4*)Ap, va1 = *(const float4*)(Ap + 4);
  float4 vb0 = *(const float4*)Bp, vb1 = *(const float4*)(Bp + 4);
  for (int kt = 0; kt < 16; ++kt) {
    __syncthreads();
    STORE_T128(As, va0, va1); STORE_T128(Bs, vb0, vb1);
    __syncthreads();
    if (kt < 15) {
      va0 = *(const float4*)(Ap + (kt + 1) * 16);
      va1 = *(const float4*)(Ap + (kt + 1) * 16 + 4);
      vb0 = *(const float4*)(Bp + (kt + 1) * 16);
      vb1 = *(const float4*)(Bp + (kt + 1) * 16 + 4);
    }
    GEMM128_INNER(As, Bs);
  }
  float* Cc = bufA + (size_t)blockIdx.z * NN;
  WRITE_TILE_NORM(Cc);
  if (bx == 1) { WRITE_TILE_MIRROR(Cc); }
}

// ---------------------------------------------------------------------------
// tridiag helpers: per-chunk matvec (f64 acc) and rank-2 update (f32).
// c0 is 64-aligned and wave-uniform; R0 is the wave's row-block base.
// ---------------------------------------------------------------------------
__device__ __forceinline__ double mv_chunk(const float* __restrict__ P, int c0,
                                           int j, int r, int R0, int triR,
                                           float ureg) {
  double pi0 = 0.0, pi1 = 0.0, pi2 = 0.0, pi3 = 0.0;
  if (c0 < N) {
    int lbeg = (c0 > j + 1) ? c0 : (j + 1);
    int lend = c0 + 64;
    if (lbeg < lend) {
      if (c0 + 64 <= R0) {
        // class A: all l < r -> row-contiguous triR+lmv (no select)
        int lmv = lbeg;
        for (; lmv + 3 < lend; lmv += 4) {
          float uv0 = rdlane(ureg, lmv - c0), uv1 = rdlane(ureg, lmv + 1 - c0);
          float uv2 = rdlane(ureg, lmv + 2 - c0), uv3 = rdlane(ureg, lmv + 3 - c0);
          float v0 = P[triR + lmv], v1 = P[triR + lmv + 1];
          float v2 = P[triR + lmv + 2], v3 = P[triR + lmv + 3];
          pi0 += (double)v0 * (double)uv0;
          pi1 += (double)v1 * (double)uv1;
          pi2 += (double)v2 * (double)uv2;
          pi3 += (double)v3 * (double)uv3;
        }
        for (; lmv < lend; ++lmv)
          pi0 += (double)P[triR + lmv] * (double)rdlane(ureg, lmv - c0);
      } else if (c0 >= R0 + 64) {
        // class C: all l > r -> s(l)+r, incremental s (no select)
        int lmv = lbeg;
        int s = (lmv * (lmv + 1)) >> 1;
        for (; lmv + 3 < lend; lmv += 4) {
          int s0 = s, s1 = s0 + lmv + 1, s2 = s1 + lmv + 2, s3 = s2 + lmv + 3;
          s = s3 + lmv + 4;
          float uv0 = rdlane(ureg, lmv - c0), uv1 = rdlane(ureg, lmv + 1 - c0);
          float uv2 = rdlane(ureg, lmv + 2 - c0), uv3 = rdlane(ureg, lmv + 3 - c0);
          pi0 += (double)P[s0 + r] * (double)uv0;
          pi1 += (double)P[s1 + r] * (double)uv1;
          pi2 += (double)P[s2 + r] * (double)uv2;
          pi3 += (double)P[s3 + r] * (double)uv3;
        }
        for (; lmv < lend; ++lmv) {
          pi0 += (double)P[s + r] * (double)rdlane(ureg, lmv - c0);
          s += lmv + 1;
        }
      } else {
        // class B: diagonal chunk, per-element select
        int lmv = lbeg;
        int s = (lmv * (lmv + 1)) >> 1;
        for (; lmv < lend; ++lmv) {
          float uv = rdlane(ureg, lmv - c0);
          float v = P[(lmv <= r) ? (triR + lmv) : (s + r)];
          pi0 += (double)v * (double)uv;
          s += lmv + 1;
        }
      }
    }
  }
  return (pi0 + pi1) + (pi2 + pi3);
}

__device__ __forceinline__ void upd_chunk(float* __restrict__ P, int c0, int j,
                                          int r, int R0, int triR, float ureg,
                                          float wreg, float urf, float wrf) {
  if (c0 >= N) return;
  int lbeg = (c0 > j + 1) ? c0 : (j + 1);
  int lend = c0 + 64;
  int lcap = (r | 63) + 1; // wave-uniform cap
  if (lend > lcap) lend = lcap;
  if (c0 + 64 <= R0) {
    // class A: full range, all l < r, contiguous
    int lmv = lbeg;
    for (; lmv + 1 < lend; lmv += 2) {
      float uv0 = rdlane(ureg, lmv - c0), wv0 = rdlane(wreg, lmv - c0);
      float uv1 = rdlane(ureg, lmv + 1 - c0), wv1 = rdlane(wreg, lmv + 1 - c0);
      P[triR + lmv] = fmaf(-wrf, uv0, fmaf(-urf, wv0, P[triR + lmv]));
      P[triR + lmv + 1] = fmaf(-wrf, uv1, fmaf(-urf, wv1, P[triR + lmv + 1]));
    }
    if (lmv < lend) {
      float uv0 = rdlane(ureg, lmv - c0), wv0 = rdlane(wreg, lmv - c0);
      P[triR + lmv] = fmaf(-wrf, uv0, fmaf(-urf, wv0, P[triR + lmv]));
    }
  } else if (c0 == R0) {
    // class B: diagonal chunk, per-lane cap
    for (int lmv = lbeg; lmv < lend; ++lmv) {
      float uv = rdlane(ureg, lmv - c0), wv = rdlane(wreg, lmv - c0);
      if (lmv <= r)
        P[triR + lmv] = fmaf(-wrf, uv, fmaf(-urf, wv, P[triR + lmv]));
    }
  }
  // c0 >= R0+64: lend <= lcap = R0+64 <= c0 < lbeg -> empty
}

// ---------------------------------------------------------------------------
// 4) Householder tridiag: 1024 threads = 4 column-groups x 256 rows (one
//    64-column chunk per group; 16 waves = 4/SIMD for latency hiding) with
//    the 5-barrier overlapped schedule: matvec with RAW column x merged into
//    the sigma phase (fixup p = p' - bsub*P(:,j+1)), merged K reduction
//    computed redundantly by all groups (0.25-weighted). f64 matvec, f32
//    rank-2 update.  (R12, measured 3052 us -- unchanged this round.)
// ---------------------------------------------------------------------------
__global__ __launch_bounds__(1024) void k_tridiag(const float* __restrict__ Gall,
                                                  float* __restrict__ small, int base) {
  extern __shared__ double dls[];
  double* redd = dls;              // 16 (sigma partials)
  double* redd2 = dls + 16;        // 16 (K partials)
  double* pip = dls + 32;          // 1024
  float* P = (float*)(dls + 1056); // 32896 packed lower triangle
  float* uf = P + 32896;           // 256
  float* wf = uf + 256;            // 256 (f32 w for the update)
  int tid = threadIdx.x, lane = tid & 63;
  int r = tid & 255, g = tid >> 8; // g in {0..3}
  int wid = tid >> 6;              // 0..15
  int R0 = (wid & 3) << 6;         // wave row-block base (r = R0 + lane)
  int c = base + blockIdx.x;
  const int* ip = (const int*)small;
  if (ip[OFF_MODE + c] != 2) return;
  const float* G = Gall + (size_t)blockIdx.x * NN;
  double* aq = (double*)(small + OFF_AQ) + (size_t)c * 256;
  double* bq = (double*)(small + OFF_BQ) + (size_t)c * 256;
  const int triR = (r * (r + 1)) >> 1;

  for (int i = g; i < N; i += 4)
    if (r <= i) P[((i * (i + 1)) >> 1) + r] = G[i * N + r];
  __syncthreads();

  for (int j = 0; j + 2 < N; ++j) {
    // phase 1: column j -> uf
    if (g == 0 && r >= j + 1) uf[r] = P[triR + j];
    __syncthreads(); // B1
    float x_r = uf[r];                 // valid for r >= j+1
    double x0 = (double)uf[j + 1];
    int cbase = (j + 1) & ~63;
    int c0 = cbase + 64 * g;           // wave-uniform
    float ureg = 0.f;
    if (c0 < N) ureg = uf[c0 + lane];  // uniform cond: rdlane source
    // phase 2 (merged): sigma partial + matvec p' = P*x (raw column)
    double sp = (g == 0 && r >= j + 2) ? (double)x_r * (double)x_r : 0.0;
    double myp = mv_chunk(P, c0, j, r, R0, triR, ureg);
    pip[tid] = (r >= j + 1) ? myp : 0.0;
    for (int off = 32; off; off >>= 1) sp += __shfl_down(sp, off, 64);
    if (lane == 0) redd[wid] = sp;
    __syncthreads(); // B2
    double sigma = (((redd[0] + redd[1]) + (redd[2] + redd[3])) +
                    ((redd[4] + redd[5]) + (redd[6] + redd[7]))) +
                   (((redd[8] + redd[9]) + (redd[10] + redd[11])) +
                    ((redd[12] + redd[13]) + (redd[14] + redd[15])));
    if (sigma <= 1e-40) { // column already tridiagonal
      if (tid == 0) bq[j] = x0;
      continue; // B2 (this iter) orders reads before next iter's B1 writes
    }
    double nu = sqrt(x0 * x0 + sigma);
    double bsub = (x0 >= 0.0) ? -nu : nu;
    double beta = 1.0 / (nu * (nu + fabs(x0)));
    // patch u register at the column-(j+1) slot (self-register write)
    if (c0 <= j + 1 && j + 1 < c0 + 64 && lane == j + 1 - c0)
      ureg = (float)(x0 - bsub);
    // phase 3: pi_r with fixup (all groups redundantly) + K partial
    double pi = 0.0, u_r = 0.0, kp = 0.0;
    if (r >= j + 1) {
      double fix = -bsub * (double)P[triR + (j + 1)];
      pi = (pip[r] + pip[256 + r] + pip[512 + r] + pip[768 + r] + fix) * beta;
      u_r = (r == j + 1) ? (x0 - bsub) : (double)x_r;
      kp = u_r * pi * 0.25; // 0.25: four groups quadruple-count
    }
    for (int off = 32; off; off >>= 1) kp += __shfl_down(kp, off, 64);
    if (lane == 0) redd2[wid] = kp;
    __syncthreads(); // B3
    double K = ((((redd2[0] + redd2[1]) + (redd2[2] + redd2[3])) +
                 ((redd2[4] + redd2[5]) + (redd2[6] + redd2[7]))) +
                (((redd2[8] + redd2[9]) + (redd2[10] + redd2[11])) +
                 ((redd2[12] + redd2[13]) + (redd2[14] + redd2[15])))) *
               beta * 0.5;
    if (g == 0 && r >= j + 1) wf[r] = (float)(pi - K * u_r);
    __syncthreads(); // B4
    float wreg = 0.f;
    if (c0 < N) wreg = wf[c0 + lane]; // uniform cond: rdlane source
    // phase 4: rank-2 update (f32)
    if (r >= j + 1) {
      float urf = (float)u_r;
      float wrf = wf[r];
      upd_chunk(P, c0, j, r, R0, triR, ureg, wreg, urf, wrf);
    }
    if (tid == 0) bq[j] = bsub;
    __syncthreads(); // B5
  }
  if (g == 0) aq[r] = (double)P[triR + r];
  if (tid == 0) bq[N - 2] = (double)P[(((N - 1) * N) >> 1) + N - 2];
}

// ---------------------------------------------------------------------------
// 5) fp64 Sturm 64-way multisection -> t, alpha, polar-express schedule,
//    and per-channel it_sw (first iteration with margin l >= 0.02, safe for
//    f16 MFMA: f16 spectral perturbation ~5e-4, 20-40x margin).
// ---------------------------------------------------------------------------
__device__ __forceinline__ int sturm_count_lds(const double* a, const double* b,
                                               double t) {
  double d = a[0] - t;
  int cnt = (d < 0.0);
  for (int i = 1; i < N; ++i) {
    double den = d;
    if (fabs(den) < 1e-20) den = (den < 0.0) ? -1e-20 : 1e-20;
    double bb = b[i - 1];
    d = (a[i] - t) - bb * bb / den;
    cnt += (d < 0.0);
  }
  return cnt; // #{eig < t}
}

__global__ __launch_bounds__(64) void k_bisect(float* __restrict__ small,
                                               int base, int cc) {
  int ci = blockIdx.x;
  if (ci >= cc) return;
  int c = base + ci, lane = threadIdx.x;
  int* ip = (int*)small;
  if (ip[OFF_MODE + c] != 2) {
    if (lane == 0) { ip[OFF_MC + c] = 0; ip[OFF_ITSW + c] = 0; }
    return;
  }
  int k = ip[OFF_K + c];
  const double* a = (const double*)(small + OFF_AQ) + (size_t)c * 256;
  const double* b = (const double*)(small + OFF_BQ) + (size_t)c * 256;
  __shared__ double sa[256], sb[256];
  for (int i = lane; i < N; i += 64) {
    sa[i] = a[i];
    if (i < N - 1) sb[i] = b[i];
  }
  __syncthreads();
  // Gershgorin bounds (wave-parallel)
  double lo = 1e300, hi = -1e300;
  for (int i = lane; i < N; i += 64) {
    double rr = (i > 0 ? fabs(sb[i - 1]) : 0.0) + (i < N - 1 ? fabs(sb[i]) : 0.0);
    lo = fmin(lo, sa[i] - rr);
    hi = fmax(hi, sa[i] + rr);
  }
  for (int off = 32; off; off >>= 1) {
    lo = fmin(lo, __shfl_xor(lo, off, 64));
    hi = fmax(hi, __shfl_xor(hi, off, 64));
  }
  double lamk = 0.0, lamk1 = 0.0;
  for (int which = 0; which < 2; ++which) {
    int j = (which == 0) ? (N - k + 1) : (N - k); // ascending index of mu_j
    double l0 = lo, h0 = hi;
    for (int pass = 0; pass < 10; ++pass) {
      double step = (h0 - l0) * (1.0 / 65.0);
      double t = l0 + step * (double)(lane + 1);
      int cnt = sturm_count_lds(sa, sb, t);
      unsigned long long mask = __ballot(cnt >= j);
      if (mask == 0ull) {
        l0 = l0 + step * 64.0; // mu_j above all probes
      } else {
        int bpos = __ffsll((long long)mask) - 1; // first probe with cnt>=j
        double nl = (bpos == 0) ? l0 : (l0 + step * (double)bpos);
        h0 = l0 + step * (double)(bpos + 1);
        l0 = nl;
      }
    }
    double v = 0.5 * (l0 + h0);
    if (which == 0) lamk = v; else lamk1 = v;
  }
  if (lane == 0) {
    double t = 0.5 * (lamk + lamk1);
    double gap = fmax(lamk - lamk1, 0.0);
    double alpha = 1.002 * fmax(hi - t, t - lo) + 1e-30;
    double g0 = fmax(gap / (2.0 * alpha), 2e-6);
    // polar-express schedule: equioscillation cubic per iteration
    float* cf = small + OFF_COEF + (size_t)c * (2 * NS_MAX);
    double l = fmin(g0, 0.99);
    int m = 0, isw = NS_MAX;
    while (m < NS_MAX - 2 && l < 0.9999) {
      if (isw == NS_MAX && l >= 0.02) isw = m;
      double aa = sqrt(27.0 / (4.0 * (1.0 + l + l * l)));
      double bb = (4.0 / 27.0) * aa * aa * aa;
      cf[2 * m] = (float)aa;
      cf[2 * m + 1] = (float)bb;
      double pl = aa * l - bb * l * l * l;
      double p1 = aa - bb;
      l = fmin(pl, p1);
      m++;
    }
    for (int e = 0; e < 2; ++e) {
      if (isw == NS_MAX && l >= 0.02) isw = m;
      cf[2 * m] = 1.5f; cf[2 * m + 1] = 0.5f; m++;
    }
    if (isw > m) isw = m;
    ip[OFF_MC + c] = m;
    ip[OFF_ITSW + c] = isw;
    ((double*)(small + OFF_T))[c] = t;
    ((double*)(small + OFF_ALPHA))[c] = alpha;
  }
}

// 6) X0 = (G - t*I)/alpha (in place on bufA, fp64 scale)
__global__ void k_x0(const float* __restrict__ small, float* __restrict__ bufA,
                     int base) {
  int ci = blockIdx.y, c = base + ci;
  const int* ip = (const int*)small;
  if (ip[OFF_MODE + c] != 2) return;
  double t = ((const double*)(small + OFF_T))[c];
  double inva = 1.0 / ((const double*)(small + OFF_ALPHA))[c];
  float* X = bufA + (size_t)ci * NN;
  int r = blockIdx.x, tid = threadIdx.x;
  double gg = (double)X[r * N + tid];
  if (tid == r) gg -= t;
  X[r * N + tid] = (float)(gg * inva);
}

// 7a) S = X*X (X symmetric; lower tiles + mirror) -- fp32 path (it < it_sw)
__global__ __launch_bounds__(256) void k_ns1(const float* __restrict__ src,
                                             float* __restrict__ Sb,
                                             const float* __restrict__ small,
                                             int base, int it) {
  const int* ip = (const int*)small;
  int c = base + blockIdx.z;
  if (ip[OFF_MODE + c] != 2 || it >= ip[OFF_ITSW + c]) return;
  __shared__ float As[16][132], Bs[16][132];
  GEMM128_VARS; SYM_MAP;
  const float* X = src + (size_t)blockIdx.z * NN;
  float acc[8][8] = {};
  const float* Ap = X + (size_t)(i0 + lm) * N + lq * 4;
  const float* Bp = X + (size_t)(j0 + lm) * N + lq * 4;
  float4 va0 = *(const float4*)Ap, va1 = *(const float4*)(Ap + 4);
  float4 vb0 = *(const float4*)Bp, vb1 = *(const float4*)(Bp + 4);
  for (int kt = 0; kt < 16; ++kt) {
    __syncthreads();
    STORE_T128(As, va0, va1); STORE_T128(Bs, vb0, vb1);
    __syncthreads();
    if (kt < 15) {
      va0 = *(const float4*)(Ap + (kt + 1) * 16);
      va1 = *(const float4*)(Ap + (kt + 1) * 16 + 4);
      vb0 = *(const float4*)(Bp + (kt + 1) * 16);
      vb1 = *(const float4*)(Bp + (kt + 1) * 16 + 4);
    }
    GEMM128_INNER(As, Bs);
  }
  float* Cc = Sb + (size_t)blockIdx.z * NN;
  WRITE_TILE_NORM(Cc);
  if (bx == 1) { WRITE_TILE_MIRROR(Cc); }
}

// 7b) Y = a*X - b*X*S (commuting symmetric -> Y symmetric; tiles + mirror)
__global__ __launch_bounds__(256) void k_ns2(const float* __restrict__ src,
                                             const float* __restrict__ Sb,
                                             float* __restrict__ dst,
                                             const float* __restrict__ small,
                                             int base, int it) {
  const int* ip = (const int*)small;
  int c = base + blockIdx.z;
  if (ip[OFF_MODE + c] != 2 || it >= ip[OFF_ITSW + c]) return;
  float ca = small[OFF_COEF + (size_t)c * (2 * NS_MAX) + 2 * it];
  float cb = small[OFF_COEF + (size_t)c * (2 * NS_MAX) + 2 * it + 1];
  __shared__ float As[16][132], Bs[16][132];
  GEMM128_VARS; SYM_MAP;
  const float* X = src + (size_t)blockIdx.z * NN;
  const float* S = Sb + (size_t)blockIdx.z * NN;
  float acc[8][8] = {};
  const float* Ap = X + (size_t)(i0 + lm) * N + lq * 4;
  const float* Bp = S + (size_t)(j0 + lm) * N + lq * 4;
  float4 va0 = *(const float4*)Ap, va1 = *(const float4*)(Ap + 4);
  float4 vb0 = *(const float4*)Bp, vb1 = *(const float4*)(Bp + 4);
  for (int kt = 0; kt < 16; ++kt) {
    __syncthreads();
    STORE_T128(As, va0, va1); STORE_T128(Bs, vb0, vb1);
    __syncthreads();
    if (kt < 15) {
      va0 = *(const float4*)(Ap + (kt + 1) * 16);
      va1 = *(const float4*)(Ap + (kt + 1) * 16 + 4);
      vb0 = *(const float4*)(Bp + (kt + 1) * 16);
      vb1 = *(const float4*)(Bp + (kt + 1) * 16 + 4);
    }
    GEMM128_INNER(As, Bs);
  }
  // acc <- ca*X - cb*acc (transform in place, then write norm + mirror)
#pragma unroll
  for (int rh = 0; rh < 2; ++rh)
#pragma unroll
    for (int rr = 0; rr < 4; ++rr) {
      int rI = rh * 4 + rr;
      const float* rowp = X + (size_t)(i0 + rh * 64 + ty4 + rr) * N + j0;
      float4 x0 = *(const float4*)(rowp + tx4);
      float4 x1 = *(const float4*)(rowp + 64 + tx4);
      acc[rI][0] = ca * x0.x - cb * acc[rI][0];
      acc[rI][1] = ca * x0.y - cb * acc[rI][1];
      acc[rI][2] = ca * x0.z - cb * acc[rI][2];
      acc[rI][3] = ca * x0.w - cb * acc[rI][3];
      acc[rI][4] = ca * x1.x - cb * acc[rI][4];
      acc[rI][5] = ca * x1.y - cb * acc[rI][5];
      acc[rI][6] = ca * x1.z - cb * acc[rI][6];
      acc[rI][7] = ca * x1.w - cb * acc[rI][7];
    }
  float* Y = dst + (size_t)blockIdx.z * NN;
  WRITE_TILE_NORM(Y);
  if (bx == 1) { WRITE_TILE_MIRROR(Y); }
}

// ---------------------------------------------------------------------------
// 7c) k_nsf: fused f16 MFMA NS iteration, ONE CHANNEL PER BLOCK (512 thr).
//     X staged once into LDS (256 x 264 f16). Phase B: S = X*X -> f16 to the
//     channel's Sf (bufC) alias. threadfence+syncthreads (single-producer
//     block). Phase C: Y = ca*X - cb*X*S with S via L2. WRITE POLICY matches
//     k_nsh bitwise (R14 fix): same-128-block -> direct; gr>=128>gc -> write
//     + mirror; upper off-diag -> skip (those waves skip MFMA too). Final
//     iteration writes fp32 Y full slot instead of the f16 alias.
//     Waves: 8 = 4 row-blocks(64) x 2 col-blocks(128); 4x8 16x16 frags.
// ---------------------------------------------------------------------------
__global__ __launch_bounds__(512) void k_nsf(const float* __restrict__ srcF,
                                             float* __restrict__ Sf,
                                             float* __restrict__ dstF,
                                             const float* __restrict__ small,
                                             int base, int it) {
  const int* ip = (const int*)small;
  int ci = blockIdx.x, c = base + ci;
  if (ip[OFF_MODE + c] != 2) return;
  int isw = ip[OFF_ITSW + c], mc = ip[OFF_MC + c];
  if (it < isw || it >= mc) return;
  extern __shared__ char ldsraw[];
  u16* Xl = (u16*)ldsraw; // 256 rows x 264 (8-elem pad)
  int tid = threadIdx.x;
  const float* XF = srcF + (size_t)ci * NN;
  const u16* XH = (const u16*)XF; // f16 alias (first half of slot)
  if (it == isw) { // stage from fp32, convert in flight
#pragma unroll
    for (int i = 0; i < 16; ++i) {
      int e = tid * 8 + i * 4096;
      float4 v0 = *(const float4*)(XF + e);
      float4 v1 = *(const float4*)(XF + e + 4);
      h8 hv;
      hv[0] = (_Float16)v0.x; hv[1] = (_Float16)v0.y;
      hv[2] = (_Float16)v0.z; hv[3] = (_Float16)v0.w;
      hv[4] = (_Float16)v1.x; hv[5] = (_Float16)v1.y;
      hv[6] = (_Float16)v1.z; hv[7] = (_Float16)v1.w;
      *(h8*)&Xl[(e >> 8) * 264 + (e & 255)] = hv;
    }
  } else { // stage f16 image
#pragma unroll
    for (int i = 0; i < 16; ++i) {
      int e = tid * 8 + i * 4096;
      *(uint4*)&Xl[(e >> 8) * 264 + (e & 255)] = *(const uint4*)(XH + e);
    }
  }
  __syncthreads();

  int l = tid & 63, wid = tid >> 6;
  int r0 = (wid >> 1) * 64, cB = (wid & 1) * 128; // wave's 64x128 sub-tile
  int rl = l & 15, kB = (l >> 4) << 3, lr4 = (l >> 4) << 2;
  // wave-uniform block classification (row 128-block vs col 128-block)
  int rb = r0 >> 7, cb2 = cB >> 7;
  bool diagw = (rb == cb2);   // same 128-block: direct write
  bool mirw = (rb > cb2);     // lower off-diag: write + mirror
  bool skipw = (rb < cb2);    // upper off-diag: skip entirely
  u16* SH = (u16*)(Sf + (size_t)ci * NN);
  f32x4 zero = {0.f, 0.f, 0.f, 0.f};
  f32x4 acc[4][8];

  // ---- phase B: S = X*X (lower blocks + mirror, k_nsh policy) ----
  if (!skipw) {
#pragma unroll
    for (int mi = 0; mi < 4; ++mi)
#pragma unroll
      for (int ni = 0; ni < 8; ++ni) acc[mi][ni] = zero;
#pragma unroll
    for (int kc = 0; kc < 8; ++kc) {
      int kof = kc * 32 + kB;
      h8 af[4], bf[8];
#pragma unroll
      for (int mi = 0; mi < 4; ++mi)
        af[mi] = *(const h8*)&Xl[(size_t)(r0 + mi * 16 + rl) * 264 + kof];
#pragma unroll
      for (int ni = 0; ni < 8; ++ni)
        bf[ni] = *(const h8*)&Xl[(size_t)(cB + ni * 16 + rl) * 264 + kof];
#pragma unroll
      for (int mi = 0; mi < 4; ++mi)
#pragma unroll
        for (int ni = 0; ni < 8; ++ni)
          acc[mi][ni] = __builtin_amdgcn_mfma_f32_16x16x32_f16(
              af[mi], bf[ni], acc[mi][ni], 0, 0, 0);
    }
    // C/D layout (m89-verified): col = lane&15, row = (lane>>4)*4 + reg
#pragma unroll
    for (int mi = 0; mi < 4; ++mi)
#pragma unroll
      for (int ni = 0; ni < 8; ++ni)
#pragma unroll
        for (int rg = 0; rg < 4; ++rg) {
          int gr = r0 + mi * 16 + lr4 + rg;
          int gc = cB + ni * 16 + rl;
          u16 hv = f2h(acc[mi][ni][rg]);
          SH[(size_t)gr * N + gc] = hv;
          if (mirw) SH[(size_t)gc * N + gr] = hv;
        }
  }
  __threadfence(); // drain S writes (single-producer block; L2-coherent)
  __syncthreads();

  // ---- phase C: Y = ca*X - cb*X*S (same write policy) ----
  float cav = small[OFF_COEF + (size_t)c * (2 * NS_MAX) + 2 * it];
  float cbv = small[OFF_COEF + (size_t)c * (2 * NS_MAX) + 2 * it + 1];
  bool last = (it == mc - 1);
  if (!skipw) {
#pragma unroll
    for (int mi = 0; mi < 4; ++mi)
#pragma unroll
      for (int ni = 0; ni < 8; ++ni) acc[mi][ni] = zero;
#pragma unroll
    for (int kc = 0; kc < 8; ++kc) {
      int kof = kc * 32 + kB;
      h8 af[4], bf[8];
#pragma unroll
      for (int mi = 0; mi < 4; ++mi)
        af[mi] = *(const h8*)&Xl[(size_t)(r0 + mi * 16 + rl) * 264 + kof];
#pragma unroll
      for (int ni = 0; ni < 8; ++ni) // S symmetric: B[k][col] = S[col][k]
        bf[ni] = *(const h8*)(SH + (size_t)(cB + ni * 16 + rl) * N + kof);
#pragma unroll
      for (int mi = 0; mi < 4; ++mi)
#pragma unroll
        for (int ni = 0; ni < 8; ++ni)
          acc[mi][ni] = __builtin_amdgcn_mfma_f32_16x16x32_f16(
              af[mi], bf[ni], acc[mi][ni], 0, 0, 0);
    }
    float* oF = dstF + (size_t)ci * NN;
    u16* oH = (u16*)oF;
#pragma unroll
    for (int mi = 0; mi < 4; ++mi)
#pragma unroll
      for (int ni = 0; ni < 8; ++ni)
#pragma unroll
        for (int rg = 0; rg < 4; ++rg) {
          int gr = r0 + mi * 16 + lr4 + rg;
          int gc = cB + ni * 16 + rl;
          float xv = h2f(Xl[(size_t)gr * 264 + gc]);
          float v = cav * xv - cbv * acc[mi][ni][rg];
          if (!last) {
            u16 hv = f2h(v);
            oH[(size_t)gr * N + gc] = hv;
            if (mirw) oH[(size_t)gc * N + gr] = hv;
          } else {
            oF[(size_t)gr * N + gc] = v;
            if (mirw) oF[(size_t)gc * N + gr] = v;
          }
        }
  }
}

// 8) A_k = 0.5*(sign(X)*A + A) (modes: 0 -> zeros, 1 -> copy A)
__global__ __launch_bounds__(256) void k_proj(const float* __restrict__ bufA,
                                              const float* __restrict__ bufB,
                                              const float* __restrict__ x,
                                              float* __restrict__ bufC,
                                              const float* __restrict__ small,
                                              int base) {
  const int* ip = (const int*)small;
  int ci = blockIdx.z, c = base + ci;
  int mode = ip[OFF_MODE + c];
  GEMM128_VARS;
  int i0 = blockIdx.x * 128, j0 = blockIdx.y * 128;
  float* Cc = bufC + (size_t)ci * NN;
  const float* xc = x + (size_t)c * NN;
  if (mode != 2) {
#pragma unroll
    for (int rh = 0; rh < 2; ++rh)
#pragma unroll
      for (int rr = 0; rr < 4; ++rr) {
        size_t ro = (size_t)(i0 + rh * 64 + ty4 + rr) * N + j0;
        if (mode == 0) {
          *(float4*)(Cc + ro + tx4) = make_float4(0.f, 0.f, 0.f, 0.f);
          *(float4*)(Cc + ro + 64 + tx4) = make_float4(0.f, 0.f, 0.f, 0.f);
        } else {
          *(float4*)(Cc + ro + tx4) = *(const float4*)(xc + ro + tx4);
          *(float4*)(Cc + ro + 64 + tx4) = *(const float4*)(xc + ro + 64 + tx4);
        }
      }
    return;
  }
  int mc = ip[OFF_MC + c];
  const float* Xh = ((mc & 1) ? bufB : bufA) + (size_t)ci * NN;
  __shared__ float As[16][132], Bs[16][132];
  float acc[8][8] = {};
  const float* Ap = Xh + (size_t)(i0 + lm) * N + lq * 4;
  const float* Bp = xc + (size_t)lk * N + j0 + lc * 4;
  float4 va0 = *(const float4*)Ap, va1 = *(const float4*)(Ap + 4);
  float4 vb0 = *(const float4*)Bp, vb1 = *(const float4*)(Bp + 4);
  for (int kt = 0; kt < 16; ++kt) {
    __syncthreads();
    STORE_T128(As, va0, va1);
    *(float4*)&Bs[lk][lc * 4] = vb0;
    *(float4*)&Bs[lk][(lc + 1) * 4] = vb1;
    __syncthreads();
    if (kt < 15) {
      va0 = *(const float4*)(Ap + (kt + 1) * 16);
      va1 = *(const float4*)(Ap + (kt + 1) * 16 + 4);
      const float* Bp2 = xc + (size_t)((kt + 1) * 16 + lk) * N + j0 + lc * 4;
      vb0 = *(const float4*)Bp2;
      vb1 = *(const float4*)(Bp2 + 4);
    }
    GEMM128_INNER(As, Bs);
  }
#pragma unroll
  for (int rh = 0; rh < 2; ++rh)
#pragma unroll
    for (int rr = 0; rr < 4; ++rr) {
      int rI = rh * 4 + rr;
      const float* rowp = xc + (size_t)(i0 + rh * 64 + ty4 + rr) * N + j0;
      float4 x0 = *(const float4*)(rowp + tx4);
      float4 x1 = *(const float4*)(rowp + 64 + tx4);
      acc[rI][0] = 0.5f * (acc[rI][0] + x0.x);
      acc[rI][1] = 0.5f * (acc[rI][1] + x0.y);
      acc[rI][2] = 0.5f * (acc[rI][2] + x0.z);
      acc[rI][3] = 0.5f * (acc[rI][3] + x0.w);
      acc[rI][4] = 0.5f * (acc[rI][4] + x1.x);
      acc[rI][5] = 0.5f * (acc[rI][5] + x1.y);
      acc[rI][6] = 0.5f * (acc[rI][6] + x1.z);
      acc[rI][7] = 0.5f * (acc[rI][7] + x1.w);
    }
  WRITE_TILE_NORM(Cc);
}

// 9) accumulate sum & max over channels
__global__ void k_accum(const float* __restrict__ bufC, float* __restrict__ sum_hw,
                        float* __restrict__ max_hw, int cc, int first) {
  int p = blockIdx.x * 256 + threadIdx.x;
  float s = first ? 0.f : sum_hw[p];
  float m = first ? -1e30f : max_hw[p];
  for (int ci = 0; ci < cc; ++ci) {
    float v = bufC[(size_t)ci * NN + p];
    s += v;
    m = fmaxf(m, v);
  }
  sum_hw[p] = s;
  max_hw[p] = m;
}

// 10) 7x7 conv (pad 3) on [avg, max] -> clamp EPS -> sigmoid
__global__ void k_conv(const float* __restrict__ sum_hw, const float* __restrict__ max_hw,
                       const float* __restrict__ cw, float* __restrict__ out) {
  int p = blockIdx.x * 256 + threadIdx.x;
  int h = p >> 8, w = p & 255;
  float acc = 0.f;
  for (int dy = 0; dy < 7; ++dy) {
    int hy = h + dy - 3;
    if (hy < 0 || hy > 255) continue;
    for (int dx = 0; dx < 7; ++dx) {
      int wx = w + dx - 3;
      if (wx < 0 || wx > 255) continue;
      int q = hy * 256 + wx;
      acc += cw[dy * 7 + dx] * (sum_hw[q] * (1.f / 256.f)) +
             cw[49 + dy * 7 + dx] * max_hw[q];
    }
  }
  acc = fmaxf(acc, EPSF);
  out[p] = 1.f / (1.f + expf(-acc));
}

// ---------------------------------------------------------------------------
extern "C" void kernel_launch(void* const* d_in, const int* in_sizes, int n_in,
                              void* d_out, int out_size, void* d_ws, size_t ws_size,
                              hipStream_t stream) {
  const float* x = (const float*)d_in[0];
  const float* w1 = (const float*)d_in[1];
  const float* w2 = (const float*)d_in[2];
  const float* cw = (const float*)d_in[3];
  const int* kv = (const int*)d_in[4];
  float* out = (float*)d_out;
  float* small = (float*)d_ws;

  size_t small_bytes = (size_t)SMALL_FLOATS * 4;
  size_t avail = ws_size > small_bytes ? ws_size - small_bytes : 0;
  long chunk = (long)(avail / (3ull * NN * 4)); // 3 fp32 matrices per channel
  if (chunk > NCH) chunk = NCH;
  if (chunk < 1) chunk = 1;
  float* bufA = small + SMALL_FLOATS;
  float* bufB = bufA + (size_t)chunk * NN;
  float* bufC = bufB + (size_t)chunk * NN;

  const int tridiag_lds = 1056 * 8 + 32896 * 4 + 512 * 4; // 142080 B
  hipFuncSetAttribute((const void*)k_tridiag,
                      hipFuncAttributeMaxDynamicSharedMemorySize, tridiag_lds);
  hipFuncSetAttribute((const void*)k_nsf,
                      hipFuncAttributeMaxDynamicSharedMemorySize, NSF_LDS);

  k_chan_stats<<<NCH, 256, 0, stream>>>(x, small);
  k_attention<<<1, 256, 0, stream>>>(w1, w2, kv, small);

  const int IT32 = 13; // it_sw <= 12 provably; fp32 path never needed past this

  for (int base = 0; base < NCH; base += (int)chunk) {
    int cc = (NCH - base < (int)chunk) ? (NCH - base) : (int)chunk;
    dim3 gsym(3, 1, cc);
    dim3 gproj(2, 2, cc);
    k_gram<<<gsym, 256, 0, stream>>>(x, bufA, base);
    k_tridiag<<<cc, 1024, tridiag_lds, stream>>>(bufA, small, base);
    k_bisect<<<cc, 64, 0, stream>>>(small, base, cc);
    k_x0<<<dim3(N, cc), 256, 0, stream>>>(small, bufA, base);
    for (int it = 0; it < NS_MAX; ++it) {
      const float* src = (it & 1) ? bufB : bufA;
      float* dst = (it & 1) ? bufA : bufB;
      if (it < IT32) {
        k_ns1<<<gsym, 256, 0, stream>>>(src, bufC, small, base, it);
        k_ns2<<<gsym, 256, 0, stream>>>(src, bufC, dst, small, base, it);
      }
      k_nsf<<<cc, 512, NSF_LDS, stream>>>(src, bufC, dst, small, base, it);
    }
    k_proj<<<gproj, 256, 0, stream>>>(bufA, bufB, x, bufC, small, base);
    k_accum<<<256, 256, 0, stream>>>(bufC, small + OFF_SUM, small + OFF_MAXHW, cc,
                                     base == 0 ? 1 : 0);
  }
  k_conv<<<256, 256, 0, stream>>>(small + OFF_SUM, small + OFF_MAXHW, cw, out);
}

// Round 10
// 5755.448 us; speedup vs baseline: 1.0071x; 1.0071x over previous
//
#include <hip/hip_runtime.h>

// ============================================================================
// AFAR: channel-attention -> per-channel truncated-SVD recon -> spatial attn.
// A_k = P*A, P = step(G - t), G = A*A^T. t from mixed-precision Householder
// tridiag + fp64 Sturm multisection. Projector via polar-express schedule;
// late iterations (certified margin l >= 0.02) run as f16 MFMA GEMMs.
// R15: fix k_nsf's phase-C memory pattern (R14 regression: B-operand read S
// from global scattered, 64 cache lines/instr at 2 waves/SIMD). Phase C now
// stages S columns per-kc into a 256x40 f16 LDS chunk (coalesced uint4, all
// 512 threads incl. skip-waves), MFMA B-frags read from LDS (~2-way bank
// aliasing = free). Values bit-identical to R14; write policy (diag direct /
// lower+mirror / upper skip) untouched -> absmax unchanged. Tridiag = R12.
// ============================================================================

#define NCH 256
#define N 256
#define NN 65536
#define NS_MAX 22

// small-region float offsets inside d_ws (double regions 8B-aligned)
#define OFF_K 0          // int[256]
#define OFF_MODE 256     // int[256]: 0 -> A_k=0, 1 -> A_k=A, 2 -> project
#define OFF_MC 512       // int[256]
#define OFF_COEF 768     // float[256][2*NS_MAX]
#define OFF_SUM 12032    // float[65536]
#define OFF_MAXHW 77568  // float[65536]
#define OFF_MEAND 143104 // double[256]
#define OFF_MAXD 143616  // double[256]
#define OFF_T 144128     // double[256]
#define OFF_ALPHA 144640 // double[256]
#define OFF_AQ 145152    // double[256][256]
#define OFF_BQ 276224    // double[256][256]
#define OFF_ITSW 407296  // int[256]: first iteration index safe for f16 MFMA
#define SMALL_FLOATS 407552

#define NSF_LDS 155648   // X: 256x264 f16 (135168) + S chunk: 256x40 f16 (20480)

static const float EPSF = 2.220446049250313e-16f;

typedef unsigned short u16;
typedef _Float16 h8 __attribute__((ext_vector_type(8)));
typedef float f32x4 __attribute__((ext_vector_type(4)));

__device__ __forceinline__ float rdlane(float v, int l) {
  return __uint_as_float(__builtin_amdgcn_readlane(__float_as_uint(v), l));
}

__device__ __forceinline__ u16 f2h(float v) {
  _Float16 h = (_Float16)v;
  u16 u;
  __builtin_memcpy(&u, &h, 2);
  return u;
}
__device__ __forceinline__ float h2f(u16 u) {
  _Float16 h;
  __builtin_memcpy(&h, &u, 2);
  return (float)h;
}

// ---------------------------------------------------------------------------
// 1) per-channel mean & max over H*W (fp64 sum)
// ---------------------------------------------------------------------------
__global__ __launch_bounds__(256) void k_chan_stats(const float* __restrict__ x,
                                                    float* __restrict__ small) {
  int c = blockIdx.x, tid = threadIdx.x;
  const float4* xc = (const float4*)(x + (size_t)c * NN);
  double s = 0.0;
  float m = -1e30f;
  for (int i = tid; i < NN / 4; i += 256) {
    float4 v = xc[i];
    s += (double)v.x + (double)v.y + (double)v.z + (double)v.w;
    m = fmaxf(m, fmaxf(fmaxf(v.x, v.y), fmaxf(v.z, v.w)));
  }
  __shared__ double rs[4];
  __shared__ float rm[4];
  for (int off = 32; off; off >>= 1) {
    s += __shfl_down(s, off, 64);
    m = fmaxf(m, __shfl_down(m, off, 64));
  }
  if ((tid & 63) == 0) { rs[tid >> 6] = s; rm[tid >> 6] = m; }
  __syncthreads();
  if (tid == 0) {
    ((double*)(small + OFF_MEAND))[c] = (rs[0] + rs[1] + rs[2] + rs[3]) / (double)NN;
    ((double*)(small + OFF_MAXD))[c] =
        (double)fmaxf(fmaxf(rm[0], rm[1]), fmaxf(rm[2], rm[3]));
  }
}

// ---------------------------------------------------------------------------
// 2) shared-MLP channel attention (fp64) -> gates yc -> k_c, mode_c
// ---------------------------------------------------------------------------
__global__ __launch_bounds__(256) void k_attention(const float* __restrict__ w1,
                                                   const float* __restrict__ w2,
                                                   const int* __restrict__ kvp,
                                                   float* __restrict__ small) {
  int tid = threadIdx.x;
  __shared__ double ha[16], hm[16], redd[8], ymn[256], ymx[256];
  double va = ((const double*)(small + OFF_MEAND))[tid];
  double vm = ((const double*)(small + OFF_MAXD))[tid];
  for (int r = 0; r < 16; ++r) {
    double wv = (double)w1[r * 256 + tid];
    double pa = wv * va, pm = wv * vm;
    for (int off = 32; off; off >>= 1) {
      pa += __shfl_down(pa, off, 64);
      pm += __shfl_down(pm, off, 64);
    }
    if ((tid & 63) == 0) { redd[tid >> 6] = pa; redd[4 + (tid >> 6)] = pm; }
    __syncthreads();
    if (tid == 0) {
      ha[r] = fmax(redd[0] + redd[1] + redd[2] + redd[3], 0.0);
      hm[r] = fmax(redd[4] + redd[5] + redd[6] + redd[7], 0.0);
    }
    __syncthreads();
  }
  double ya = 0.0, ym = 0.0;
  for (int r = 0; r < 16; ++r) {
    double wv = (double)w2[tid * 16 + r];
    ya += ha[r] * wv;
    ym += hm[r] * wv;
  }
  double y = 1.0 / (1.0 + exp(-(ya + ym)));
  ymn[tid] = y; ymx[tid] = y;
  __syncthreads();
  for (int off = 128; off; off >>= 1) {
    if (tid < off) {
      ymn[tid] = fmin(ymn[tid], ymn[tid + off]);
      ymx[tid] = fmax(ymx[tid], ymx[tid + off]);
    }
    __syncthreads();
  }
  double yc = (y - ymn[0]) / (ymx[0] - ymn[0] + 1e-20);
  int kv = kvp[0];
  int k = (int)floor(256.0 * (double)kv * yc);
  int mode = (k <= 0) ? 0 : ((k >= 256) ? 1 : 2);
  int* ip = (int*)small;
  ip[OFF_K + tid] = k;
  ip[OFF_MODE + tid] = mode;
}

// ---------------------------------------------------------------------------
// GEMM core: 128x128 tile, 256 threads, 8x8 micro-tile (2x2 quadrants of 4)
// ---------------------------------------------------------------------------
#define GEMM128_VARS                                                           \
  int tid = threadIdx.x;                                                       \
  int tx4 = (tid & 15) * 4, ty4 = (tid >> 4) * 4;                              \
  int lm = tid >> 1, lq = (tid & 1) * 2;                                       \
  int lk = tid >> 4, lc = (tid & 15) * 2;                                      \
  (void)lk; (void)lc;

#define STORE_T128(Ls, v0, v1)                                                 \
  Ls[lq * 4 + 0][lm] = v0.x; Ls[lq * 4 + 1][lm] = v0.y;                        \
  Ls[lq * 4 + 2][lm] = v0.z; Ls[lq * 4 + 3][lm] = v0.w;                        \
  Ls[lq * 4 + 4][lm] = v1.x; Ls[lq * 4 + 5][lm] = v1.y;                        \
  Ls[lq * 4 + 6][lm] = v1.z; Ls[lq * 4 + 7][lm] = v1.w;

#define GEMM128_INNER(AsM, BsM)                                                \
  _Pragma("unroll") for (int kk = 0; kk < 16; ++kk) {                          \
    float4 a0 = *(const float4*)&AsM[kk][ty4];                                 \
    float4 a1 = *(const float4*)&AsM[kk][64 + ty4];                            \
    float4 b0 = *(const float4*)&BsM[kk][tx4];                                 \
    float4 b1 = *(const float4*)&BsM[kk][64 + tx4];                            \
    float av[8] = {a0.x, a0.y, a0.z, a0.w, a1.x, a1.y, a1.z, a1.w};            \
    float bv[8] = {b0.x, b0.y, b0.z, b0.w, b1.x, b1.y, b1.z, b1.w};            \
    _Pragma("unroll") for (int rr = 0; rr < 8; ++rr)                           \
      _Pragma("unroll") for (int cc2 = 0; cc2 < 8; ++cc2)                      \
        acc[rr][cc2] += av[rr] * bv[cc2];                                      \
  }

#define WRITE_TILE_NORM(Cc)                                                    \
  _Pragma("unroll") for (int rh = 0; rh < 2; ++rh)                             \
  _Pragma("unroll") for (int rr = 0; rr < 4; ++rr) {                           \
    int rI = rh * 4 + rr;                                                      \
    float* rowp = (Cc) + (size_t)(i0 + rh * 64 + ty4 + rr) * N + j0;           \
    *(float4*)(rowp + tx4) =                                                   \
        make_float4(acc[rI][0], acc[rI][1], acc[rI][2], acc[rI][3]);           \
    *(float4*)(rowp + 64 + tx4) =                                              \
        make_float4(acc[rI][4], acc[rI][5], acc[rI][6], acc[rI][7]);           \
  }

#define WRITE_TILE_MIRROR(Cc)                                                  \
  _Pragma("unroll") for (int ch = 0; ch < 2; ++ch)                             \
  _Pragma("unroll") for (int cc2 = 0; cc2 < 4; ++cc2) {                        \
    int cI = ch * 4 + cc2;                                                     \
    float* rowp = (Cc) + (size_t)(j0 + ch * 64 + tx4 + cc2) * N + i0;          \
    *(float4*)(rowp + ty4) =                                                   \
        make_float4(acc[0][cI], acc[1][cI], acc[2][cI], acc[3][cI]);           \
    *(float4*)(rowp + 64 + ty4) =                                              \
        make_float4(acc[4][cI], acc[5][cI], acc[6][cI], acc[7][cI]);           \
  }

// sym block map: bx 0,1,2 -> (0,0),(1,0),(1,1)
#define SYM_MAP                                                                \
  int bx = blockIdx.x;                                                         \
  int i0 = (bx >= 1) ? 128 : 0, j0 = (bx == 2) ? 128 : 0;

// 3) G = A*A^T per channel (lower tiles + mirror)
__global__ __launch_bounds__(256) void k_gram(const float* __restrict__ x,
                                              float* __restrict__ bufA, int base) {
  __shared__ float As[16][132], Bs[16][132];
  GEMM128_VARS; SYM_MAP;
  const float* A = x + (size_t)(base + blockIdx.z) * NN;
  float acc[8][8] = {};
  const float* Ap = A + (size_t)(i0 + lm) * N + lq * 4;
  const float* Bp = A + (size_t)(j0 + lm) * N + lq * 4;
  float4 va0 = *(const float4*)Ap, va1 = *(const float4*)(Ap + 4);
  float4 vb0 = *(const float4*)Bp, vb1 = *(const float4*)(Bp + 4);
  for (int kt = 0; kt < 16; ++kt) {
    __syncthreads();
    STORE_T128(As, va0, va1); STORE_T128(Bs, vb0, vb1);
    __syncthreads();
    if (kt < 15) {
      va0 = *(const float4*)(Ap + (kt + 1) * 16);
      va1 = *(const float4*)(Ap + (kt + 1) * 16 + 4);
      vb0 = *(const float4*)(Bp + (kt + 1) * 16);
      vb1 = *(const float4*)(Bp + (kt + 1) * 16 + 4);
    }
    GEMM128_INNER(As, Bs);
  }
  float* Cc = bufA + (size_t)blockIdx.z * NN;
  WRITE_TILE_NORM(Cc);
  if (bx == 1) { WRITE_TILE_MIRROR(Cc); }
}

// ---------------------------------------------------------------------------
// tridiag helpers: per-chunk matvec (f64 acc) and rank-2 update (f32).
// c0 is 64-aligned and wave-uniform; R0 is the wave's row-block base.
// ---------------------------------------------------------------------------
__device__ __forceinline__ double mv_chunk(const float* __restrict__ P, int c0,
                                           int j, int r, int R0, int triR,
                                           float ureg) {
  double pi0 = 0.0, pi1 = 0.0, pi2 = 0.0, pi3 = 0.0;
  if (c0 < N) {
    int lbeg = (c0 > j + 1) ? c0 : (j + 1);
    int lend = c0 + 64;
    if (lbeg < lend) {
      if (c0 + 64 <= R0) {
        // class A: all l < r -> row-contiguous triR+lmv (no select)
        int lmv = lbeg;
        for (; lmv + 3 < lend; lmv += 4) {
          float uv0 = rdlane(ureg, lmv - c0), uv1 = rdlane(ureg, lmv + 1 - c0);
          float uv2 = rdlane(ureg, lmv + 2 - c0), uv3 = rdlane(ureg, lmv + 3 - c0);
          float v0 = P[triR + lmv], v1 = P[triR + lmv + 1];
          float v2 = P[triR + lmv + 2], v3 = P[triR + lmv + 3];
          pi0 += (double)v0 * (double)uv0;
          pi1 += (double)v1 * (double)uv1;
          pi2 += (double)v2 * (double)uv2;
          pi3 += (double)v3 * (double)uv3;
        }
        for (; lmv < lend; ++lmv)
          pi0 += (double)P[triR + lmv] * (double)rdlane(ureg, lmv - c0);
      } else if (c0 >= R0 + 64) {
        // class C: all l > r -> s(l)+r, incremental s (no select)
        int lmv = lbeg;
        int s = (lmv * (lmv + 1)) >> 1;
        for (; lmv + 3 < lend; lmv += 4) {
          int s0 = s, s1 = s0 + lmv + 1, s2 = s1 + lmv + 2, s3 = s2 + lmv + 3;
          s = s3 + lmv + 4;
          float uv0 = rdlane(ureg, lmv - c0), uv1 = rdlane(ureg, lmv + 1 - c0);
          float uv2 = rdlane(ureg, lmv + 2 - c0), uv3 = rdlane(ureg, lmv + 3 - c0);
          pi0 += (double)P[s0 + r] * (double)uv0;
          pi1 += (double)P[s1 + r] * (double)uv1;
          pi2 += (double)P[s2 + r] * (double)uv2;
          pi3 += (double)P[s3 + r] * (double)uv3;
        }
        for (; lmv < lend; ++lmv) {
          pi0 += (double)P[s + r] * (double)rdlane(ureg, lmv - c0);
          s += lmv + 1;
        }
      } else {
        // class B: diagonal chunk, per-element select
        int lmv = lbeg;
        int s = (lmv * (lmv + 1)) >> 1;
        for (; lmv < lend; ++lmv) {
          float uv = rdlane(ureg, lmv - c0);
          float v = P[(lmv <= r) ? (triR + lmv) : (s + r)];
          pi0 += (double)v * (double)uv;
          s += lmv + 1;
        }
      }
    }
  }
  return (pi0 + pi1) + (pi2 + pi3);
}

__device__ __forceinline__ void upd_chunk(float* __restrict__ P, int c0, int j,
                                          int r, int R0, int triR, float ureg,
                                          float wreg, float urf, float wrf) {
  if (c0 >= N) return;
  int lbeg = (c0 > j + 1) ? c0 : (j + 1);
  int lend = c0 + 64;
  int lcap = (r | 63) + 1; // wave-uniform cap
  if (lend > lcap) lend = lcap;
  if (c0 + 64 <= R0) {
    // class A: full range, all l < r, contiguous
    int lmv = lbeg;
    for (; lmv + 1 < lend; lmv += 2) {
      float uv0 = rdlane(ureg, lmv - c0), wv0 = rdlane(wreg, lmv - c0);
      float uv1 = rdlane(ureg, lmv + 1 - c0), wv1 = rdlane(wreg, lmv + 1 - c0);
      P[triR + lmv] = fmaf(-wrf, uv0, fmaf(-urf, wv0, P[triR + lmv]));
      P[triR + lmv + 1] = fmaf(-wrf, uv1, fmaf(-urf, wv1, P[triR + lmv + 1]));
    }
    if (lmv < lend) {
      float uv0 = rdlane(ureg, lmv - c0), wv0 = rdlane(wreg, lmv - c0);
      P[triR + lmv] = fmaf(-wrf, uv0, fmaf(-urf, wv0, P[triR + lmv]));
    }
  } else if (c0 == R0) {
    // class B: diagonal chunk, per-lane cap
    for (int lmv = lbeg; lmv < lend; ++lmv) {
      float uv = rdlane(ureg, lmv - c0), wv = rdlane(wreg, lmv - c0);
      if (lmv <= r)
        P[triR + lmv] = fmaf(-wrf, uv, fmaf(-urf, wv, P[triR + lmv]));
    }
  }
  // c0 >= R0+64: lend <= lcap = R0+64 <= c0 < lbeg -> empty
}

// ---------------------------------------------------------------------------
// 4) Householder tridiag: 1024 threads = 4 column-groups x 256 rows (one
//    64-column chunk per group; 16 waves = 4/SIMD for latency hiding) with
//    the 5-barrier overlapped schedule: matvec with RAW column x merged into
//    the sigma phase (fixup p = p' - bsub*P(:,j+1)), merged K reduction
//    computed redundantly by all groups (0.25-weighted). f64 matvec, f32
//    rank-2 update.  (R12 structure, measured ~3030 us.)
// ---------------------------------------------------------------------------
__global__ __launch_bounds__(1024) void k_tridiag(const float* __restrict__ Gall,
                                                  float* __restrict__ small, int base) {
  extern __shared__ double dls[];
  double* redd = dls;              // 16 (sigma partials)
  double* redd2 = dls + 16;        // 16 (K partials)
  double* pip = dls + 32;          // 1024
  float* P = (float*)(dls + 1056); // 32896 packed lower triangle
  float* uf = P + 32896;           // 256
  float* wf = uf + 256;            // 256 (f32 w for the update)
  int tid = threadIdx.x, lane = tid & 63;
  int r = tid & 255, g = tid >> 8; // g in {0..3}
  int wid = tid >> 6;              // 0..15
  int R0 = (wid & 3) << 6;         // wave row-block base (r = R0 + lane)
  int c = base + blockIdx.x;
  const int* ip = (const int*)small;
  if (ip[OFF_MODE + c] != 2) return;
  const float* G = Gall + (size_t)blockIdx.x * NN;
  double* aq = (double*)(small + OFF_AQ) + (size_t)c * 256;
  double* bq = (double*)(small + OFF_BQ) + (size_t)c * 256;
  const int triR = (r * (r + 1)) >> 1;

  for (int i = g; i < N; i += 4)
    if (r <= i) P[((i * (i + 1)) >> 1) + r] = G[i * N + r];
  __syncthreads();

  for (int j = 0; j + 2 < N; ++j) {
    // phase 1: column j -> uf
    if (g == 0 && r >= j + 1) uf[r] = P[triR + j];
    __syncthreads(); // B1
    float x_r = uf[r];                 // valid for r >= j+1
    double x0 = (double)uf[j + 1];
    int cbase = (j + 1) & ~63;
    int c0 = cbase + 64 * g;           // wave-uniform
    float ureg = 0.f;
    if (c0 < N) ureg = uf[c0 + lane];  // uniform cond: rdlane source
    // phase 2 (merged): sigma partial + matvec p' = P*x (raw column)
    double sp = (g == 0 && r >= j + 2) ? (double)x_r * (double)x_r : 0.0;
    double myp = mv_chunk(P, c0, j, r, R0, triR, ureg);
    pip[tid] = (r >= j + 1) ? myp : 0.0;
    for (int off = 32; off; off >>= 1) sp += __shfl_down(sp, off, 64);
    if (lane == 0) redd[wid] = sp;
    __syncthreads(); // B2
    double sigma = (((redd[0] + redd[1]) + (redd[2] + redd[3])) +
                    ((redd[4] + redd[5]) + (redd[6] + redd[7]))) +
                   (((redd[8] + redd[9]) + (redd[10] + redd[11])) +
                    ((redd[12] + redd[13]) + (redd[14] + redd[15])));
    if (sigma <= 1e-40) { // column already tridiagonal
      if (tid == 0) bq[j] = x0;
      continue; // B2 (this iter) orders reads before next iter's B1 writes
    }
    double nu = sqrt(x0 * x0 + sigma);
    double bsub = (x0 >= 0.0) ? -nu : nu;
    double beta = 1.0 / (nu * (nu + fabs(x0)));
    // patch u register at the column-(j+1) slot (self-register write)
    if (c0 <= j + 1 && j + 1 < c0 + 64 && lane == j + 1 - c0)
      ureg = (float)(x0 - bsub);
    // phase 3: pi_r with fixup (all groups redundantly) + K partial
    double pi = 0.0, u_r = 0.0, kp = 0.0;
    if (r >= j + 1) {
      double fix = -bsub * (double)P[triR + (j + 1)];
      pi = (pip[r] + pip[256 + r] + pip[512 + r] + pip[768 + r] + fix) * beta;
      u_r = (r == j + 1) ? (x0 - bsub) : (double)x_r;
      kp = u_r * pi * 0.25; // 0.25: four groups quadruple-count
    }
    for (int off = 32; off; off >>= 1) kp += __shfl_down(kp, off, 64);
    if (lane == 0) redd2[wid] = kp;
    __syncthreads(); // B3
    double K = ((((redd2[0] + redd2[1]) + (redd2[2] + redd2[3])) +
                 ((redd2[4] + redd2[5]) + (redd2[6] + redd2[7]))) +
                (((redd2[8] + redd2[9]) + (redd2[10] + redd2[11])) +
                 ((redd2[12] + redd2[13]) + (redd2[14] + redd2[15])))) *
               beta * 0.5;
    if (g == 0 && r >= j + 1) wf[r] = (float)(pi - K * u_r);
    __syncthreads(); // B4
    float wreg = 0.f;
    if (c0 < N) wreg = wf[c0 + lane]; // uniform cond: rdlane source
    // phase 4: rank-2 update (f32)
    if (r >= j + 1) {
      float urf = (float)u_r;
      float wrf = wf[r];
      upd_chunk(P, c0, j, r, R0, triR, ureg, wreg, urf, wrf);
    }
    if (tid == 0) bq[j] = bsub;
    __syncthreads(); // B5
  }
  if (g == 0) aq[r] = (double)P[triR + r];
  if (tid == 0) bq[N - 2] = (double)P[(((N - 1) * N) >> 1) + N - 2];
}

// ---------------------------------------------------------------------------
// 5) fp64 Sturm 64-way multisection -> t, alpha, polar-express schedule,
//    and per-channel it_sw (first iteration with margin l >= 0.02, safe for
//    f16 MFMA: f16 spectral perturbation ~5e-4, 20-40x margin).
// ---------------------------------------------------------------------------
__device__ __forceinline__ int sturm_count_lds(const double* a, const double* b,
                                               double t) {
  double d = a[0] - t;
  int cnt = (d < 0.0);
  for (int i = 1; i < N; ++i) {
    double den = d;
    if (fabs(den) < 1e-20) den = (den < 0.0) ? -1e-20 : 1e-20;
    double bb = b[i - 1];
    d = (a[i] - t) - bb * bb / den;
    cnt += (d < 0.0);
  }
  return cnt; // #{eig < t}
}

__global__ __launch_bounds__(64) void k_bisect(float* __restrict__ small,
                                               int base, int cc) {
  int ci = blockIdx.x;
  if (ci >= cc) return;
  int c = base + ci, lane = threadIdx.x;
  int* ip = (int*)small;
  if (ip[OFF_MODE + c] != 2) {
    if (lane == 0) { ip[OFF_MC + c] = 0; ip[OFF_ITSW + c] = 0; }
    return;
  }
  int k = ip[OFF_K + c];
  const double* a = (const double*)(small + OFF_AQ) + (size_t)c * 256;
  const double* b = (const double*)(small + OFF_BQ) + (size_t)c * 256;
  __shared__ double sa[256], sb[256];
  for (int i = lane; i < N; i += 64) {
    sa[i] = a[i];
    if (i < N - 1) sb[i] = b[i];
  }
  __syncthreads();
  // Gershgorin bounds (wave-parallel)
  double lo = 1e300, hi = -1e300;
  for (int i = lane; i < N; i += 64) {
    double rr = (i > 0 ? fabs(sb[i - 1]) : 0.0) + (i < N - 1 ? fabs(sb[i]) : 0.0);
    lo = fmin(lo, sa[i] - rr);
    hi = fmax(hi, sa[i] + rr);
  }
  for (int off = 32; off; off >>= 1) {
    lo = fmin(lo, __shfl_xor(lo, off, 64));
    hi = fmax(hi, __shfl_xor(hi, off, 64));
  }
  double lamk = 0.0, lamk1 = 0.0;
  for (int which = 0; which < 2; ++which) {
    int j = (which == 0) ? (N - k + 1) : (N - k); // ascending index of mu_j
    double l0 = lo, h0 = hi;
    for (int pass = 0; pass < 10; ++pass) {
      double step = (h0 - l0) * (1.0 / 65.0);
      double t = l0 + step * (double)(lane + 1);
      int cnt = sturm_count_lds(sa, sb, t);
      unsigned long long mask = __ballot(cnt >= j);
      if (mask == 0ull) {
        l0 = l0 + step * 64.0; // mu_j above all probes
      } else {
        int bpos = __ffsll((long long)mask) - 1; // first probe with cnt>=j
        double nl = (bpos == 0) ? l0 : (l0 + step * (double)bpos);
        h0 = l0 + step * (double)(bpos + 1);
        l0 = nl;
      }
    }
    double v = 0.5 * (l0 + h0);
    if (which == 0) lamk = v; else lamk1 = v;
  }
  if (lane == 0) {
    double t = 0.5 * (lamk + lamk1);
    double gap = fmax(lamk - lamk1, 0.0);
    double alpha = 1.002 * fmax(hi - t, t - lo) + 1e-30;
    double g0 = fmax(gap / (2.0 * alpha), 2e-6);
    // polar-express schedule: equioscillation cubic per iteration
    float* cf = small + OFF_COEF + (size_t)c * (2 * NS_MAX);
    double l = fmin(g0, 0.99);
    int m = 0, isw = NS_MAX;
    while (m < NS_MAX - 2 && l < 0.9999) {
      if (isw == NS_MAX && l >= 0.02) isw = m;
      double aa = sqrt(27.0 / (4.0 * (1.0 + l + l * l)));
      double bb = (4.0 / 27.0) * aa * aa * aa;
      cf[2 * m] = (float)aa;
      cf[2 * m + 1] = (float)bb;
      double pl = aa * l - bb * l * l * l;
      double p1 = aa - bb;
      l = fmin(pl, p1);
      m++;
    }
    for (int e = 0; e < 2; ++e) {
      if (isw == NS_MAX && l >= 0.02) isw = m;
      cf[2 * m] = 1.5f; cf[2 * m + 1] = 0.5f; m++;
    }
    if (isw > m) isw = m;
    ip[OFF_MC + c] = m;
    ip[OFF_ITSW + c] = isw;
    ((double*)(small + OFF_T))[c] = t;
    ((double*)(small + OFF_ALPHA))[c] = alpha;
  }
}

// 6) X0 = (G - t*I)/alpha (in place on bufA, fp64 scale)
__global__ void k_x0(const float* __restrict__ small, float* __restrict__ bufA,
                     int base) {
  int ci = blockIdx.y, c = base + ci;
  const int* ip = (const int*)small;
  if (ip[OFF_MODE + c] != 2) return;
  double t = ((const double*)(small + OFF_T))[c];
  double inva = 1.0 / ((const double*)(small + OFF_ALPHA))[c];
  float* X = bufA + (size_t)ci * NN;
  int r = blockIdx.x, tid = threadIdx.x;
  double gg = (double)X[r * N + tid];
  if (tid == r) gg -= t;
  X[r * N + tid] = (float)(gg * inva);
}

// 7a) S = X*X (X symmetric; lower tiles + mirror) -- fp32 path (it < it_sw)
__global__ __launch_bounds__(256) void k_ns1(const float* __restrict__ src,
                                             float* __restrict__ Sb,
                                             const float* __restrict__ small,
                                             int base, int it) {
  const int* ip = (const int*)small;
  int c = base + blockIdx.z;
  if (ip[OFF_MODE + c] != 2 || it >= ip[OFF_ITSW + c]) return;
  __shared__ float As[16][132], Bs[16][132];
  GEMM128_VARS; SYM_MAP;
  const float* X = src + (size_t)blockIdx.z * NN;
  float acc[8][8] = {};
  const float* Ap = X + (size_t)(i0 + lm) * N + lq * 4;
  const float* Bp = X + (size_t)(j0 + lm) * N + lq * 4;
  float4 va0 = *(const float4*)Ap, va1 = *(const float4*)(Ap + 4);
  float4 vb0 = *(const float4*)Bp, vb1 = *(const float4*)(Bp + 4);
  for (int kt = 0; kt < 16; ++kt) {
    __syncthreads();
    STORE_T128(As, va0, va1); STORE_T128(Bs, vb0, vb1);
    __syncthreads();
    if (kt < 15) {
      va0 = *(const float4*)(Ap + (kt + 1) * 16);
      va1 = *(const float4*)(Ap + (kt + 1) * 16 + 4);
      vb0 = *(const float4*)(Bp + (kt + 1) * 16);
      vb1 = *(const float4*)(Bp + (kt + 1) * 16 + 4);
    }
    GEMM128_INNER(As, Bs);
  }
  float* Cc = Sb + (size_t)blockIdx.z * NN;
  WRITE_TILE_NORM(Cc);
  if (bx == 1) { WRITE_TILE_MIRROR(Cc); }
}

// 7b) Y = a*X - b*X*S (commuting symmetric -> Y symmetric; tiles + mirror)
__global__ __launch_bounds__(256) void k_ns2(const float* __restrict__ src,
                                             const float* __restrict__ Sb,
                                             float* __restrict__ dst,
                                             const float* __restrict__ small,
                                             int base, int it) {
  const int* ip = (const int*)small;
  int c = base + blockIdx.z;
  if (ip[OFF_MODE + c] != 2 || it >= ip[OFF_ITSW + c]) return;
  float ca = small[OFF_COEF + (size_t)c * (2 * NS_MAX) + 2 * it];
  float cb = small[OFF_COEF + (size_t)c * (2 * NS_MAX) + 2 * it + 1];
  __shared__ float As[16][132], Bs[16][132];
  GEMM128_VARS; SYM_MAP;
  const float* X = src + (size_t)blockIdx.z * NN;
  const float* S = Sb + (size_t)blockIdx.z * NN;
  float acc[8][8] = {};
  const float* Ap = X + (size_t)(i0 + lm) * N + lq * 4;
  const float* Bp = S + (size_t)(j0 + lm) * N + lq * 4;
  float4 va0 = *(const float4*)Ap, va1 = *(const float4*)(Ap + 4);
  float4 vb0 = *(const float4*)Bp, vb1 = *(const float4*)(Bp + 4);
  for (int kt = 0; kt < 16; ++kt) {
    __syncthreads();
    STORE_T128(As, va0, va1); STORE_T128(Bs, vb0, vb1);
    __syncthreads();
    if (kt < 15) {
      va0 = *(const float4*)(Ap + (kt + 1) * 16);
      va1 = *(const float4*)(Ap + (kt + 1) * 16 + 4);
      vb0 = *(const float4*)(Bp + (kt + 1) * 16);
      vb1 = *(const float4*)(Bp + (kt + 1) * 16 + 4);
    }
    GEMM128_INNER(As, Bs);
  }
  // acc <- ca*X - cb*acc (transform in place, then write norm + mirror)
#pragma unroll
  for (int rh = 0; rh < 2; ++rh)
#pragma unroll
    for (int rr = 0; rr < 4; ++rr) {
      int rI = rh * 4 + rr;
      const float* rowp = X + (size_t)(i0 + rh * 64 + ty4 + rr) * N + j0;
      float4 x0 = *(const float4*)(rowp + tx4);
      float4 x1 = *(const float4*)(rowp + 64 + tx4);
      acc[rI][0] = ca * x0.x - cb * acc[rI][0];
      acc[rI][1] = ca * x0.y - cb * acc[rI][1];
      acc[rI][2] = ca * x0.z - cb * acc[rI][2];
      acc[rI][3] = ca * x0.w - cb * acc[rI][3];
      acc[rI][4] = ca * x1.x - cb * acc[rI][4];
      acc[rI][5] = ca * x1.y - cb * acc[rI][5];
      acc[rI][6] = ca * x1.z - cb * acc[rI][6];
      acc[rI][7] = ca * x1.w - cb * acc[rI][7];
    }
  float* Y = dst + (size_t)blockIdx.z * NN;
  WRITE_TILE_NORM(Y);
  if (bx == 1) { WRITE_TILE_MIRROR(Y); }
}

// ---------------------------------------------------------------------------
// 7c) k_nsf: fused f16 MFMA NS iteration, ONE CHANNEL PER BLOCK (512 thr).
//     X staged once into LDS (256 x 264 f16). Phase B: S = X*X -> f16 to the
//     channel's Sf (bufC) alias (diag direct / lower+mirror / upper skip =
//     k_nsh policy, bitwise). threadfence+syncthreads. Phase C: per-kc the
//     whole block stages S[:, kc*32..+32) into a 256x40 f16 LDS chunk
//     (coalesced uint4; R15 fix for the scattered global B-reads), then
//     Y = ca*X - cb*X*S with B-frags from LDS. Same write policy; final
//     iteration writes fp32 Y full slot instead of the f16 alias.
// ---------------------------------------------------------------------------
__global__ __launch_bounds__(512) void k_nsf(const float* __restrict__ srcF,
                                             float* __restrict__ Sf,
                                             float* __restrict__ dstF,
                                             const float* __restrict__ small,
                                             int base, int it) {
  const int* ip = (const int*)small;
  int ci = blockIdx.x, c = base + ci;
  if (ip[OFF_MODE + c] != 2) return;
  int isw = ip[OFF_ITSW + c], mc = ip[OFF_MC + c];
  if (it < isw || it >= mc) return;
  extern __shared__ char ldsraw[];
  u16* Xl = (u16*)ldsraw;           // 256 rows x 264 (8-elem pad)
  u16* Sl = Xl + 256 * 264;         // 256 rows x 40 (per-kc S column chunk)
  int tid = threadIdx.x;
  const float* XF = srcF + (size_t)ci * NN;
  const u16* XH = (const u16*)XF; // f16 alias (first half of slot)
  if (it == isw) { // stage from fp32, convert in flight
#pragma unroll
    for (int i = 0; i < 16; ++i) {
      int e = tid * 8 + i * 4096;
      float4 v0 = *(const float4*)(XF + e);
      float4 v1 = *(const float4*)(XF + e + 4);
      h8 hv;
      hv[0] = (_Float16)v0.x; hv[1] = (_Float16)v0.y;
      hv[2] = (_Float16)v0.z; hv[3] = (_Float16)v0.w;
      hv[4] = (_Float16)v1.x; hv[5] = (_Float16)v1.y;
      hv[6] = (_Float16)v1.z; hv[7] = (_Float16)v1.w;
      *(h8*)&Xl[(e >> 8) * 264 + (e & 255)] = hv;
    }
  } else { // stage f16 image
#pragma unroll
    for (int i = 0; i < 16; ++i) {
      int e = tid * 8 + i * 4096;
      *(uint4*)&Xl[(e >> 8) * 264 + (e & 255)] = *(const uint4*)(XH + e);
    }
  }
  __syncthreads();

  int l = tid & 63, wid = tid >> 6;
  int r0 = (wid >> 1) * 64, cB = (wid & 1) * 128; // wave's 64x128 sub-tile
  int rl = l & 15, kB = (l >> 4) << 3, lr4 = (l >> 4) << 2;
  // wave-uniform block classification (row 128-block vs col 128-block)
  int rb = r0 >> 7, cb2 = cB >> 7;
  bool mirw = (rb > cb2);     // lower off-diag: write + mirror
  bool skipw = (rb < cb2);    // upper off-diag: skip MFMA (stage only)
  u16* SH = (u16*)(Sf + (size_t)ci * NN);
  f32x4 zero = {0.f, 0.f, 0.f, 0.f};
  f32x4 acc[4][8];

  // ---- phase B: S = X*X (lower blocks + mirror, k_nsh policy) ----
  if (!skipw) {
#pragma unroll
    for (int mi = 0; mi < 4; ++mi)
#pragma unroll
      for (int ni = 0; ni < 8; ++ni) acc[mi][ni] = zero;
#pragma unroll
    for (int kc = 0; kc < 8; ++kc) {
      int kof = kc * 32 + kB;
      h8 af[4], bf[8];
#pragma unroll
      for (int mi = 0; mi < 4; ++mi)
        af[mi] = *(const h8*)&Xl[(size_t)(r0 + mi * 16 + rl) * 264 + kof];
#pragma unroll
      for (int ni = 0; ni < 8; ++ni)
        bf[ni] = *(const h8*)&Xl[(size_t)(cB + ni * 16 + rl) * 264 + kof];
#pragma unroll
      for (int mi = 0; mi < 4; ++mi)
#pragma unroll
        for (int ni = 0; ni < 8; ++ni)
          acc[mi][ni] = __builtin_amdgcn_mfma_f32_16x16x32_f16(
              af[mi], bf[ni], acc[mi][ni], 0, 0, 0);
    }
    // C/D layout (m89-verified): col = lane&15, row = (lane>>4)*4 + reg
#pragma unroll
    for (int mi = 0; mi < 4; ++mi)
#pragma unroll
      for (int ni = 0; ni < 8; ++ni)
#pragma unroll
        for (int rg = 0; rg < 4; ++rg) {
          int gr = r0 + mi * 16 + lr4 + rg;
          int gc = cB + ni * 16 + rl;
          u16 hv = f2h(acc[mi][ni][rg]);
          SH[(size_t)gr * N + gc] = hv;
          if (mirw) SH[(size_t)gc * N + gr] = hv;
        }
  }
  __threadfence(); // drain S writes (single-producer block; L2-coherent)
  __syncthreads();

  // ---- phase C: Y = ca*X - cb*X*S (B-frags via per-kc LDS chunk) ----
  float cav = small[OFF_COEF + (size_t)c * (2 * NS_MAX) + 2 * it];
  float cbv = small[OFF_COEF + (size_t)c * (2 * NS_MAX) + 2 * it + 1];
  bool last = (it == mc - 1);
  if (!skipw) {
#pragma unroll
    for (int mi = 0; mi < 4; ++mi)
#pragma unroll
      for (int ni = 0; ni < 8; ++ni) acc[mi][ni] = zero;
  }
  for (int kc = 0; kc < 8; ++kc) {
    __syncthreads(); // previous chunk fully consumed
    // stage S[:, kc*32 .. +32) -> Sl (coalesced uint4, ALL threads)
#pragma unroll
    for (int i = 0; i < 2; ++i) {
      int idx = tid + i * 512;       // 0..1023
      int row = idx >> 2, colg = (idx & 3) * 8;
      *(uint4*)&Sl[row * 40 + colg] =
          *(const uint4*)(SH + (size_t)row * N + kc * 32 + colg);
    }
    __syncthreads();
    if (!skipw) {
      int kof = kc * 32 + kB;
      h8 af[4], bf[8];
#pragma unroll
      for (int mi = 0; mi < 4; ++mi)
        af[mi] = *(const h8*)&Xl[(size_t)(r0 + mi * 16 + rl) * 264 + kof];
#pragma unroll
      for (int ni = 0; ni < 8; ++ni) // S symmetric: B[k][col] = S[col][k]
        bf[ni] = *(const h8*)&Sl[(size_t)(cB + ni * 16 + rl) * 40 + kB];
#pragma unroll
      for (int mi = 0; mi < 4; ++mi)
#pragma unroll
        for (int ni = 0; ni < 8; ++ni)
          acc[mi][ni] = __builtin_amdgcn_mfma_f32_16x16x32_f16(
              af[mi], bf[ni], acc[mi][ni], 0, 0, 0);
    }
  }
  if (!skipw) {
    float* oF = dstF + (size_t)ci * NN;
    u16* oH = (u16*)oF;
#pragma unroll
    for (int mi = 0; mi < 4; ++mi)
#pragma unroll
      for (int ni = 0; ni < 8; ++ni)
#pragma unroll
        for (int rg = 0; rg < 4; ++rg) {
          int gr = r0 + mi * 16 + lr4 + rg;
          int gc = cB + ni * 16 + rl;
          float xv = h2f(Xl[(size_t)gr * 264 + gc]);
          float v = cav * xv - cbv * acc[mi][ni][rg];
          if (!last) {
            u16 hv = f2h(v);
            oH[(size_t)gr * N + gc] = hv;
            if (mirw) oH[(size_t)gc * N + gr] = hv;
          } else {
            oF[(size_t)gr * N + gc] = v;
            if (mirw) oF[(size_t)gc * N + gr] = v;
          }
        }
  }
}

// 8) A_k = 0.5*(sign(X)*A + A) (modes: 0 -> zeros, 1 -> copy A)
__global__ __launch_bounds__(256) void k_proj(const float* __restrict__ bufA,
                                              const float* __restrict__ bufB,
                                              const float* __restrict__ x,
                                              float* __restrict__ bufC,
                                              const float* __restrict__ small,
                                              int base) {
  const int* ip = (const int*)small;
  int ci = blockIdx.z, c = base + ci;
  int mode = ip[OFF_MODE + c];
  GEMM128_VARS;
  int i0 = blockIdx.x * 128, j0 = blockIdx.y * 128;
  float* Cc = bufC + (size_t)ci * NN;
  const float* xc = x + (size_t)c * NN;
  if (mode != 2) {
#pragma unroll
    for (int rh = 0; rh < 2; ++rh)
#pragma unroll
      for (int rr = 0; rr < 4; ++rr) {
        size_t ro = (size_t)(i0 + rh * 64 + ty4 + rr) * N + j0;
        if (mode == 0) {
          *(float4*)(Cc + ro + tx4) = make_float4(0.f, 0.f, 0.f, 0.f);
          *(float4*)(Cc + ro + 64 + tx4) = make_float4(0.f, 0.f, 0.f, 0.f);
        } else {
          *(float4*)(Cc + ro + tx4) = *(const float4*)(xc + ro + tx4);
          *(float4*)(Cc + ro + 64 + tx4) = *(const float4*)(xc + ro + 64 + tx4);
        }
      }
    return;
  }
  int mc = ip[OFF_MC + c];
  const float* Xh = ((mc & 1) ? bufB : bufA) + (size_t)ci * NN;
  __shared__ float As[16][132], Bs[16][132];
  float acc[8][8] = {};
  const float* Ap = Xh + (size_t)(i0 + lm) * N + lq * 4;
  const float* Bp = xc + (size_t)lk * N + j0 + lc * 4;
  float4 va0 = *(const float4*)Ap, va1 = *(const float4*)(Ap + 4);
  float4 vb0 = *(const float4*)Bp, vb1 = *(const float4*)(Bp + 4);
  for (int kt = 0; kt < 16; ++kt) {
    __syncthreads();
    STORE_T128(As, va0, va1);
    *(float4*)&Bs[lk][lc * 4] = vb0;
    *(float4*)&Bs[lk][(lc + 1) * 4] = vb1;
    __syncthreads();
    if (kt < 15) {
      va0 = *(const float4*)(Ap + (kt + 1) * 16);
      va1 = *(const float4*)(Ap + (kt + 1) * 16 + 4);
      const float* Bp2 = xc + (size_t)((kt + 1) * 16 + lk) * N + j0 + lc * 4;
      vb0 = *(const float4*)Bp2;
      vb1 = *(const float4*)(Bp2 + 4);
    }
    GEMM128_INNER(As, Bs);
  }
#pragma unroll
  for (int rh = 0; rh < 2; ++rh)
#pragma unroll
    for (int rr = 0; rr < 4; ++rr) {
      int rI = rh * 4 + rr;
      const float* rowp = xc + (size_t)(i0 + rh * 64 + ty4 + rr) * N + j0;
      float4 x0 = *(const float4*)(rowp + tx4);
      float4 x1 = *(const float4*)(rowp + 64 + tx4);
      acc[rI][0] = 0.5f * (acc[rI][0] + x0.x);
      acc[rI][1] = 0.5f * (acc[rI][1] + x0.y);
      acc[rI][2] = 0.5f * (acc[rI][2] + x0.z);
      acc[rI][3] = 0.5f * (acc[rI][3] + x0.w);
      acc[rI][4] = 0.5f * (acc[rI][4] + x1.x);
      acc[rI][5] = 0.5f * (acc[rI][5] + x1.y);
      acc[rI][6] = 0.5f * (acc[rI][6] + x1.z);
      acc[rI][7] = 0.5f * (acc[rI][7] + x1.w);
    }
  WRITE_TILE_NORM(Cc);
}

// 9) accumulate sum & max over channels
__global__ void k_accum(const float* __restrict__ bufC, float* __restrict__ sum_hw,
                        float* __restrict__ max_hw, int cc, int first) {
  int p = blockIdx.x * 256 + threadIdx.x;
  float s = first ? 0.f : sum_hw[p];
  float m = first ? -1e30f : max_hw[p];
  for (int ci = 0; ci < cc; ++ci) {
    float v = bufC[(size_t)ci * NN + p];
    s += v;
    m = fmaxf(m, v);
  }
  sum_hw[p] = s;
  max_hw[p] = m;
}

// 10) 7x7 conv (pad 3) on [avg, max] -> clamp EPS -> sigmoid
__global__ void k_conv(const float* __restrict__ sum_hw, const float* __restrict__ max_hw,
                       const float* __restrict__ cw, float* __restrict__ out) {
  int p = blockIdx.x * 256 + threadIdx.x;
  int h = p >> 8, w = p & 255;
  float acc = 0.f;
  for (int dy = 0; dy < 7; ++dy) {
    int hy = h + dy - 3;
    if (hy < 0 || hy > 255) continue;
    for (int dx = 0; dx < 7; ++dx) {
      int wx = w + dx - 3;
      if (wx < 0 || wx > 255) continue;
      int q = hy * 256 + wx;
      acc += cw[dy * 7 + dx] * (sum_hw[q] * (1.f / 256.f)) +
             cw[49 + dy * 7 + dx] * max_hw[q];
    }
  }
  acc = fmaxf(acc, EPSF);
  out[p] = 1.f / (1.f + expf(-acc));
}

// ---------------------------------------------------------------------------
extern "C" void kernel_launch(void* const* d_in, const int* in_sizes, int n_in,
                              void* d_out, int out_size, void* d_ws, size_t ws_size,
                              hipStream_t stream) {
  const float* x = (const float*)d_in[0];
  const float* w1 = (const float*)d_in[1];
  const float* w2 = (const float*)d_in[2];
  const float* cw = (const float*)d_in[3];
  const int* kv = (const int*)d_in[4];
  float* out = (float*)d_out;
  float* small = (float*)d_ws;

  size_t small_bytes = (size_t)SMALL_FLOATS * 4;
  size_t avail = ws_size > small_bytes ? ws_size - small_bytes : 0;
  long chunk = (long)(avail / (3ull * NN * 4)); // 3 fp32 matrices per channel
  if (chunk > NCH) chunk = NCH;
  if (chunk < 1) chunk = 1;
  float* bufA = small + SMALL_FLOATS;
  float* bufB = bufA + (size_t)chunk * NN;
  float* bufC = bufB + (size_t)chunk * NN;

  const int tridiag_lds = 1056 * 8 + 32896 * 4 + 512 * 4; // 142080 B
  hipFuncSetAttribute((const void*)k_tridiag,
                      hipFuncAttributeMaxDynamicSharedMemorySize, tridiag_lds);
  hipFuncSetAttribute((const void*)k_nsf,
                      hipFuncAttributeMaxDynamicSharedMemorySize, NSF_LDS);

  k_chan_stats<<<NCH, 256, 0, stream>>>(x, small);
  k_attention<<<1, 256, 0, stream>>>(w1, w2, kv, small);

  const int IT32 = 13; // it_sw <= 12 provably; fp32 path never needed past this

  for (int base = 0; base < NCH; base += (int)chunk) {
    int cc = (NCH - base < (int)chunk) ? (NCH - base) : (int)chunk;
    dim3 gsym(3, 1, cc);
    dim3 gproj(2, 2, cc);
    k_gram<<<gsym, 256, 0, stream>>>(x, bufA, base);
    k_tridiag<<<cc, 1024, tridiag_lds, stream>>>(bufA, small, base);
    k_bisect<<<cc, 64, 0, stream>>>(small, base, cc);
    k_x0<<<dim3(N, cc), 256, 0, stream>>>(small, bufA, base);
    for (int it = 0; it < NS_MAX; ++it) {
      const float* src = (it & 1) ? bufB : bufA;
      float* dst = (it & 1) ? bufA : bufB;
      if (it < IT32) {
        k_ns1<<<gsym, 256, 0, stream>>>(src, bufC, small, base, it);
        k_ns2<<<gsym, 256, 0, stream>>>(src, bufC, dst, small, base, it);
      }
      k_nsf<<<cc, 512, NSF_LDS, stream>>>(src, bufC, dst, small, base, it);
    }
    k_proj<<<gproj, 256, 0, stream>>>(bufA, bufB, x, bufC, small, base);
    k_accum<<<256, 256, 0, stream>>>(bufC, small + OFF_SUM, small + OFF_MAXHW, cc,
                                     base == 0 ? 1 : 0);
  }
  k_conv<<<256, 256, 0, stream>>>(small + OFF_SUM, small + OFF_MAXHW, cw, out);
}

// Round 11
// 5626.371 us; speedup vs baseline: 1.0302x; 1.0229x over previous
//
#include <hip/hip_runtime.h>

// ============================================================================
// AFAR: channel-attention -> per-channel truncated-SVD recon -> spatial attn.
// A_k = P*A, P = step(G - t), G = A*A^T. t from mixed-precision Householder
// tridiag + fp64 Sturm multisection. Projector via polar-express schedule;
// late iterations (certified margin l >= 0.02) run as f16 MFMA GEMMs.
// R16 = R12 exact revert (measured best, 5575 us). The R13-R15 fused-NS arc
// concluded NEGATIVE: one-block-per-channel fusion caps at 8 waves/CU (135KB
// LDS) and serializes S->Y inside the block, losing to the two-dispatch
// k_nsh path (12 waves/CU, cross-channel phase overlap) by ~180-220 us.
// k_tridiag: 1024 thr = 4 column-groups x 256 rows, 5-barrier overlapped
// schedule (raw-x matvec merged with sigma, redundant K reduction), f64
// matvec, f32 rank-2 update, compact packed triangle.
// ============================================================================

#define NCH 256
#define N 256
#define NN 65536
#define NS_MAX 22

// small-region float offsets inside d_ws (double regions 8B-aligned)
#define OFF_K 0          // int[256]
#define OFF_MODE 256     // int[256]: 0 -> A_k=0, 1 -> A_k=A, 2 -> project
#define OFF_MC 512       // int[256]
#define OFF_COEF 768     // float[256][2*NS_MAX]
#define OFF_SUM 12032    // float[65536]
#define OFF_MAXHW 77568  // float[65536]
#define OFF_MEAND 143104 // double[256]
#define OFF_MAXD 143616  // double[256]
#define OFF_T 144128     // double[256]
#define OFF_ALPHA 144640 // double[256]
#define OFF_AQ 145152    // double[256][256]
#define OFF_BQ 276224    // double[256][256]
#define OFF_ITSW 407296  // int[256]: first iteration index safe for f16 MFMA
#define SMALL_FLOATS 407552

#define NSH_LDS 135168   // 2 panels x 128 rows x (256+8) f16
#define F16_PANEL 33792  // 128*264 u16 elements

static const float EPSF = 2.220446049250313e-16f;

typedef unsigned short u16;
typedef _Float16 h8 __attribute__((ext_vector_type(8)));
typedef float f32x4 __attribute__((ext_vector_type(4)));

__device__ __forceinline__ float rdlane(float v, int l) {
  return __uint_as_float(__builtin_amdgcn_readlane(__float_as_uint(v), l));
}

__device__ __forceinline__ u16 f2h(float v) {
  _Float16 h = (_Float16)v;
  u16 u;
  __builtin_memcpy(&u, &h, 2);
  return u;
}
__device__ __forceinline__ float h2f(u16 u) {
  _Float16 h;
  __builtin_memcpy(&h, &u, 2);
  return (float)h;
}

// ---------------------------------------------------------------------------
// 1) per-channel mean & max over H*W (fp64 sum)
// ---------------------------------------------------------------------------
__global__ __launch_bounds__(256) void k_chan_stats(const float* __restrict__ x,
                                                    float* __restrict__ small) {
  int c = blockIdx.x, tid = threadIdx.x;
  const float4* xc = (const float4*)(x + (size_t)c * NN);
  double s = 0.0;
  float m = -1e30f;
  for (int i = tid; i < NN / 4; i += 256) {
    float4 v = xc[i];
    s += (double)v.x + (double)v.y + (double)v.z + (double)v.w;
    m = fmaxf(m, fmaxf(fmaxf(v.x, v.y), fmaxf(v.z, v.w)));
  }
  __shared__ double rs[4];
  __shared__ float rm[4];
  for (int off = 32; off; off >>= 1) {
    s += __shfl_down(s, off, 64);
    m = fmaxf(m, __shfl_down(m, off, 64));
  }
  if ((tid & 63) == 0) { rs[tid >> 6] = s; rm[tid >> 6] = m; }
  __syncthreads();
  if (tid == 0) {
    ((double*)(small + OFF_MEAND))[c] = (rs[0] + rs[1] + rs[2] + rs[3]) / (double)NN;
    ((double*)(small + OFF_MAXD))[c] =
        (double)fmaxf(fmaxf(rm[0], rm[1]), fmaxf(rm[2], rm[3]));
  }
}

// ---------------------------------------------------------------------------
// 2) shared-MLP channel attention (fp64) -> gates yc -> k_c, mode_c
// ---------------------------------------------------------------------------
__global__ __launch_bounds__(256) void k_attention(const float* __restrict__ w1,
                                                   const float* __restrict__ w2,
                                                   const int* __restrict__ kvp,
                                                   float* __restrict__ small) {
  int tid = threadIdx.x;
  __shared__ double ha[16], hm[16], redd[8], ymn[256], ymx[256];
  double va = ((const double*)(small + OFF_MEAND))[tid];
  double vm = ((const double*)(small + OFF_MAXD))[tid];
  for (int r = 0; r < 16; ++r) {
    double wv = (double)w1[r * 256 + tid];
    double pa = wv * va, pm = wv * vm;
    for (int off = 32; off; off >>= 1) {
      pa += __shfl_down(pa, off, 64);
      pm += __shfl_down(pm, off, 64);
    }
    if ((tid & 63) == 0) { redd[tid >> 6] = pa; redd[4 + (tid >> 6)] = pm; }
    __syncthreads();
    if (tid == 0) {
      ha[r] = fmax(redd[0] + redd[1] + redd[2] + redd[3], 0.0);
      hm[r] = fmax(redd[4] + redd[5] + redd[6] + redd[7], 0.0);
    }
    __syncthreads();
  }
  double ya = 0.0, ym = 0.0;
  for (int r = 0; r < 16; ++r) {
    double wv = (double)w2[tid * 16 + r];
    ya += ha[r] * wv;
    ym += hm[r] * wv;
  }
  double y = 1.0 / (1.0 + exp(-(ya + ym)));
  ymn[tid] = y; ymx[tid] = y;
  __syncthreads();
  for (int off = 128; off; off >>= 1) {
    if (tid < off) {
      ymn[tid] = fmin(ymn[tid], ymn[tid + off]);
      ymx[tid] = fmax(ymx[tid], ymx[tid + off]);
    }
    __syncthreads();
  }
  double yc = (y - ymn[0]) / (ymx[0] - ymn[0] + 1e-20);
  int kv = kvp[0];
  int k = (int)floor(256.0 * (double)kv * yc);
  int mode = (k <= 0) ? 0 : ((k >= 256) ? 1 : 2);
  int* ip = (int*)small;
  ip[OFF_K + tid] = k;
  ip[OFF_MODE + tid] = mode;
}

// ---------------------------------------------------------------------------
// GEMM core: 128x128 tile, 256 threads, 8x8 micro-tile (2x2 quadrants of 4)
// ---------------------------------------------------------------------------
#define GEMM128_VARS                                                           \
  int tid = threadIdx.x;                                                       \
  int tx4 = (tid & 15) * 4, ty4 = (tid >> 4) * 4;                              \
  int lm = tid >> 1, lq = (tid & 1) * 2;                                       \
  int lk = tid >> 4, lc = (tid & 15) * 2;                                      \
  (void)lk; (void)lc;

#define STORE_T128(Ls, v0, v1)                                                 \
  Ls[lq * 4 + 0][lm] = v0.x; Ls[lq * 4 + 1][lm] = v0.y;                        \
  Ls[lq * 4 + 2][lm] = v0.z; Ls[lq * 4 + 3][lm] = v0.w;                        \
  Ls[lq * 4 + 4][lm] = v1.x; Ls[lq * 4 + 5][lm] = v1.y;                        \
  Ls[lq * 4 + 6][lm] = v1.z; Ls[lq * 4 + 7][lm] = v1.w;

#define GEMM128_INNER(AsM, BsM)                                                \
  _Pragma("unroll") for (int kk = 0; kk < 16; ++kk) {                          \
    float4 a0 = *(const float4*)&AsM[kk][ty4];                                 \
    float4 a1 = *(const float4*)&AsM[kk][64 + ty4];                            \
    float4 b0 = *(const float4*)&BsM[kk][tx4];                                 \
    float4 b1 = *(const float4*)&BsM[kk][64 + tx4];                            \
    float av[8] = {a0.x, a0.y, a0.z, a0.w, a1.x, a1.y, a1.z, a1.w};            \
    float bv[8] = {b0.x, b0.y, b0.z, b0.w, b1.x, b1.y, b1.z, b1.w};            \
    _Pragma("unroll") for (int rr = 0; rr < 8; ++rr)                           \
      _Pragma("unroll") for (int cc2 = 0; cc2 < 8; ++cc2)                      \
        acc[rr][cc2] += av[rr] * bv[cc2];                                      \
  }

#define WRITE_TILE_NORM(Cc)                                                    \
  _Pragma("unroll") for (int rh = 0; rh < 2; ++rh)                             \
  _Pragma("unroll") for (int rr = 0; rr < 4; ++rr) {                           \
    int rI = rh * 4 + rr;                                                      \
    float* rowp = (Cc) + (size_t)(i0 + rh * 64 + ty4 + rr) * N + j0;           \
    *(float4*)(rowp + tx4) =                                                   \
        make_float4(acc[rI][0], acc[rI][1], acc[rI][2], acc[rI][3]);           \
    *(float4*)(rowp + 64 + tx4) =                                              \
        make_float4(acc[rI][4], acc[rI][5], acc[rI][6], acc[rI][7]);           \
  }

#define WRITE_TILE_MIRROR(Cc)                                                  \
  _Pragma("unroll") for (int ch = 0; ch < 2; ++ch)                             \
  _Pragma("unroll") for (int cc2 = 0; cc2 < 4; ++cc2) {                        \
    int cI = ch * 4 + cc2;                                                     \
    float* rowp = (Cc) + (size_t)(j0 + ch * 64 + tx4 + cc2) * N + i0;          \
    *(float4*)(rowp + ty4) =                                                   \
        make_float4(acc[0][cI], acc[1][cI], acc[2][cI], acc[3][cI]);           \
    *(float4*)(rowp + 64 + ty4) =                                              \
        make_float4(acc[4][cI], acc[5][cI], acc[6][cI], acc[7][cI]);           \
  }

// sym block map: bx 0,1,2 -> (0,0),(1,0),(1,1)
#define SYM_MAP                                                                \
  int bx = blockIdx.x;                                                         \
  int i0 = (bx >= 1) ? 128 : 0, j0 = (bx == 2) ? 128 : 0;

// 3) G = A*A^T per channel (lower tiles + mirror)
__global__ __launch_bounds__(256) void k_gram(const float* __restrict__ x,
                                              float* __restrict__ bufA, int base) {
  __shared__ float As[16][132], Bs[16][132];
  GEMM128_VARS; SYM_MAP;
  const float* A = x + (size_t)(base + blockIdx.z) * NN;
  float acc[8][8] = {};
  const float* Ap = A + (size_t)(i0 + lm) * N + lq * 4;
  const float* Bp = A + (size_t)(j0 + lm) * N + lq * 4;
  float4 va0 = *(const float4*)Ap, va1 = *(const float4*)(Ap + 4);
  float4 vb0 = *(const float4*)Bp, vb1 = *(const float4*)(Bp + 4);
  for (int kt = 0; kt < 16; ++kt) {
    __syncthreads();
    STORE_T128(As, va0, va1); STORE_T128(Bs, vb0, vb1);
    __syncthreads();
    if (kt < 15) {
      va0 = *(const float4*)(Ap + (kt + 1) * 16);
      va1 = *(const float4*)(Ap + (kt + 1) * 16 + 4);
      vb0 = *(const float4*)(Bp + (kt + 1) * 16);
      vb1 = *(const float4*)(Bp + (kt + 1) * 16 + 4);
    }
    GEMM128_INNER(As, Bs);
  }
  float* Cc = bufA + (size_t)blockIdx.z * NN;
  WRITE_TILE_NORM(Cc);
  if (bx == 1) { WRITE_TILE_MIRROR(Cc); }
}

// ---------------------------------------------------------------------------
// tridiag helpers: per-chunk matvec (f64 acc) and rank-2 update (f32).
// c0 is 64-aligned and wave-uniform; R0 is the wave's row-block base.
// ---------------------------------------------------------------------------
__device__ __forceinline__ double mv_chunk(const float* __restrict__ P, int c0,
                                           int j, int r, int R0, int triR,
                                           float ureg) {
  double pi0 = 0.0, pi1 = 0.0, pi2 = 0.0, pi3 = 0.0;
  if (c0 < N) {
    int lbeg = (c0 > j + 1) ? c0 : (j + 1);
    int lend = c0 + 64;
    if (lbeg < lend) {
      if (c0 + 64 <= R0) {
        // class A: all l < r -> row-contiguous triR+lmv (no select)
        int lmv = lbeg;
        for (; lmv + 3 < lend; lmv += 4) {
          float uv0 = rdlane(ureg, lmv - c0), uv1 = rdlane(ureg, lmv + 1 - c0);
          float uv2 = rdlane(ureg, lmv + 2 - c0), uv3 = rdlane(ureg, lmv + 3 - c0);
          float v0 = P[triR + lmv], v1 = P[triR + lmv + 1];
          float v2 = P[triR + lmv + 2], v3 = P[triR + lmv + 3];
          pi0 += (double)v0 * (double)uv0;
          pi1 += (double)v1 * (double)uv1;
          pi2 += (double)v2 * (double)uv2;
          pi3 += (double)v3 * (double)uv3;
        }
        for (; lmv < lend; ++lmv)
          pi0 += (double)P[triR + lmv] * (double)rdlane(ureg, lmv - c0);
      } else if (c0 >= R0 + 64) {
        // class C: all l > r -> s(l)+r, incremental s (no select)
        int lmv = lbeg;
        int s = (lmv * (lmv + 1)) >> 1;
        for (; lmv + 3 < lend; lmv += 4) {
          int s0 = s, s1 = s0 + lmv + 1, s2 = s1 + lmv + 2, s3 = s2 + lmv + 3;
          s = s3 + lmv + 4;
          float uv0 = rdlane(ureg, lmv - c0), uv1 = rdlane(ureg, lmv + 1 - c0);
          float uv2 = rdlane(ureg, lmv + 2 - c0), uv3 = rdlane(ureg, lmv + 3 - c0);
          pi0 += (double)P[s0 + r] * (double)uv0;
          pi1 += (double)P[s1 + r] * (double)uv1;
          pi2 += (double)P[s2 + r] * (double)uv2;
          pi3 += (double)P[s3 + r] * (double)uv3;
        }
        for (; lmv < lend; ++lmv) {
          pi0 += (double)P[s + r] * (double)rdlane(ureg, lmv - c0);
          s += lmv + 1;
        }
      } else {
        // class B: diagonal chunk, per-element select
        int lmv = lbeg;
        int s = (lmv * (lmv + 1)) >> 1;
        for (; lmv < lend; ++lmv) {
          float uv = rdlane(ureg, lmv - c0);
          float v = P[(lmv <= r) ? (triR + lmv) : (s + r)];
          pi0 += (double)v * (double)uv;
          s += lmv + 1;
        }
      }
    }
  }
  return (pi0 + pi1) + (pi2 + pi3);
}

__device__ __forceinline__ void upd_chunk(float* __restrict__ P, int c0, int j,
                                          int r, int R0, int triR, float ureg,
                                          float wreg, float urf, float wrf) {
  if (c0 >= N) return;
  int lbeg = (c0 > j + 1) ? c0 : (j + 1);
  int lend = c0 + 64;
  int lcap = (r | 63) + 1; // wave-uniform cap
  if (lend > lcap) lend = lcap;
  if (c0 + 64 <= R0) {
    // class A: full range, all l < r, contiguous
    int lmv = lbeg;
    for (; lmv + 1 < lend; lmv += 2) {
      float uv0 = rdlane(ureg, lmv - c0), wv0 = rdlane(wreg, lmv - c0);
      float uv1 = rdlane(ureg, lmv + 1 - c0), wv1 = rdlane(wreg, lmv + 1 - c0);
      P[triR + lmv] = fmaf(-wrf, uv0, fmaf(-urf, wv0, P[triR + lmv]));
      P[triR + lmv + 1] = fmaf(-wrf, uv1, fmaf(-urf, wv1, P[triR + lmv + 1]));
    }
    if (lmv < lend) {
      float uv0 = rdlane(ureg, lmv - c0), wv0 = rdlane(wreg, lmv - c0);
      P[triR + lmv] = fmaf(-wrf, uv0, fmaf(-urf, wv0, P[triR + lmv]));
    }
  } else if (c0 == R0) {
    // class B: diagonal chunk, per-lane cap
    for (int lmv = lbeg; lmv < lend; ++lmv) {
      float uv = rdlane(ureg, lmv - c0), wv = rdlane(wreg, lmv - c0);
      if (lmv <= r)
        P[triR + lmv] = fmaf(-wrf, uv, fmaf(-urf, wv, P[triR + lmv]));
    }
  }
  // c0 >= R0+64: lend <= lcap = R0+64 <= c0 < lbeg -> empty
}

// ---------------------------------------------------------------------------
// 4) Householder tridiag: 1024 threads = 4 column-groups x 256 rows (one
//    64-column chunk per group; 16 waves = 4/SIMD for latency hiding) with
//    the 5-barrier overlapped schedule: matvec with RAW column x merged into
//    the sigma phase (fixup p = p' - bsub*P(:,j+1)), merged K reduction
//    computed redundantly by all groups (0.25-weighted). f64 matvec, f32
//    rank-2 update.
// ---------------------------------------------------------------------------
__global__ __launch_bounds__(1024) void k_tridiag(const float* __restrict__ Gall,
                                                  float* __restrict__ small, int base) {
  extern __shared__ double dls[];
  double* redd = dls;              // 16 (sigma partials)
  double* redd2 = dls + 16;        // 16 (K partials)
  double* pip = dls + 32;          // 1024
  float* P = (float*)(dls + 1056); // 32896 packed lower triangle
  float* uf = P + 32896;           // 256
  float* wf = uf + 256;            // 256 (f32 w for the update)
  int tid = threadIdx.x, lane = tid & 63;
  int r = tid & 255, g = tid >> 8; // g in {0..3}
  int wid = tid >> 6;              // 0..15
  int R0 = (wid & 3) << 6;         // wave row-block base (r = R0 + lane)
  int c = base + blockIdx.x;
  const int* ip = (const int*)small;
  if (ip[OFF_MODE + c] != 2) return;
  const float* G = Gall + (size_t)blockIdx.x * NN;
  double* aq = (double*)(small + OFF_AQ) + (size_t)c * 256;
  double* bq = (double*)(small + OFF_BQ) + (size_t)c * 256;
  const int triR = (r * (r + 1)) >> 1;

  for (int i = g; i < N; i += 4)
    if (r <= i) P[((i * (i + 1)) >> 1) + r] = G[i * N + r];
  __syncthreads();

  for (int j = 0; j + 2 < N; ++j) {
    // phase 1: column j -> uf
    if (g == 0 && r >= j + 1) uf[r] = P[triR + j];
    __syncthreads(); // B1
    float x_r = uf[r];                 // valid for r >= j+1
    double x0 = (double)uf[j + 1];
    int cbase = (j + 1) & ~63;
    int c0 = cbase + 64 * g;           // wave-uniform
    float ureg = 0.f;
    if (c0 < N) ureg = uf[c0 + lane];  // uniform cond: rdlane source
    // phase 2 (merged): sigma partial + matvec p' = P*x (raw column)
    double sp = (g == 0 && r >= j + 2) ? (double)x_r * (double)x_r : 0.0;
    double myp = mv_chunk(P, c0, j, r, R0, triR, ureg);
    pip[tid] = (r >= j + 1) ? myp : 0.0;
    for (int off = 32; off; off >>= 1) sp += __shfl_down(sp, off, 64);
    if (lane == 0) redd[wid] = sp;
    __syncthreads(); // B2
    double sigma = (((redd[0] + redd[1]) + (redd[2] + redd[3])) +
                    ((redd[4] + redd[5]) + (redd[6] + redd[7]))) +
                   (((redd[8] + redd[9]) + (redd[10] + redd[11])) +
                    ((redd[12] + redd[13]) + (redd[14] + redd[15])));
    if (sigma <= 1e-40) { // column already tridiagonal
      if (tid == 0) bq[j] = x0;
      continue; // B2 (this iter) orders reads before next iter's B1 writes
    }
    double nu = sqrt(x0 * x0 + sigma);
    double bsub = (x0 >= 0.0) ? -nu : nu;
    double beta = 1.0 / (nu * (nu + fabs(x0)));
    // patch u register at the column-(j+1) slot (self-register write)
    if (c0 <= j + 1 && j + 1 < c0 + 64 && lane == j + 1 - c0)
      ureg = (float)(x0 - bsub);
    // phase 3: pi_r with fixup (all groups redundantly) + K partial
    double pi = 0.0, u_r = 0.0, kp = 0.0;
    if (r >= j + 1) {
      double fix = -bsub * (double)P[triR + (j + 1)];
      pi = (pip[r] + pip[256 + r] + pip[512 + r] + pip[768 + r] + fix) * beta;
      u_r = (r == j + 1) ? (x0 - bsub) : (double)x_r;
      kp = u_r * pi * 0.25; // 0.25: four groups quadruple-count
    }
    for (int off = 32; off; off >>= 1) kp += __shfl_down(kp, off, 64);
    if (lane == 0) redd2[wid] = kp;
    __syncthreads(); // B3
    double K = ((((redd2[0] + redd2[1]) + (redd2[2] + redd2[3])) +
                 ((redd2[4] + redd2[5]) + (redd2[6] + redd2[7]))) +
                (((redd2[8] + redd2[9]) + (redd2[10] + redd2[11])) +
                 ((redd2[12] + redd2[13]) + (redd2[14] + redd2[15])))) *
               beta * 0.5;
    if (g == 0 && r >= j + 1) wf[r] = (float)(pi - K * u_r);
    __syncthreads(); // B4
    float wreg = 0.f;
    if (c0 < N) wreg = wf[c0 + lane]; // uniform cond: rdlane source
    // phase 4: rank-2 update (f32)
    if (r >= j + 1) {
      float urf = (float)u_r;
      float wrf = wf[r];
      upd_chunk(P, c0, j, r, R0, triR, ureg, wreg, urf, wrf);
    }
    if (tid == 0) bq[j] = bsub;
    __syncthreads(); // B5
  }
  if (g == 0) aq[r] = (double)P[triR + r];
  if (tid == 0) bq[N - 2] = (double)P[(((N - 1) * N) >> 1) + N - 2];
}

// ---------------------------------------------------------------------------
// 5) fp64 Sturm 64-way multisection -> t, alpha, polar-express schedule,
//    and per-channel it_sw (first iteration with margin l >= 0.02, safe for
//    f16 MFMA: f16 spectral perturbation ~5e-4, 20-40x margin).
// ---------------------------------------------------------------------------
__device__ __forceinline__ int sturm_count_lds(const double* a, const double* b,
                                               double t) {
  double d = a[0] - t;
  int cnt = (d < 0.0);
  for (int i = 1; i < N; ++i) {
    double den = d;
    if (fabs(den) < 1e-20) den = (den < 0.0) ? -1e-20 : 1e-20;
    double bb = b[i - 1];
    d = (a[i] - t) - bb * bb / den;
    cnt += (d < 0.0);
  }
  return cnt; // #{eig < t}
}

__global__ __launch_bounds__(64) void k_bisect(float* __restrict__ small,
                                               int base, int cc) {
  int ci = blockIdx.x;
  if (ci >= cc) return;
  int c = base + ci, lane = threadIdx.x;
  int* ip = (int*)small;
  if (ip[OFF_MODE + c] != 2) {
    if (lane == 0) { ip[OFF_MC + c] = 0; ip[OFF_ITSW + c] = 0; }
    return;
  }
  int k = ip[OFF_K + c];
  const double* a = (const double*)(small + OFF_AQ) + (size_t)c * 256;
  const double* b = (const double*)(small + OFF_BQ) + (size_t)c * 256;
  __shared__ double sa[256], sb[256];
  for (int i = lane; i < N; i += 64) {
    sa[i] = a[i];
    if (i < N - 1) sb[i] = b[i];
  }
  __syncthreads();
  // Gershgorin bounds (wave-parallel)
  double lo = 1e300, hi = -1e300;
  for (int i = lane; i < N; i += 64) {
    double rr = (i > 0 ? fabs(sb[i - 1]) : 0.0) + (i < N - 1 ? fabs(sb[i]) : 0.0);
    lo = fmin(lo, sa[i] - rr);
    hi = fmax(hi, sa[i] + rr);
  }
  for (int off = 32; off; off >>= 1) {
    lo = fmin(lo, __shfl_xor(lo, off, 64));
    hi = fmax(hi, __shfl_xor(hi, off, 64));
  }
  double lamk = 0.0, lamk1 = 0.0;
  for (int which = 0; which < 2; ++which) {
    int j = (which == 0) ? (N - k + 1) : (N - k); // ascending index of mu_j
    double l0 = lo, h0 = hi;
    for (int pass = 0; pass < 10; ++pass) {
      double step = (h0 - l0) * (1.0 / 65.0);
      double t = l0 + step * (double)(lane + 1);
      int cnt = sturm_count_lds(sa, sb, t);
      unsigned long long mask = __ballot(cnt >= j);
      if (mask == 0ull) {
        l0 = l0 + step * 64.0; // mu_j above all probes
      } else {
        int bpos = __ffsll((long long)mask) - 1; // first probe with cnt>=j
        double nl = (bpos == 0) ? l0 : (l0 + step * (double)bpos);
        h0 = l0 + step * (double)(bpos + 1);
        l0 = nl;
      }
    }
    double v = 0.5 * (l0 + h0);
    if (which == 0) lamk = v; else lamk1 = v;
  }
  if (lane == 0) {
    double t = 0.5 * (lamk + lamk1);
    double gap = fmax(lamk - lamk1, 0.0);
    double alpha = 1.002 * fmax(hi - t, t - lo) + 1e-30;
    double g0 = fmax(gap / (2.0 * alpha), 2e-6);
    // polar-express schedule: equioscillation cubic per iteration
    float* cf = small + OFF_COEF + (size_t)c * (2 * NS_MAX);
    double l = fmin(g0, 0.99);
    int m = 0, isw = NS_MAX;
    while (m < NS_MAX - 2 && l < 0.9999) {
      if (isw == NS_MAX && l >= 0.02) isw = m;
      double aa = sqrt(27.0 / (4.0 * (1.0 + l + l * l)));
      double bb = (4.0 / 27.0) * aa * aa * aa;
      cf[2 * m] = (float)aa;
      cf[2 * m + 1] = (float)bb;
      double pl = aa * l - bb * l * l * l;
      double p1 = aa - bb;
      l = fmin(pl, p1);
      m++;
    }
    for (int e = 0; e < 2; ++e) {
      if (isw == NS_MAX && l >= 0.02) isw = m;
      cf[2 * m] = 1.5f; cf[2 * m + 1] = 0.5f; m++;
    }
    if (isw > m) isw = m;
    ip[OFF_MC + c] = m;
    ip[OFF_ITSW + c] = isw;
    ((double*)(small + OFF_T))[c] = t;
    ((double*)(small + OFF_ALPHA))[c] = alpha;
  }
}

// 6) X0 = (G - t*I)/alpha (in place on bufA, fp64 scale)
__global__ void k_x0(const float* __restrict__ small, float* __restrict__ bufA,
                     int base) {
  int ci = blockIdx.y, c = base + ci;
  const int* ip = (const int*)small;
  if (ip[OFF_MODE + c] != 2) return;
  double t = ((const double*)(small + OFF_T))[c];
  double inva = 1.0 / ((const double*)(small + OFF_ALPHA))[c];
  float* X = bufA + (size_t)ci * NN;
  int r = blockIdx.x, tid = threadIdx.x;
  double gg = (double)X[r * N + tid];
  if (tid == r) gg -= t;
  X[r * N + tid] = (float)(gg * inva);
}

// 7a) S = X*X (X symmetric; lower tiles + mirror) -- fp32 path (it < it_sw)
__global__ __launch_bounds__(256) void k_ns1(const float* __restrict__ src,
                                             float* __restrict__ Sb,
                                             const float* __restrict__ small,
                                             int base, int it) {
  const int* ip = (const int*)small;
  int c = base + blockIdx.z;
  if (ip[OFF_MODE + c] != 2 || it >= ip[OFF_ITSW + c]) return;
  __shared__ float As[16][132], Bs[16][132];
  GEMM128_VARS; SYM_MAP;
  const float* X = src + (size_t)blockIdx.z * NN;
  float acc[8][8] = {};
  const float* Ap = X + (size_t)(i0 + lm) * N + lq * 4;
  const float* Bp = X + (size_t)(j0 + lm) * N + lq * 4;
  float4 va0 = *(const float4*)Ap, va1 = *(const float4*)(Ap + 4);
  float4 vb0 = *(const float4*)Bp, vb1 = *(const float4*)(Bp + 4);
  for (int kt = 0; kt < 16; ++kt) {
    __syncthreads();
    STORE_T128(As, va0, va1); STORE_T128(Bs, vb0, vb1);
    __syncthreads();
    if (kt < 15) {
      va0 = *(const float4*)(Ap + (kt + 1) * 16);
      va1 = *(const float4*)(Ap + (kt + 1) * 16 + 4);
      vb0 = *(const float4*)(Bp + (kt + 1) * 16);
      vb1 = *(const float4*)(Bp + (kt + 1) * 16 + 4);
    }
    GEMM128_INNER(As, Bs);
  }
  float* Cc = Sb + (size_t)blockIdx.z * NN;
  WRITE_TILE_NORM(Cc);
  if (bx == 1) { WRITE_TILE_MIRROR(Cc); }
}

// 7b) Y = a*X - b*X*S (commuting symmetric -> Y symmetric; tiles + mirror)
__global__ __launch_bounds__(256) void k_ns2(const float* __restrict__ src,
                                             const float* __restrict__ Sb,
                                             float* __restrict__ dst,
                                             const float* __restrict__ small,
                                             int base, int it) {
  const int* ip = (const int*)small;
  int c = base + blockIdx.z;
  if (ip[OFF_MODE + c] != 2 || it >= ip[OFF_ITSW + c]) return;
  float ca = small[OFF_COEF + (size_t)c * (2 * NS_MAX) + 2 * it];
  float cb = small[OFF_COEF + (size_t)c * (2 * NS_MAX) + 2 * it + 1];
  __shared__ float As[16][132], Bs[16][132];
  GEMM128_VARS; SYM_MAP;
  const float* X = src + (size_t)blockIdx.z * NN;
  const float* S = Sb + (size_t)blockIdx.z * NN;
  float acc[8][8] = {};
  const float* Ap = X + (size_t)(i0 + lm) * N + lq * 4;
  const float* Bp = S + (size_t)(j0 + lm) * N + lq * 4;
  float4 va0 = *(const float4*)Ap, va1 = *(const float4*)(Ap + 4);
  float4 vb0 = *(const float4*)Bp, vb1 = *(const float4*)(Bp + 4);
  for (int kt = 0; kt < 16; ++kt) {
    __syncthreads();
    STORE_T128(As, va0, va1); STORE_T128(Bs, vb0, vb1);
    __syncthreads();
    if (kt < 15) {
      va0 = *(const float4*)(Ap + (kt + 1) * 16);
      va1 = *(const float4*)(Ap + (kt + 1) * 16 + 4);
      vb0 = *(const float4*)(Bp + (kt + 1) * 16);
      vb1 = *(const float4*)(Bp + (kt + 1) * 16 + 4);
    }
    GEMM128_INNER(As, Bs);
  }
  // acc <- ca*X - cb*acc (transform in place, then write norm + mirror)
#pragma unroll
  for (int rh = 0; rh < 2; ++rh)
#pragma unroll
    for (int rr = 0; rr < 4; ++rr) {
      int rI = rh * 4 + rr;
      const float* rowp = X + (size_t)(i0 + rh * 64 + ty4 + rr) * N + j0;
      float4 x0 = *(const float4*)(rowp + tx4);
      float4 x1 = *(const float4*)(rowp + 64 + tx4);
      acc[rI][0] = ca * x0.x - cb * acc[rI][0];
      acc[rI][1] = ca * x0.y - cb * acc[rI][1];
      acc[rI][2] = ca * x0.z - cb * acc[rI][2];
      acc[rI][3] = ca * x0.w - cb * acc[rI][3];
      acc[rI][4] = ca * x1.x - cb * acc[rI][4];
      acc[rI][5] = ca * x1.y - cb * acc[rI][5];
      acc[rI][6] = ca * x1.z - cb * acc[rI][6];
      acc[rI][7] = ca * x1.w - cb * acc[rI][7];
    }
  float* Y = dst + (size_t)blockIdx.z * NN;
  WRITE_TILE_NORM(Y);
  if (bx == 1) { WRITE_TILE_MIRROR(Y); }
}

// ---------------------------------------------------------------------------
// panel staging helpers: 128x256 f16 panel in LDS, 264-elem padded rows
// (16B pad per 512B row -> bank rotation). Source either f16 image or fp32
// (converted in-flight at it == it_sw).
// ---------------------------------------------------------------------------
__device__ __forceinline__ void stage_h(u16* pan, const u16* g16, int tid) {
#pragma unroll
  for (int i = 0; i < 16; ++i) {
    int g = tid * 16 + i * 4096;          // byte offset in 64KB panel
    int lo = g + ((g >> 9) << 4);
    *(uint4*)((char*)pan + lo) = *(const uint4*)((const char*)g16 + g);
  }
}
__device__ __forceinline__ void stage_f(u16* pan, const float* gF, int tid) {
#pragma unroll
  for (int i = 0; i < 16; ++i) {
    int e = tid * 8 + i * 2048;           // f16-element offset
    float4 v0 = *(const float4*)(gF + e);
    float4 v1 = *(const float4*)(gF + e + 4);
    h8 hv;
    hv[0] = (_Float16)v0.x; hv[1] = (_Float16)v0.y;
    hv[2] = (_Float16)v0.z; hv[3] = (_Float16)v0.w;
    hv[4] = (_Float16)v1.x; hv[5] = (_Float16)v1.y;
    hv[6] = (_Float16)v1.z; hv[7] = (_Float16)v1.w;
    int b = e * 2;
    int lo = b + ((b >> 9) << 4);
    *(h8*)((char*)pan + lo) = hv;
  }
}

// ---------------------------------------------------------------------------
// 7d) f16 MFMA NS step (it_sw <= it < mc). phase 0: S = X*X -> f16 alias of
//     the channel's Sf slot. phase 1: Y = ca*X - cb*X*S -> f16 alias of the
//     dst slot (final iteration writes full fp32 Y instead; race-free).
// ---------------------------------------------------------------------------
__global__ __launch_bounds__(256) void k_nsh(const float* __restrict__ srcF,
                                             float* __restrict__ Sf,
                                             float* __restrict__ dstF,
                                             const float* __restrict__ small,
                                             int base, int it, int phase) {
  const int* ip = (const int*)small;
  int ci = blockIdx.z, c = base + ci;
  if (ip[OFF_MODE + c] != 2) return;
  int isw = ip[OFF_ITSW + c], mc = ip[OFF_MC + c];
  if (it < isw || it >= mc) return;
  SYM_MAP;
  extern __shared__ char ldsraw[];
  u16* Apan = (u16*)ldsraw;
  u16* Bpan = Apan + F16_PANEL;
  int tid = threadIdx.x;
  bool cvtA = (it == isw);                 // stage X from fp32, convert
  bool sameP = (phase == 0) && (bx != 1);  // diag block of S=X*X: one panel
  const float* XF = srcF + (size_t)ci * NN;
  const u16* XH = (const u16*)XF;          // f16 alias (first half of slot)
  if (cvtA) stage_f(Apan, XF + (size_t)i0 * N, tid);
  else      stage_h(Apan, XH + (size_t)i0 * N, tid);
  if (!sameP) {
    if (phase == 0) {
      if (cvtA) stage_f(Bpan, XF + (size_t)j0 * N, tid);
      else      stage_h(Bpan, XH + (size_t)j0 * N, tid);
    } else {
      const u16* SH = (const u16*)(Sf + (size_t)ci * NN);
      stage_h(Bpan, SH + (size_t)j0 * N, tid);
    }
  }
  const u16* Bb = sameP ? Apan : Bpan;
  __syncthreads();

  int l = tid & 63, wid = tid >> 6;
  int wr = (wid >> 1) * 64, wc = (wid & 1) * 64; // wave's 64x64 sub-tile
  int rA = wr + (l & 15), rB = wc + (l & 15);
  int kB = (l >> 4) << 3;
  f32x4 zero = {0.f, 0.f, 0.f, 0.f};
  f32x4 acc[4][4];
#pragma unroll
  for (int mi = 0; mi < 4; ++mi)
#pragma unroll
    for (int ni = 0; ni < 4; ++ni) acc[mi][ni] = zero;

#pragma unroll
  for (int kc = 0; kc < 8; ++kc) {
    int kof = kc * 32 + kB; // f16 element offset within row
    h8 af[4], bf[4];
#pragma unroll
    for (int mi = 0; mi < 4; ++mi)
      af[mi] = *(const h8*)((const char*)Apan +
                            ((size_t)(rA + mi * 16) * 264 + kof) * 2);
#pragma unroll
    for (int ni = 0; ni < 4; ++ni)
      bf[ni] = *(const h8*)((const char*)Bb +
                            ((size_t)(rB + ni * 16) * 264 + kof) * 2);
#pragma unroll
    for (int mi = 0; mi < 4; ++mi)
#pragma unroll
      for (int ni = 0; ni < 4; ++ni)
        acc[mi][ni] = __builtin_amdgcn_mfma_f32_16x16x32_f16(
            af[mi], bf[ni], acc[mi][ni], 0, 0, 0);
  }

  float cav = 0.f, cbv = 0.f;
  bool last = false;
  if (phase) {
    cav = small[OFF_COEF + (size_t)c * (2 * NS_MAX) + 2 * it];
    cbv = small[OFF_COEF + (size_t)c * (2 * NS_MAX) + 2 * it + 1];
    last = (it == mc - 1);
  }
  float* oF = dstF + (size_t)ci * NN;
  u16* oH = phase ? (u16*)oF : (u16*)(Sf + (size_t)ci * NN);
  int lr4 = (l >> 4) << 2, lcn = l & 15;
  // C/D layout (m89-verified): col = lane&15, row = (lane>>4)*4 + reg
#pragma unroll
  for (int mi = 0; mi < 4; ++mi)
#pragma unroll
    for (int ni = 0; ni < 4; ++ni)
#pragma unroll
      for (int rg = 0; rg < 4; ++rg) {
        int gr = i0 + wr + mi * 16 + lr4 + rg;
        int gc = j0 + wc + ni * 16 + lcn;
        float v = acc[mi][ni][rg];
        if (phase) {
          float xv = h2f(Apan[(size_t)(gr - i0) * 264 + gc]);
          v = cav * xv - cbv * v;
        }
        if (!last) { // f16 store (skipped on final iter: aliases oF region)
          u16 hv = f2h(v);
          oH[(size_t)gr * N + gc] = hv;
          if (bx == 1) oH[(size_t)gc * N + gr] = hv;
        } else {
          oF[(size_t)gr * N + gc] = v;
          if (bx == 1) oF[(size_t)gc * N + gr] = v;
        }
      }
}

// 8) A_k = 0.5*(sign(X)*A + A) (modes: 0 -> zeros, 1 -> copy A)
__global__ __launch_bounds__(256) void k_proj(const float* __restrict__ bufA,
                                              const float* __restrict__ bufB,
                                              const float* __restrict__ x,
                                              float* __restrict__ bufC,
                                              const float* __restrict__ small,
                                              int base) {
  const int* ip = (const int*)small;
  int ci = blockIdx.z, c = base + ci;
  int mode = ip[OFF_MODE + c];
  GEMM128_VARS;
  int i0 = blockIdx.x * 128, j0 = blockIdx.y * 128;
  float* Cc = bufC + (size_t)ci * NN;
  const float* xc = x + (size_t)c * NN;
  if (mode != 2) {
#pragma unroll
    for (int rh = 0; rh < 2; ++rh)
#pragma unroll
      for (int rr = 0; rr < 4; ++rr) {
        size_t ro = (size_t)(i0 + rh * 64 + ty4 + rr) * N + j0;
        if (mode == 0) {
          *(float4*)(Cc + ro + tx4) = make_float4(0.f, 0.f, 0.f, 0.f);
          *(float4*)(Cc + ro + 64 + tx4) = make_float4(0.f, 0.f, 0.f, 0.f);
        } else {
          *(float4*)(Cc + ro + tx4) = *(const float4*)(xc + ro + tx4);
          *(float4*)(Cc + ro + 64 + tx4) = *(const float4*)(xc + ro + 64 + tx4);
        }
      }
    return;
  }
  int mc = ip[OFF_MC + c];
  const float* Xh = ((mc & 1) ? bufB : bufA) + (size_t)ci * NN;
  __shared__ float As[16][132], Bs[16][132];
  float acc[8][8] = {};
  const float* Ap = Xh + (size_t)(i0 + lm) * N + lq * 4;
  const float* Bp = xc + (size_t)lk * N + j0 + lc * 4;
  float4 va0 = *(const float4*)Ap, va1 = *(const float4*)(Ap + 4);
  float4 vb0 = *(const float4*)Bp, vb1 = *(const float4*)(Bp + 4);
  for (int kt = 0; kt < 16; ++kt) {
    __syncthreads();
    STORE_T128(As, va0, va1);
    *(float4*)&Bs[lk][lc * 4] = vb0;
    *(float4*)&Bs[lk][(lc + 1) * 4] = vb1;
    __syncthreads();
    if (kt < 15) {
      va0 = *(const float4*)(Ap + (kt + 1) * 16);
      va1 = *(const float4*)(Ap + (kt + 1) * 16 + 4);
      const float* Bp2 = xc + (size_t)((kt + 1) * 16 + lk) * N + j0 + lc * 4;
      vb0 = *(const float4*)Bp2;
      vb1 = *(const float4*)(Bp2 + 4);
    }
    GEMM128_INNER(As, Bs);
  }
#pragma unroll
  for (int rh = 0; rh < 2; ++rh)
#pragma unroll
    for (int rr = 0; rr < 4; ++rr) {
      int rI = rh * 4 + rr;
      const float* rowp = xc + (size_t)(i0 + rh * 64 + ty4 + rr) * N + j0;
      float4 x0 = *(const float4*)(rowp + tx4);
      float4 x1 = *(const float4*)(rowp + 64 + tx4);
      acc[rI][0] = 0.5f * (acc[rI][0] + x0.x);
      acc[rI][1] = 0.5f * (acc[rI][1] + x0.y);
      acc[rI][2] = 0.5f * (acc[rI][2] + x0.z);
      acc[rI][3] = 0.5f * (acc[rI][3] + x0.w);
      acc[rI][4] = 0.5f * (acc[rI][4] + x1.x);
      acc[rI][5] = 0.5f * (acc[rI][5] + x1.y);
      acc[rI][6] = 0.5f * (acc[rI][6] + x1.z);
      acc[rI][7] = 0.5f * (acc[rI][7] + x1.w);
    }
  WRITE_TILE_NORM(Cc);
}

// 9) accumulate sum & max over channels
__global__ void k_accum(const float* __restrict__ bufC, float* __restrict__ sum_hw,
                        float* __restrict__ max_hw, int cc, int first) {
  int p = blockIdx.x * 256 + threadIdx.x;
  float s = first ? 0.f : sum_hw[p];
  float m = first ? -1e30f : max_hw[p];
  for (int ci = 0; ci < cc; ++ci) {
    float v = bufC[(size_t)ci * NN + p];
    s += v;
    m = fmaxf(m, v);
  }
  sum_hw[p] = s;
  max_hw[p] = m;
}

// 10) 7x7 conv (pad 3) on [avg, max] -> clamp EPS -> sigmoid
__global__ void k_conv(const float* __restrict__ sum_hw, const float* __restrict__ max_hw,
                       const float* __restrict__ cw, float* __restrict__ out) {
  int p = blockIdx.x * 256 + threadIdx.x;
  int h = p >> 8, w = p & 255;
  float acc = 0.f;
  for (int dy = 0; dy < 7; ++dy) {
    int hy = h + dy - 3;
    if (hy < 0 || hy > 255) continue;
    for (int dx = 0; dx < 7; ++dx) {
      int wx = w + dx - 3;
      if (wx < 0 || wx > 255) continue;
      int q = hy * 256 + wx;
      acc += cw[dy * 7 + dx] * (sum_hw[q] * (1.f / 256.f)) +
             cw[49 + dy * 7 + dx] * max_hw[q];
    }
  }
  acc = fmaxf(acc, EPSF);
  out[p] = 1.f / (1.f + expf(-acc));
}

// ---------------------------------------------------------------------------
extern "C" void kernel_launch(void* const* d_in, const int* in_sizes, int n_in,
                              void* d_out, int out_size, void* d_ws, size_t ws_size,
                              hipStream_t stream) {
  const float* x = (const float*)d_in[0];
  const float* w1 = (const float*)d_in[1];
  const float* w2 = (const float*)d_in[2];
  const float* cw = (const float*)d_in[3];
  const int* kv = (const int*)d_in[4];
  float* out = (float*)d_out;
  float* small = (float*)d_ws;

  size_t small_bytes = (size_t)SMALL_FLOATS * 4;
  size_t avail = ws_size > small_bytes ? ws_size - small_bytes : 0;
  long chunk = (long)(avail / (3ull * NN * 4)); // 3 fp32 matrices per channel
  if (chunk > NCH) chunk = NCH;
  if (chunk < 1) chunk = 1;
  float* bufA = small + SMALL_FLOATS;
  float* bufB = bufA + (size_t)chunk * NN;
  float* bufC = bufB + (size_t)chunk * NN;

  const int tridiag_lds = 1056 * 8 + 32896 * 4 + 512 * 4; // 142080 B
  hipFuncSetAttribute((const void*)k_tridiag,
                      hipFuncAttributeMaxDynamicSharedMemorySize, tridiag_lds);
  hipFuncSetAttribute((const void*)k_nsh,
                      hipFuncAttributeMaxDynamicSharedMemorySize, NSH_LDS);

  k_chan_stats<<<NCH, 256, 0, stream>>>(x, small);
  k_attention<<<1, 256, 0, stream>>>(w1, w2, kv, small);

  const int IT32 = 13; // it_sw <= 12 provably; fp32 path never needed past this

  for (int base = 0; base < NCH; base += (int)chunk) {
    int cc = (NCH - base < (int)chunk) ? (NCH - base) : (int)chunk;
    dim3 gsym(3, 1, cc);
    dim3 gproj(2, 2, cc);
    k_gram<<<gsym, 256, 0, stream>>>(x, bufA, base);
    k_tridiag<<<cc, 1024, tridiag_lds, stream>>>(bufA, small, base);
    k_bisect<<<cc, 64, 0, stream>>>(small, base, cc);
    k_x0<<<dim3(N, cc), 256, 0, stream>>>(small, bufA, base);
    for (int it = 0; it < NS_MAX; ++it) {
      const float* src = (it & 1) ? bufB : bufA;
      float* dst = (it & 1) ? bufA : bufB;
      if (it < IT32) {
        k_ns1<<<gsym, 256, 0, stream>>>(src, bufC, small, base, it);
        k_ns2<<<gsym, 256, 0, stream>>>(src, bufC, dst, small, base, it);
      }
      k_nsh<<<gsym, 256, NSH_LDS, stream>>>(src, bufC, dst, small, base, it, 0);
      k_nsh<<<gsym, 256, NSH_LDS, stream>>>(src, bufC, dst, small, base, it, 1);
    }
    k_proj<<<gproj, 256, 0, stream>>>(bufA, bufB, x, bufC, small, base);
    k_accum<<<256, 256, 0, stream>>>(bufC, small + OFF_SUM, small + OFF_MAXHW, cc,
                                     base == 0 ? 1 : 0);
  }
  k_conv<<<256, 256, 0, stream>>>(small + OFF_SUM, small + OFF_MAXHW, cw, out);
}

// Round 14
// 5533.022 us; speedup vs baseline: 1.0476x; 1.0169x over previous
//
#include <hip/hip_runtime.h>

// ============================================================================
// AFAR: channel-attention -> per-channel truncated-SVD recon -> spatial attn.
// A_k = P*A, P = step(G - t), G = A*A^T. t from mixed-precision Householder
// tridiag + fp64 Sturm multisection. Projector via polar-express schedule;
// late iterations (certified margin l >= 0.02) run as f16 MFMA GEMMs (k_nsh
// two-dispatch path, R12/R16 verified best).
// R19 = R18 + missing barrier. R18's fused column extraction was correct,
// but the PROLOGUE read uf0[r] = P[r][0] raced with the triangle init (the
// writer of P[r][0] is a different thread; no barrier in between) -> first
// Householder vector corrupted -> absmax 0.156. One __syncthreads() between
// init and the prologue column read fixes it. All step arithmetic is
// bitwise R16: K via pi + redundant kpart + separate reduction (R17's
// cancellation-prone K expansion stays reverted); column j+1 extraction
// fused into the rank-2 update (peeled fmaf result -> P and double-buffered
// uf). Barriers/step: 5 -> 4. sigma~0 fallback keeps explicit column read.
// ============================================================================

#define NCH 256
#define N 256
#define NN 65536
#define NS_MAX 22

// small-region float offsets inside d_ws (double regions 8B-aligned)
#define OFF_K 0          // int[256]
#define OFF_MODE 256     // int[256]: 0 -> A_k=0, 1 -> A_k=A, 2 -> project
#define OFF_MC 512       // int[256]
#define OFF_COEF 768     // float[256][2*NS_MAX]
#define OFF_SUM 12032    // float[65536]
#define OFF_MAXHW 77568  // float[65536]
#define OFF_MEAND 143104 // double[256]
#define OFF_MAXD 143616  // double[256]
#define OFF_T 144128     // double[256]
#define OFF_ALPHA 144640 // double[256]
#define OFF_AQ 145152    // double[256][256]
#define OFF_BQ 276224    // double[256][256]
#define OFF_ITSW 407296  // int[256]: first iteration index safe for f16 MFMA
#define SMALL_FLOATS 407552

#define NSH_LDS 135168   // 2 panels x 128 rows x (256+8) f16
#define F16_PANEL 33792  // 128*264 u16 elements

static const float EPSF = 2.220446049250313e-16f;

typedef unsigned short u16;
typedef _Float16 h8 __attribute__((ext_vector_type(8)));
typedef float f32x4 __attribute__((ext_vector_type(4)));

__device__ __forceinline__ float rdlane(float v, int l) {
  return __uint_as_float(__builtin_amdgcn_readlane(__float_as_uint(v), l));
}

__device__ __forceinline__ u16 f2h(float v) {
  _Float16 h = (_Float16)v;
  u16 u;
  __builtin_memcpy(&u, &h, 2);
  return u;
}
__device__ __forceinline__ float h2f(u16 u) {
  _Float16 h;
  __builtin_memcpy(&h, &u, 2);
  return (float)h;
}

// ---------------------------------------------------------------------------
// 1) per-channel mean & max over H*W (fp64 sum)
// ---------------------------------------------------------------------------
__global__ __launch_bounds__(256) void k_chan_stats(const float* __restrict__ x,
                                                    float* __restrict__ small) {
  int c = blockIdx.x, tid = threadIdx.x;
  const float4* xc = (const float4*)(x + (size_t)c * NN);
  double s = 0.0;
  float m = -1e30f;
  for (int i = tid; i < NN / 4; i += 256) {
    float4 v = xc[i];
    s += (double)v.x + (double)v.y + (double)v.z + (double)v.w;
    m = fmaxf(m, fmaxf(fmaxf(v.x, v.y), fmaxf(v.z, v.w)));
  }
  __shared__ double rs[4];
  __shared__ float rm[4];
  for (int off = 32; off; off >>= 1) {
    s += __shfl_down(s, off, 64);
    m = fmaxf(m, __shfl_down(m, off, 64));
  }
  if ((tid & 63) == 0) { rs[tid >> 6] = s; rm[tid >> 6] = m; }
  __syncthreads();
  if (tid == 0) {
    ((double*)(small + OFF_MEAND))[c] = (rs[0] + rs[1] + rs[2] + rs[3]) / (double)NN;
    ((double*)(small + OFF_MAXD))[c] =
        (double)fmaxf(fmaxf(rm[0], rm[1]), fmaxf(rm[2], rm[3]));
  }
}

// ---------------------------------------------------------------------------
// 2) shared-MLP channel attention (fp64) -> gates yc -> k_c, mode_c
// ---------------------------------------------------------------------------
__global__ __launch_bounds__(256) void k_attention(const float* __restrict__ w1,
                                                   const float* __restrict__ w2,
                                                   const int* __restrict__ kvp,
                                                   float* __restrict__ small) {
  int tid = threadIdx.x;
  __shared__ double ha[16], hm[16], redd[8], ymn[256], ymx[256];
  double va = ((const double*)(small + OFF_MEAND))[tid];
  double vm = ((const double*)(small + OFF_MAXD))[tid];
  for (int r = 0; r < 16; ++r) {
    double wv = (double)w1[r * 256 + tid];
    double pa = wv * va, pm = wv * vm;
    for (int off = 32; off; off >>= 1) {
      pa += __shfl_down(pa, off, 64);
      pm += __shfl_down(pm, off, 64);
    }
    if ((tid & 63) == 0) { redd[tid >> 6] = pa; redd[4 + (tid >> 6)] = pm; }
    __syncthreads();
    if (tid == 0) {
      ha[r] = fmax(redd[0] + redd[1] + redd[2] + redd[3], 0.0);
      hm[r] = fmax(redd[4] + redd[5] + redd[6] + redd[7], 0.0);
    }
    __syncthreads();
  }
  double ya = 0.0, ym = 0.0;
  for (int r = 0; r < 16; ++r) {
    double wv = (double)w2[tid * 16 + r];
    ya += ha[r] * wv;
    ym += hm[r] * wv;
  }
  double y = 1.0 / (1.0 + exp(-(ya + ym)));
  ymn[tid] = y; ymx[tid] = y;
  __syncthreads();
  for (int off = 128; off; off >>= 1) {
    if (tid < off) {
      ymn[tid] = fmin(ymn[tid], ymn[tid + off]);
      ymx[tid] = fmax(ymx[tid], ymx[tid + off]);
    }
    __syncthreads();
  }
  double yc = (y - ymn[0]) / (ymx[0] - ymn[0] + 1e-20);
  int kv = kvp[0];
  int k = (int)floor(256.0 * (double)kv * yc);
  int mode = (k <= 0) ? 0 : ((k >= 256) ? 1 : 2);
  int* ip = (int*)small;
  ip[OFF_K + tid] = k;
  ip[OFF_MODE + tid] = mode;
}

// ---------------------------------------------------------------------------
// GEMM core: 128x128 tile, 256 threads, 8x8 micro-tile (2x2 quadrants of 4)
// ---------------------------------------------------------------------------
#define GEMM128_VARS                                                           \
  int tid = threadIdx.x;                                                       \
  int tx4 = (tid & 15) * 4, ty4 = (tid >> 4) * 4;                              \
  int lm = tid >> 1, lq = (tid & 1) * 2;                                       \
  int lk = tid >> 4, lc = (tid & 15) * 2;                                      \
  (void)lk; (void)lc;

#define STORE_T128(Ls, v0, v1)                                                 \
  Ls[lq * 4 + 0][lm] = v0.x; Ls[lq * 4 + 1][lm] = v0.y;                        \
  Ls[lq * 4 + 2][lm] = v0.z; Ls[lq * 4 + 3][lm] = v0.w;                        \
  Ls[lq * 4 + 4][lm] = v1.x; Ls[lq * 4 + 5][lm] = v1.y;                        \
  Ls[lq * 4 + 6][lm] = v1.z; Ls[lq * 4 + 7][lm] = v1.w;

#define GEMM128_INNER(AsM, BsM)                                                \
  _Pragma("unroll") for (int kk = 0; kk < 16; ++kk) {                          \
    float4 a0 = *(const float4*)&AsM[kk][ty4];                                 \
    float4 a1 = *(const float4*)&AsM[kk][64 + ty4];                            \
    float4 b0 = *(const float4*)&BsM[kk][tx4];                                 \
    float4 b1 = *(const float4*)&BsM[kk][64 + tx4];                            \
    float av[8] = {a0.x, a0.y, a0.z, a0.w, a1.x, a1.y, a1.z, a1.w};            \
    float bv[8] = {b0.x, b0.y, b0.z, b0.w, b1.x, b1.y, b1.z, b1.w};            \
    _Pragma("unroll") for (int rr = 0; rr < 8; ++rr)                           \
      _Pragma("unroll") for (int cc2 = 0; cc2 < 8; ++cc2)                      \
        acc[rr][cc2] += av[rr] * bv[cc2];                                      \
  }

#define WRITE_TILE_NORM(Cc)                                                    \
  _Pragma("unroll") for (int rh = 0; rh < 2; ++rh)                             \
  _Pragma("unroll") for (int rr = 0; rr < 4; ++rr) {                           \
    int rI = rh * 4 + rr;                                                      \
    float* rowp = (Cc) + (size_t)(i0 + rh * 64 + ty4 + rr) * N + j0;           \
    *(float4*)(rowp + tx4) =                                                   \
        make_float4(acc[rI][0], acc[rI][1], acc[rI][2], acc[rI][3]);           \
    *(float4*)(rowp + 64 + tx4) =                                              \
        make_float4(acc[rI][4], acc[rI][5], acc[rI][6], acc[rI][7]);           \
  }

#define WRITE_TILE_MIRROR(Cc)                                                  \
  _Pragma("unroll") for (int ch = 0; ch < 2; ++ch)                             \
  _Pragma("unroll") for (int cc2 = 0; cc2 < 4; ++cc2) {                        \
    int cI = ch * 4 + cc2;                                                     \
    float* rowp = (Cc) + (size_t)(j0 + ch * 64 + tx4 + cc2) * N + i0;          \
    *(float4*)(rowp + ty4) =                                                   \
        make_float4(acc[0][cI], acc[1][cI], acc[2][cI], acc[3][cI]);           \
    *(float4*)(rowp + 64 + ty4) =                                              \
        make_float4(acc[4][cI], acc[5][cI], acc[6][cI], acc[7][cI]);           \
  }

// sym block map: bx 0,1,2 -> (0,0),(1,0),(1,1)
#define SYM_MAP                                                                \
  int bx = blockIdx.x;                                                         \
  int i0 = (bx >= 1) ? 128 : 0, j0 = (bx == 2) ? 128 : 0;

// 3) G = A*A^T per channel (lower tiles + mirror)
__global__ __launch_bounds__(256) void k_gram(const float* __restrict__ x,
                                              float* __restrict__ bufA, int base) {
  __shared__ float As[16][132], Bs[16][132];
  GEMM128_VARS; SYM_MAP;
  const float* A = x + (size_t)(base + blockIdx.z) * NN;
  float acc[8][8] = {};
  const float* Ap = A + (size_t)(i0 + lm) * N + lq * 4;
  const float* Bp = A + (size_t)(j0 + lm) * N + lq * 4;
  float4 va0 = *(const float4*)Ap, va1 = *(const float4*)(Ap + 4);
  float4 vb0 = *(const float4*)Bp, vb1 = *(const float4*)(Bp + 4);
  for (int kt = 0; kt < 16; ++kt) {
    __syncthreads();
    STORE_T128(As, va0, va1); STORE_T128(Bs, vb0, vb1);
    __syncthreads();
    if (kt < 15) {
      va0 = *(const float4*)(Ap + (kt + 1) * 16);
      va1 = *(const float4*)(Ap + (kt + 1) * 16 + 4);
      vb0 = *(const float4*)(Bp + (kt + 1) * 16);
      vb1 = *(const float4*)(Bp + (kt + 1) * 16 + 4);
    }
    GEMM128_INNER(As, Bs);
  }
  float* Cc = bufA + (size_t)blockIdx.z * NN;
  WRITE_TILE_NORM(Cc);
  if (bx == 1) { WRITE_TILE_MIRROR(Cc); }
}

// ---------------------------------------------------------------------------
// tridiag helpers: per-chunk matvec (f64 acc) and rank-2 update (f32, with
// fused column-(j+1) extraction for group 0). c0 is 64-aligned and
// wave-uniform; R0 is the wave's row-block base.
// ---------------------------------------------------------------------------
__device__ __forceinline__ double mv_chunk(const float* __restrict__ P, int c0,
                                           int j, int r, int R0, int triR,
                                           float ureg) {
  double pi0 = 0.0, pi1 = 0.0, pi2 = 0.0, pi3 = 0.0;
  if (c0 < N) {
    int lbeg = (c0 > j + 1) ? c0 : (j + 1);
    int lend = c0 + 64;
    if (lbeg < lend) {
      if (c0 + 64 <= R0) {
        // class A: all l < r -> row-contiguous triR+lmv (no select)
        int lmv = lbeg;
        for (; lmv + 3 < lend; lmv += 4) {
          float uv0 = rdlane(ureg, lmv - c0), uv1 = rdlane(ureg, lmv + 1 - c0);
          float uv2 = rdlane(ureg, lmv + 2 - c0), uv3 = rdlane(ureg, lmv + 3 - c0);
          float v0 = P[triR + lmv], v1 = P[triR + lmv + 1];
          float v2 = P[triR + lmv + 2], v3 = P[triR + lmv + 3];
          pi0 += (double)v0 * (double)uv0;
          pi1 += (double)v1 * (double)uv1;
          pi2 += (double)v2 * (double)uv2;
          pi3 += (double)v3 * (double)uv3;
        }
        for (; lmv < lend; ++lmv)
          pi0 += (double)P[triR + lmv] * (double)rdlane(ureg, lmv - c0);
      } else if (c0 >= R0 + 64) {
        // class C: all l > r -> s(l)+r, incremental s (no select)
        int lmv = lbeg;
        int s = (lmv * (lmv + 1)) >> 1;
        for (; lmv + 3 < lend; lmv += 4) {
          int s0 = s, s1 = s0 + lmv + 1, s2 = s1 + lmv + 2, s3 = s2 + lmv + 3;
          s = s3 + lmv + 4;
          float uv0 = rdlane(ureg, lmv - c0), uv1 = rdlane(ureg, lmv + 1 - c0);
          float uv2 = rdlane(ureg, lmv + 2 - c0), uv3 = rdlane(ureg, lmv + 3 - c0);
          pi0 += (double)P[s0 + r] * (double)uv0;
          pi1 += (double)P[s1 + r] * (double)uv1;
          pi2 += (double)P[s2 + r] * (double)uv2;
          pi3 += (double)P[s3 + r] * (double)uv3;
        }
        for (; lmv < lend; ++lmv) {
          pi0 += (double)P[s + r] * (double)rdlane(ureg, lmv - c0);
          s += lmv + 1;
        }
      } else {
        // class B: diagonal chunk, per-element select
        int lmv = lbeg;
        int s = (lmv * (lmv + 1)) >> 1;
        for (; lmv < lend; ++lmv) {
          float uv = rdlane(ureg, lmv - c0);
          float v = P[(lmv <= r) ? (triR + lmv) : (s + r)];
          pi0 += (double)v * (double)uv;
          s += lmv + 1;
        }
      }
    }
  }
  return (pi0 + pi1) + (pi2 + pi3);
}

// rank-2 update with fused extraction: colB != nullptr only for group 0
// (c0 == cbase <= j+1 < c0+64), whose first update element is l == j+1.
// That peeled value is bitwise the next step's column entry.
__device__ __forceinline__ void upd_chunk_x(float* __restrict__ P, int c0, int j,
                                            int r, int R0, int triR, float ureg,
                                            float wreg, float urf, float wrf,
                                            float* __restrict__ colB) {
  if (c0 >= N) return;
  int lbeg = (c0 > j + 1) ? c0 : (j + 1);
  int lend = c0 + 64;
  int lcap = (r | 63) + 1; // wave-uniform cap
  if (lend > lcap) lend = lcap;
  if (c0 + 64 <= R0) {
    // class A: full range, all l < r, contiguous
    int lmv = lbeg;
    if (colB) { // lbeg == j+1 for group 0; peel and extract
      float uv = rdlane(ureg, lmv - c0), wv = rdlane(wreg, lmv - c0);
      float v = fmaf(-wrf, uv, fmaf(-urf, wv, P[triR + lmv]));
      P[triR + lmv] = v;
      colB[r] = v;
      ++lmv;
    }
    for (; lmv + 1 < lend; lmv += 2) {
      float uv0 = rdlane(ureg, lmv - c0), wv0 = rdlane(wreg, lmv - c0);
      float uv1 = rdlane(ureg, lmv + 1 - c0), wv1 = rdlane(wreg, lmv + 1 - c0);
      P[triR + lmv] = fmaf(-wrf, uv0, fmaf(-urf, wv0, P[triR + lmv]));
      P[triR + lmv + 1] = fmaf(-wrf, uv1, fmaf(-urf, wv1, P[triR + lmv + 1]));
    }
    if (lmv < lend) {
      float uv0 = rdlane(ureg, lmv - c0), wv0 = rdlane(wreg, lmv - c0);
      P[triR + lmv] = fmaf(-wrf, uv0, fmaf(-urf, wv0, P[triR + lmv]));
    }
  } else if (c0 == R0) {
    // class B: diagonal chunk, per-lane cap
    int lmv = lbeg;
    if (colB) { // peel l == j+1 (l <= r guaranteed: r >= j+1)
      float uv = rdlane(ureg, lmv - c0), wv = rdlane(wreg, lmv - c0);
      float v = fmaf(-wrf, uv, fmaf(-urf, wv, P[triR + lmv]));
      P[triR + lmv] = v;
      colB[r] = v;
      ++lmv;
    }
    for (; lmv < lend; ++lmv) {
      float uv = rdlane(ureg, lmv - c0), wv = rdlane(wreg, lmv - c0);
      if (lmv <= r)
        P[triR + lmv] = fmaf(-wrf, uv, fmaf(-urf, wv, P[triR + lmv]));
    }
  }
  // c0 >= R0+64: lend <= lcap = R0+64 <= c0 < lbeg -> empty
}

// ---------------------------------------------------------------------------
// 4) Householder tridiag: 1024 threads = 4 column-groups x 256 rows, 4
//    barriers/step: {matvec + sigma partials -> B2 -> pi + kpart reduction
//    (EXACT R16 arithmetic) -> B3 -> K, w store -> B4 -> rank-2 update with
//    fused column-(j+1) extraction into double-buffered uf -> B5}. f64
//    matvec, f32 rank-2 update. All values bitwise = R16.
// ---------------------------------------------------------------------------
__global__ __launch_bounds__(1024) void k_tridiag(const float* __restrict__ Gall,
                                                  float* __restrict__ small, int base) {
  extern __shared__ double dls[];
  double* redd = dls;              // 16 (sigma partials)
  double* redd2 = dls + 16;        // 16 (K partials)
  double* pip = dls + 32;          // 1024
  float* P = (float*)(dls + 1056); // 32896 packed lower triangle
  float* uf0 = P + 32896;          // 256 (column ping)
  float* uf1 = uf0 + 256;          // 256 (column pong)
  float* wf = uf1 + 256;           // 256 (f32 w for the update)
  int tid = threadIdx.x, lane = tid & 63;
  int r = tid & 255, g = tid >> 8; // g in {0..3}
  int wid = tid >> 6;              // 0..15
  int R0 = (wid & 3) << 6;         // wave row-block base (r = R0 + lane)
  int c = base + blockIdx.x;
  const int* ip = (const int*)small;
  if (ip[OFF_MODE + c] != 2) return;
  const float* G = Gall + (size_t)blockIdx.x * NN;
  double* aq = (double*)(small + OFF_AQ) + (size_t)c * 256;
  double* bq = (double*)(small + OFF_BQ) + (size_t)c * 256;
  const int triR = (r * (r + 1)) >> 1;

  for (int i = g; i < N; i += 4)
    if (r <= i) P[((i * (i + 1)) >> 1) + r] = G[i * N + r];
  __syncthreads(); // R19 FIX: init must complete before the column-0 read
                   // (P[r][0] is written by a DIFFERENT thread than reads it)
  // prologue: column 0 into uf0
  if (g == 0) uf0[r] = P[triR + 0];
  __syncthreads();

  float* ufA = uf0;
  float* ufB = uf1;
  for (int j = 0; j + 2 < N; ++j) {
    int jj = j + 1;
    float x_r = ufA[r];                // valid for r >= j+1
    double x0 = (double)ufA[jj];
    int cbase = jj & ~63;
    int c0 = cbase + 64 * g;           // wave-uniform
    float ureg = 0.f;
    if (c0 < N) ureg = ufA[c0 + lane]; // uniform cond: rdlane source
    bool act = (r >= jj);
    // merged phase: sigma partial + matvec p' = P*x (raw column)
    double sp = (g == 0 && r >= j + 2) ? (double)x_r * (double)x_r : 0.0;
    double myp = mv_chunk(P, c0, j, r, R0, triR, ureg);
    pip[tid] = act ? myp : 0.0;
    for (int off = 32; off; off >>= 1) sp += __shfl_down(sp, off, 64);
    if (lane == 0) redd[wid] = sp;
    __syncthreads(); // B2
    double sigma = (((redd[0] + redd[1]) + (redd[2] + redd[3])) +
                    ((redd[4] + redd[5]) + (redd[6] + redd[7]))) +
                   (((redd[8] + redd[9]) + (redd[10] + redd[11])) +
                    ((redd[12] + redd[13]) + (redd[14] + redd[15])));
    if (sigma <= 1e-40) { // column already tridiagonal (rare)
      if (tid == 0) bq[j] = x0;
      if (g == 0 && r >= j + 2) ufB[r] = P[triR + jj];
      __syncthreads();
      { float* t = ufA; ufA = ufB; ufB = t; }
      continue;
    }
    double nu = sqrt(x0 * x0 + sigma);
    double bsub = (x0 >= 0.0) ? -nu : nu;
    double beta = 1.0 / (nu * (nu + fabs(x0)));
    // patch u register at the column-(j+1) slot (self-register write)
    if (c0 <= jj && jj < c0 + 64 && lane == jj - c0)
      ureg = (float)(x0 - bsub);
    // phase: pi with fixup (all groups redundantly) + K partial (= R16)
    double pi = 0.0, u_r = 0.0, kp = 0.0;
    if (act) {
      double fix = -bsub * (double)P[triR + jj];
      pi = (pip[r] + pip[256 + r] + pip[512 + r] + pip[768 + r] + fix) * beta;
      u_r = (r == jj) ? (x0 - bsub) : (double)x_r;
      kp = u_r * pi * 0.25; // 0.25: four groups quadruple-count
    }
    for (int off = 32; off; off >>= 1) kp += __shfl_down(kp, off, 64);
    if (lane == 0) redd2[wid] = kp;
    __syncthreads(); // B3
    double K = ((((redd2[0] + redd2[1]) + (redd2[2] + redd2[3])) +
                 ((redd2[4] + redd2[5]) + (redd2[6] + redd2[7]))) +
                (((redd2[8] + redd2[9]) + (redd2[10] + redd2[11])) +
                 ((redd2[12] + redd2[13]) + (redd2[14] + redd2[15])))) *
               beta * 0.5;
    if (g == 0 && act) wf[r] = (float)(pi - K * u_r);
    if (tid == 0) bq[j] = bsub;
    __syncthreads(); // B4
    float wreg = 0.f;
    if (c0 < N) wreg = wf[c0 + lane]; // uniform cond: rdlane source
    // rank-2 update (f32) with fused column extraction (group 0)
    if (act) {
      float urf = (float)u_r;
      float wrf = wf[r];
      upd_chunk_x(P, c0, j, r, R0, triR, ureg, wreg, urf, wrf,
                  (g == 0) ? ufB : (float*)nullptr);
    }
    __syncthreads(); // B5
    { float* t = ufA; ufA = ufB; ufB = t; }
  }
  if (g == 0) aq[r] = (double)P[triR + r];
  if (tid == 0) bq[N - 2] = (double)P[(((N - 1) * N) >> 1) + N - 2];
}

// ---------------------------------------------------------------------------
// 5) fp64 Sturm 64-way multisection -> t, alpha, polar-express schedule,
//    and per-channel it_sw (first iteration with margin l >= 0.02, safe for
//    f16 MFMA: f16 spectral perturbation ~5e-4, 20-40x margin).
// ---------------------------------------------------------------------------
__device__ __forceinline__ int sturm_count_lds(const double* a, const double* b,
                                               double t) {
  double d = a[0] - t;
  int cnt = (d < 0.0);
  for (int i = 1; i < N; ++i) {
    double den = d;
    if (fabs(den) < 1e-20) den = (den < 0.0) ? -1e-20 : 1e-20;
    double bb = b[i - 1];
    d = (a[i] - t) - bb * bb / den;
    cnt += (d < 0.0);
  }
  return cnt; // #{eig < t}
}

__global__ __launch_bounds__(64) void k_bisect(float* __restrict__ small,
                                               int base, int cc) {
  int ci = blockIdx.x;
  if (ci >= cc) return;
  int c = base + ci, lane = threadIdx.x;
  int* ip = (int*)small;
  if (ip[OFF_MODE + c] != 2) {
    if (lane == 0) { ip[OFF_MC + c] = 0; ip[OFF_ITSW + c] = 0; }
    return;
  }
  int k = ip[OFF_K + c];
  const double* a = (const double*)(small + OFF_AQ) + (size_t)c * 256;
  const double* b = (const double*)(small + OFF_BQ) + (size_t)c * 256;
  __shared__ double sa[256], sb[256];
  for (int i = lane; i < N; i += 64) {
    sa[i] = a[i];
    if (i < N - 1) sb[i] = b[i];
  }
  __syncthreads();
  // Gershgorin bounds (wave-parallel)
  double lo = 1e300, hi = -1e300;
  for (int i = lane; i < N; i += 64) {
    double rr = (i > 0 ? fabs(sb[i - 1]) : 0.0) + (i < N - 1 ? fabs(sb[i]) : 0.0);
    lo = fmin(lo, sa[i] - rr);
    hi = fmax(hi, sa[i] + rr);
  }
  for (int off = 32; off; off >>= 1) {
    lo = fmin(lo, __shfl_xor(lo, off, 64));
    hi = fmax(hi, __shfl_xor(hi, off, 64));
  }
  double lamk = 0.0, lamk1 = 0.0;
  for (int which = 0; which < 2; ++which) {
    int j = (which == 0) ? (N - k + 1) : (N - k); // ascending index of mu_j
    double l0 = lo, h0 = hi;
    for (int pass = 0; pass < 10; ++pass) {
      double step = (h0 - l0) * (1.0 / 65.0);
      double t = l0 + step * (double)(lane + 1);
      int cnt = sturm_count_lds(sa, sb, t);
      unsigned long long mask = __ballot(cnt >= j);
      if (mask == 0ull) {
        l0 = l0 + step * 64.0; // mu_j above all probes
      } else {
        int bpos = __ffsll((long long)mask) - 1; // first probe with cnt>=j
        double nl = (bpos == 0) ? l0 : (l0 + step * (double)bpos);
        h0 = l0 + step * (double)(bpos + 1);
        l0 = nl;
      }
    }
    double v = 0.5 * (l0 + h0);
    if (which == 0) lamk = v; else lamk1 = v;
  }
  if (lane == 0) {
    double t = 0.5 * (lamk + lamk1);
    double gap = fmax(lamk - lamk1, 0.0);
    double alpha = 1.002 * fmax(hi - t, t - lo) + 1e-30;
    double g0 = fmax(gap / (2.0 * alpha), 2e-6);
    // polar-express schedule: equioscillation cubic per iteration
    float* cf = small + OFF_COEF + (size_t)c * (2 * NS_MAX);
    double l = fmin(g0, 0.99);
    int m = 0, isw = NS_MAX;
    while (m < NS_MAX - 2 && l < 0.9999) {
      if (isw == NS_MAX && l >= 0.02) isw = m;
      double aa = sqrt(27.0 / (4.0 * (1.0 + l + l * l)));
      double bb = (4.0 / 27.0) * aa * aa * aa;
      cf[2 * m] = (float)aa;
      cf[2 * m + 1] = (float)bb;
      double pl = aa * l - bb * l * l * l;
      double p1 = aa - bb;
      l = fmin(pl, p1);
      m++;
    }
    for (int e = 0; e < 2; ++e) {
      if (isw == NS_MAX && l >= 0.02) isw = m;
      cf[2 * m] = 1.5f; cf[2 * m + 1] = 0.5f; m++;
    }
    if (isw > m) isw = m;
    ip[OFF_MC + c] = m;
    ip[OFF_ITSW + c] = isw;
    ((double*)(small + OFF_T))[c] = t;
    ((double*)(small + OFF_ALPHA))[c] = alpha;
  }
}

// 6) X0 = (G - t*I)/alpha (in place on bufA, fp64 scale)
__global__ void k_x0(const float* __restrict__ small, float* __restrict__ bufA,
                     int base) {
  int ci = blockIdx.y, c = base + ci;
  const int* ip = (const int*)small;
  if (ip[OFF_MODE + c] != 2) return;
  double t = ((const double*)(small + OFF_T))[c];
  double inva = 1.0 / ((const double*)(small + OFF_ALPHA))[c];
  float* X = bufA + (size_t)ci * NN;
  int r = blockIdx.x, tid = threadIdx.x;
  double gg = (double)X[r * N + tid];
  if (tid == r) gg -= t;
  X[r * N + tid] = (float)(gg * inva);
}

// 7a) S = X*X (X symmetric; lower tiles + mirror) -- fp32 path (it < it_sw)
__global__ __launch_bounds__(256) void k_ns1(const float* __restrict__ src,
                                             float* __restrict__ Sb,
                                             const float* __restrict__ small,
                                             int base, int it) {
  const int* ip = (const int*)small;
  int c = base + blockIdx.z;
  if (ip[OFF_MODE + c] != 2 || it >= ip[OFF_ITSW + c]) return;
  __shared__ float As[16][132], Bs[16][132];
  GEMM128_VARS; SYM_MAP;
  const float* X = src + (size_t)blockIdx.z * NN;
  float acc[8][8] = {};
  const float* Ap = X + (size_t)(i0 + lm) * N + lq * 4;
  const float* Bp = X + (size_t)(j0 + lm) * N + lq * 4;
  float4 va0 = *(const float4*)Ap, va1 = *(const float4*)(Ap + 4);
  float4 vb0 = *(const float4*)Bp, vb1 = *(const float4*)(Bp + 4);
  for (int kt = 0; kt < 16; ++kt) {
    __syncthreads();
    STORE_T128(As, va0, va1); STORE_T128(Bs, vb0, vb1);
    __syncthreads();
    if (kt < 15) {
      va0 = *(const float4*)(Ap + (kt + 1) * 16);
      va1 = *(const float4*)(Ap + (kt + 1) * 16 + 4);
      vb0 = *(const float4*)(Bp + (kt + 1) * 16);
      vb1 = *(const float4*)(Bp + (kt + 1) * 16 + 4);
    }
    GEMM128_INNER(As, Bs);
  }
  float* Cc = Sb + (size_t)blockIdx.z * NN;
  WRITE_TILE_NORM(Cc);
  if (bx == 1) { WRITE_TILE_MIRROR(Cc); }
}

// 7b) Y = a*X - b*X*S (commuting symmetric -> Y symmetric; tiles + mirror)
__global__ __launch_bounds__(256) void k_ns2(const float* __restrict__ src,
                                             const float* __restrict__ Sb,
                                             float* __restrict__ dst,
                                             const float* __restrict__ small,
                                             int base, int it) {
  const int* ip = (const int*)small;
  int c = base + blockIdx.z;
  if (ip[OFF_MODE + c] != 2 || it >= ip[OFF_ITSW + c]) return;
  float ca = small[OFF_COEF + (size_t)c * (2 * NS_MAX) + 2 * it];
  float cb = small[OFF_COEF + (size_t)c * (2 * NS_MAX) + 2 * it + 1];
  __shared__ float As[16][132], Bs[16][132];
  GEMM128_VARS; SYM_MAP;
  const float* X = src + (size_t)blockIdx.z * NN;
  const float* S = Sb + (size_t)blockIdx.z * NN;
  float acc[8][8] = {};
  const float* Ap = X + (size_t)(i0 + lm) * N + lq * 4;
  const float* Bp = S + (size_t)(j0 + lm) * N + lq * 4;
  float4 va0 = *(const float4*)Ap, va1 = *(const float4*)(Ap + 4);
  float4 vb0 = *(const float4*)Bp, vb1 = *(const float4*)(Bp + 4);
  for (int kt = 0; kt < 16; ++kt) {
    __syncthreads();
    STORE_T128(As, va0, va1); STORE_T128(Bs, vb0, vb1);
    __syncthreads();
    if (kt < 15) {
      va0 = *(const float4*)(Ap + (kt + 1) * 16);
      va1 = *(const float4*)(Ap + (kt + 1) * 16 + 4);
      vb0 = *(const float4*)(Bp + (kt + 1) * 16);
      vb1 = *(const float4*)(Bp + (kt + 1) * 16 + 4);
    }
    GEMM128_INNER(As, Bs);
  }
  // acc <- ca*X - cb*acc (transform in place, then write norm + mirror)
#pragma unroll
  for (int rh = 0; rh < 2; ++rh)
#pragma unroll
    for (int rr = 0; rr < 4; ++rr) {
      int rI = rh * 4 + rr;
      const float* rowp = X + (size_t)(i0 + rh * 64 + ty4 + rr) * N + j0;
      float4 x0 = *(const float4*)(rowp + tx4);
      float4 x1 = *(const float4*)(rowp + 64 + tx4);
      acc[rI][0] = ca * x0.x - cb * acc[rI][0];
      acc[rI][1] = ca * x0.y - cb * acc[rI][1];
      acc[rI][2] = ca * x0.z - cb * acc[rI][2];
      acc[rI][3] = ca * x0.w - cb * acc[rI][3];
      acc[rI][4] = ca * x1.x - cb * acc[rI][4];
      acc[rI][5] = ca * x1.y - cb * acc[rI][5];
      acc[rI][6] = ca * x1.z - cb * acc[rI][6];
      acc[rI][7] = ca * x1.w - cb * acc[rI][7];
    }
  float* Y = dst + (size_t)blockIdx.z * NN;
  WRITE_TILE_NORM(Y);
  if (bx == 1) { WRITE_TILE_MIRROR(Y); }
}

// ---------------------------------------------------------------------------
// panel staging helpers: 128x256 f16 panel in LDS, 264-elem padded rows
// (16B pad per 512B row -> bank rotation). Source either f16 image or fp32
// (converted in-flight at it == it_sw).
// ---------------------------------------------------------------------------
__device__ __forceinline__ void stage_h(u16* pan, const u16* g16, int tid) {
#pragma unroll
  for (int i = 0; i < 16; ++i) {
    int g = tid * 16 + i * 4096;          // byte offset in 64KB panel
    int lo = g + ((g >> 9) << 4);
    *(uint4*)((char*)pan + lo) = *(const uint4*)((const char*)g16 + g);
  }
}
__device__ __forceinline__ void stage_f(u16* pan, const float* gF, int tid) {
#pragma unroll
  for (int i = 0; i < 16; ++i) {
    int e = tid * 8 + i * 2048;           // f16-element offset
    float4 v0 = *(const float4*)(gF + e);
    float4 v1 = *(const float4*)(gF + e + 4);
    h8 hv;
    hv[0] = (_Float16)v0.x; hv[1] = (_Float16)v0.y;
    hv[2] = (_Float16)v0.z; hv[3] = (_Float16)v0.w;
    hv[4] = (_Float16)v1.x; hv[5] = (_Float16)v1.y;
    hv[6] = (_Float16)v1.z; hv[7] = (_Float16)v1.w;
    int b = e * 2;
    int lo = b + ((b >> 9) << 4);
    *(h8*)((char*)pan + lo) = hv;
  }
}

// ---------------------------------------------------------------------------
// 7d) f16 MFMA NS step (it_sw <= it < mc). phase 0: S = X*X -> f16 alias of
//     the channel's Sf slot. phase 1: Y = ca*X - cb*X*S -> f16 alias of the
//     dst slot (final iteration writes full fp32 Y instead; race-free).
// ---------------------------------------------------------------------------
__global__ __launch_bounds__(256) void k_nsh(const float* __restrict__ srcF,
                                             float* __restrict__ Sf,
                                             float* __restrict__ dstF,
                                             const float* __restrict__ small,
                                             int base, int it, int phase) {
  const int* ip = (const int*)small;
  int ci = blockIdx.z, c = base + ci;
  if (ip[OFF_MODE + c] != 2) return;
  int isw = ip[OFF_ITSW + c], mc = ip[OFF_MC + c];
  if (it < isw || it >= mc) return;
  SYM_MAP;
  extern __shared__ char ldsraw[];
  u16* Apan = (u16*)ldsraw;
  u16* Bpan = Apan + F16_PANEL;
  int tid = threadIdx.x;
  bool cvtA = (it == isw);                 // stage X from fp32, convert
  bool sameP = (phase == 0) && (bx != 1);  // diag block of S=X*X: one panel
  const float* XF = srcF + (size_t)ci * NN;
  const u16* XH = (const u16*)XF;          // f16 alias (first half of slot)
  if (cvtA) stage_f(Apan, XF + (size_t)i0 * N, tid);
  else      stage_h(Apan, XH + (size_t)i0 * N, tid);
  if (!sameP) {
    if (phase == 0) {
      if (cvtA) stage_f(Bpan, XF + (size_t)j0 * N, tid);
      else      stage_h(Bpan, XH + (size_t)j0 * N, tid);
    } else {
      const u16* SH = (const u16*)(Sf + (size_t)ci * NN);
      stage_h(Bpan, SH + (size_t)j0 * N, tid);
    }
  }
  const u16* Bb = sameP ? Apan : Bpan;
  __syncthreads();

  int l = tid & 63, wid = tid >> 6;
  int wr = (wid >> 1) * 64, wc = (wid & 1) * 64; // wave's 64x64 sub-tile
  int rA = wr + (l & 15), rB = wc + (l & 15);
  int kB = (l >> 4) << 3;
  f32x4 zero = {0.f, 0.f, 0.f, 0.f};
  f32x4 acc[4][4];
#pragma unroll
  for (int mi = 0; mi < 4; ++mi)
#pragma unroll
    for (int ni = 0; ni < 4; ++ni) acc[mi][ni] = zero;

#pragma unroll
  for (int kc = 0; kc < 8; ++kc) {
    int kof = kc * 32 + kB; // f16 element offset within row
    h8 af[4], bf[4];
#pragma unroll
    for (int mi = 0; mi < 4; ++mi)
      af[mi] = *(const h8*)((const char*)Apan +
                            ((size_t)(rA + mi * 16) * 264 + kof) * 2);
#pragma unroll
    for (int ni = 0; ni < 4; ++ni)
      bf[ni] = *(const h8*)((const char*)Bb +
                            ((size_t)(rB + ni * 16) * 264 + kof) * 2);
#pragma unroll
    for (int mi = 0; mi < 4; ++mi)
#pragma unroll
      for (int ni = 0; ni < 4; ++ni)
        acc[mi][ni] = __builtin_amdgcn_mfma_f32_16x16x32_f16(
            af[mi], bf[ni], acc[mi][ni], 0, 0, 0);
  }

  float cav = 0.f, cbv = 0.f;
  bool last = false;
  if (phase) {
    cav = small[OFF_COEF + (size_t)c * (2 * NS_MAX) + 2 * it];
    cbv = small[OFF_COEF + (size_t)c * (2 * NS_MAX) + 2 * it + 1];
    last = (it == mc - 1);
  }
  float* oF = dstF + (size_t)ci * NN;
  u16* oH = phase ? (u16*)oF : (u16*)(Sf + (size_t)ci * NN);
  int lr4 = (l >> 4) << 2, lcn = l & 15;
  // C/D layout (m89-verified): col = lane&15, row = (lane>>4)*4 + reg
#pragma unroll
  for (int mi = 0; mi < 4; ++mi)
#pragma unroll
    for (int ni = 0; ni < 4; ++ni)
#pragma unroll
      for (int rg = 0; rg < 4; ++rg) {
        int gr = i0 + wr + mi * 16 + lr4 + rg;
        int gc = j0 + wc + ni * 16 + lcn;
        float v = acc[mi][ni][rg];
        if (phase) {
          float xv = h2f(Apan[(size_t)(gr - i0) * 264 + gc]);
          v = cav * xv - cbv * v;
        }
        if (!last) { // f16 store (skipped on final iter: aliases oF region)
          u16 hv = f2h(v);
          oH[(size_t)gr * N + gc] = hv;
          if (bx == 1) oH[(size_t)gc * N + gr] = hv;
        } else {
          oF[(size_t)gr * N + gc] = v;
          if (bx == 1) oF[(size_t)gc * N + gr] = v;
        }
      }
}

// 8) A_k = 0.5*(sign(X)*A + A) (modes: 0 -> zeros, 1 -> copy A)
__global__ __launch_bounds__(256) void k_proj(const float* __restrict__ bufA,
                                              const float* __restrict__ bufB,
                                              const float* __restrict__ x,
                                              float* __restrict__ bufC,
                                              const float* __restrict__ small,
                                              int base) {
  const int* ip = (const int*)small;
  int ci = blockIdx.z, c = base + ci;
  int mode = ip[OFF_MODE + c];
  GEMM128_VARS;
  int i0 = blockIdx.x * 128, j0 = blockIdx.y * 128;
  float* Cc = bufC + (size_t)ci * NN;
  const float* xc = x + (size_t)c * NN;
  if (mode != 2) {
#pragma unroll
    for (int rh = 0; rh < 2; ++rh)
#pragma unroll
      for (int rr = 0; rr < 4; ++rr) {
        size_t ro = (size_t)(i0 + rh * 64 + ty4 + rr) * N + j0;
        if (mode == 0) {
          *(float4*)(Cc + ro + tx4) = make_float4(0.f, 0.f, 0.f, 0.f);
          *(float4*)(Cc + ro + 64 + tx4) = make_float4(0.f, 0.f, 0.f, 0.f);
        } else {
          *(float4*)(Cc + ro + tx4) = *(const float4*)(xc + ro + tx4);
          *(float4*)(Cc + ro + 64 + tx4) = *(const float4*)(xc + ro + 64 + tx4);
        }
      }
    return;
  }
  int mc = ip[OFF_MC + c];
  const float* Xh = ((mc & 1) ? bufB : bufA) + (size_t)ci * NN;
  __shared__ float As[16][132], Bs[16][132];
  float acc[8][8] = {};
  const float* Ap = Xh + (size_t)(i0 + lm) * N + lq * 4;
  const float* Bp = xc + (size_t)lk * N + j0 + lc * 4;
  float4 va0 = *(const float4*)Ap, va1 = *(const float4*)(Ap + 4);
  float4 vb0 = *(const float4*)Bp, vb1 = *(const float4*)(Bp + 4);
  for (int kt = 0; kt < 16; ++kt) {
    __syncthreads();
    STORE_T128(As, va0, va1);
    *(float4*)&Bs[lk][lc * 4] = vb0;
    *(float4*)&Bs[lk][(lc + 1) * 4] = vb1;
    __syncthreads();
    if (kt < 15) {
      va0 = *(const float4*)(Ap + (kt + 1) * 16);
      va1 = *(const float4*)(Ap + (kt + 1) * 16 + 4);
      const float* Bp2 = xc + (size_t)((kt + 1) * 16 + lk) * N + j0 + lc * 4;
      vb0 = *(const float4*)Bp2;
      vb1 = *(const float4*)(Bp2 + 4);
    }
    GEMM128_INNER(As, Bs);
  }
#pragma unroll
  for (int rh = 0; rh < 2; ++rh)
#pragma unroll
    for (int rr = 0; rr < 4; ++rr) {
      int rI = rh * 4 + rr;
      const float* rowp = xc + (size_t)(i0 + rh * 64 + ty4 + rr) * N + j0;
      float4 x0 = *(const float4*)(rowp + tx4);
      float4 x1 = *(const float4*)(rowp + 64 + tx4);
      acc[rI][0] = 0.5f * (acc[rI][0] + x0.x);
      acc[rI][1] = 0.5f * (acc[rI][1] + x0.y);
      acc[rI][2] = 0.5f * (acc[rI][2] + x0.z);
      acc[rI][3] = 0.5f * (acc[rI][3] + x0.w);
      acc[rI][4] = 0.5f * (acc[rI][4] + x1.x);
      acc[rI][5] = 0.5f * (acc[rI][5] + x1.y);
      acc[rI][6] = 0.5f * (acc[rI][6] + x1.z);
      acc[rI][7] = 0.5f * (acc[rI][7] + x1.w);
    }
  WRITE_TILE_NORM(Cc);
}

// 9) accumulate sum & max over channels
__global__ void k_accum(const float* __restrict__ bufC, float* __restrict__ sum_hw,
                        float* __restrict__ max_hw, int cc, int first) {
  int p = blockIdx.x * 256 + threadIdx.x;
  float s = first ? 0.f : sum_hw[p];
  float m = first ? -1e30f : max_hw[p];
  for (int ci = 0; ci < cc; ++ci) {
    float v = bufC[(size_t)ci * NN + p];
    s += v;
    m = fmaxf(m, v);
  }
  sum_hw[p] = s;
  max_hw[p] = m;
}

// 10) 7x7 conv (pad 3) on [avg, max] -> clamp EPS -> sigmoid
__global__ void k_conv(const float* __restrict__ sum_hw, const float* __restrict__ max_hw,
                       const float* __restrict__ cw, float* __restrict__ out) {
  int p = blockIdx.x * 256 + threadIdx.x;
  int h = p >> 8, w = p & 255;
  float acc = 0.f;
  for (int dy = 0; dy < 7; ++dy) {
    int hy = h + dy - 3;
    if (hy < 0 || hy > 255) continue;
    for (int dx = 0; dx < 7; ++dx) {
      int wx = w + dx - 3;
      if (wx < 0 || wx > 255) continue;
      int q = hy * 256 + wx;
      acc += cw[dy * 7 + dx] * (sum_hw[q] * (1.f / 256.f)) +
             cw[49 + dy * 7 + dx] * max_hw[q];
    }
  }
  acc = fmaxf(acc, EPSF);
  out[p] = 1.f / (1.f + expf(-acc));
}

// ---------------------------------------------------------------------------
extern "C" void kernel_launch(void* const* d_in, const int* in_sizes, int n_in,
                              void* d_out, int out_size, void* d_ws, size_t ws_size,
                              hipStream_t stream) {
  const float* x = (const float*)d_in[0];
  const float* w1 = (const float*)d_in[1];
  const float* w2 = (const float*)d_in[2];
  const float* cw = (const float*)d_in[3];
  const int* kv = (const int*)d_in[4];
  float* out = (float*)d_out;
  float* small = (float*)d_ws;

  size_t small_bytes = (size_t)SMALL_FLOATS * 4;
  size_t avail = ws_size > small_bytes ? ws_size - small_bytes : 0;
  long chunk = (long)(avail / (3ull * NN * 4)); // 3 fp32 matrices per channel
  if (chunk > NCH) chunk = NCH;
  if (chunk < 1) chunk = 1;
  float* bufA = small + SMALL_FLOATS;
  float* bufB = bufA + (size_t)chunk * NN;
  float* bufC = bufB + (size_t)chunk * NN;

  const int tridiag_lds = 1056 * 8 + 32896 * 4 + 768 * 4; // 143104 B
  hipFuncSetAttribute((const void*)k_tridiag,
                      hipFuncAttributeMaxDynamicSharedMemorySize, tridiag_lds);
  hipFuncSetAttribute((const void*)k_nsh,
                      hipFuncAttributeMaxDynamicSharedMemorySize, NSH_LDS);

  k_chan_stats<<<NCH, 256, 0, stream>>>(x, small);
  k_attention<<<1, 256, 0, stream>>>(w1, w2, kv, small);

  const int IT32 = 13; // it_sw <= 12 provably; fp32 path never needed past this

  for (int base = 0; base < NCH; base += (int)chunk) {
    int cc = (NCH - base < (int)chunk) ? (NCH - base) : (int)chunk;
    dim3 gsym(3, 1, cc);
    dim3 gproj(2, 2, cc);
    k_gram<<<gsym, 256, 0, stream>>>(x, bufA, base);
    k_tridiag<<<cc, 1024, tridiag_lds, stream>>>(bufA, small, base);
    k_bisect<<<cc, 64, 0, stream>>>(small, base, cc);
    k_x0<<<dim3(N, cc), 256, 0, stream>>>(small, bufA, base);
    for (int it = 0; it < NS_MAX; ++it) {
      const float* src = (it & 1) ? bufB : bufA;
      float* dst = (it & 1) ? bufA : bufB;
      if (it < IT32) {
        k_ns1<<<gsym, 256, 0, stream>>>(src, bufC, small, base, it);
        k_ns2<<<gsym, 256, 0, stream>>>(src, bufC, dst, small, base, it);
      }
      k_nsh<<<gsym, 256, NSH_LDS, stream>>>(src, bufC, dst, small, base, it, 0);
      k_nsh<<<gsym, 256, NSH_LDS, stream>>>(src, bufC, dst, small, base, it, 1);
    }
    k_proj<<<gproj, 256, 0, stream>>>(bufA, bufB, x, bufC, small, base);
    k_accum<<<256, 256, 0, stream>>>(bufC, small + OFF_SUM, small + OFF_MAXHW, cc,
                                     base == 0 ? 1 : 0);
  }
  k_conv<<<256, 256, 0, stream>>>(small + OFF_SUM, small + OFF_MAXHW, cw, out);
}

// Round 15
// 5526.811 us; speedup vs baseline: 1.0487x; 1.0011x over previous
//
#include <hip/hip_runtime.h>

// ============================================================================
// AFAR: channel-attention -> per-channel truncated-SVD recon -> spatial attn.
// A_k = P*A, P = step(G - t), G = A*A^T. t from mixed-precision Householder
// tridiag + fp64 Sturm multisection. Projector via polar-express schedule;
// late iterations (certified margin l >= 0.02) run as f16 MFMA GEMMs (k_nsh
// two-dispatch path). Tridiag = R19 (4-barrier overlapped schedule, fused
// column extraction, verified 3013 us / absmax 0.01171875).
// R20 (final polish): (a) k_x0 regridded from 65536 one-element blocks to
// cc blocks x 256 threads grid-stride (per-element arithmetic bitwise
// identical; removes ~40us of block-scheduling overhead); (b) IT32 13 -> 12
// (isw <= 10 provable: l0 >= 2e-6, growth >= 2.49x/iter below 0.02; margin 2).
// Session conclusion: tridiag is the structural floor -- 254 dependent
// Householder steps x ~28k cycles of latency-bound phase execution; R11/R12/
// R19 showed barrier-count reduction (9->4) moves it only ~3%. Breaking it
// requires blocked-WY (different algorithm, negative EV at this point).
// ============================================================================

#define NCH 256
#define N 256
#define NN 65536
#define NS_MAX 22

// small-region float offsets inside d_ws (double regions 8B-aligned)
#define OFF_K 0          // int[256]
#define OFF_MODE 256     // int[256]: 0 -> A_k=0, 1 -> A_k=A, 2 -> project
#define OFF_MC 512       // int[256]
#define OFF_COEF 768     // float[256][2*NS_MAX]
#define OFF_SUM 12032    // float[65536]
#define OFF_MAXHW 77568  // float[65536]
#define OFF_MEAND 143104 // double[256]
#define OFF_MAXD 143616  // double[256]
#define OFF_T 144128     // double[256]
#define OFF_ALPHA 144640 // double[256]
#define OFF_AQ 145152    // double[256][256]
#define OFF_BQ 276224    // double[256][256]
#define OFF_ITSW 407296  // int[256]: first iteration index safe for f16 MFMA
#define SMALL_FLOATS 407552

#define NSH_LDS 135168   // 2 panels x 128 rows x (256+8) f16
#define F16_PANEL 33792  // 128*264 u16 elements

static const float EPSF = 2.220446049250313e-16f;

typedef unsigned short u16;
typedef _Float16 h8 __attribute__((ext_vector_type(8)));
typedef float f32x4 __attribute__((ext_vector_type(4)));

__device__ __forceinline__ float rdlane(float v, int l) {
  return __uint_as_float(__builtin_amdgcn_readlane(__float_as_uint(v), l));
}

__device__ __forceinline__ u16 f2h(float v) {
  _Float16 h = (_Float16)v;
  u16 u;
  __builtin_memcpy(&u, &h, 2);
  return u;
}
__device__ __forceinline__ float h2f(u16 u) {
  _Float16 h;
  __builtin_memcpy(&h, &u, 2);
  return (float)h;
}

// ---------------------------------------------------------------------------
// 1) per-channel mean & max over H*W (fp64 sum)
// ---------------------------------------------------------------------------
__global__ __launch_bounds__(256) void k_chan_stats(const float* __restrict__ x,
                                                    float* __restrict__ small) {
  int c = blockIdx.x, tid = threadIdx.x;
  const float4* xc = (const float4*)(x + (size_t)c * NN);
  double s = 0.0;
  float m = -1e30f;
  for (int i = tid; i < NN / 4; i += 256) {
    float4 v = xc[i];
    s += (double)v.x + (double)v.y + (double)v.z + (double)v.w;
    m = fmaxf(m, fmaxf(fmaxf(v.x, v.y), fmaxf(v.z, v.w)));
  }
  __shared__ double rs[4];
  __shared__ float rm[4];
  for (int off = 32; off; off >>= 1) {
    s += __shfl_down(s, off, 64);
    m = fmaxf(m, __shfl_down(m, off, 64));
  }
  if ((tid & 63) == 0) { rs[tid >> 6] = s; rm[tid >> 6] = m; }
  __syncthreads();
  if (tid == 0) {
    ((double*)(small + OFF_MEAND))[c] = (rs[0] + rs[1] + rs[2] + rs[3]) / (double)NN;
    ((double*)(small + OFF_MAXD))[c] =
        (double)fmaxf(fmaxf(rm[0], rm[1]), fmaxf(rm[2], rm[3]));
  }
}

// ---------------------------------------------------------------------------
// 2) shared-MLP channel attention (fp64) -> gates yc -> k_c, mode_c
// ---------------------------------------------------------------------------
__global__ __launch_bounds__(256) void k_attention(const float* __restrict__ w1,
                                                   const float* __restrict__ w2,
                                                   const int* __restrict__ kvp,
                                                   float* __restrict__ small) {
  int tid = threadIdx.x;
  __shared__ double ha[16], hm[16], redd[8], ymn[256], ymx[256];
  double va = ((const double*)(small + OFF_MEAND))[tid];
  double vm = ((const double*)(small + OFF_MAXD))[tid];
  for (int r = 0; r < 16; ++r) {
    double wv = (double)w1[r * 256 + tid];
    double pa = wv * va, pm = wv * vm;
    for (int off = 32; off; off >>= 1) {
      pa += __shfl_down(pa, off, 64);
      pm += __shfl_down(pm, off, 64);
    }
    if ((tid & 63) == 0) { redd[tid >> 6] = pa; redd[4 + (tid >> 6)] = pm; }
    __syncthreads();
    if (tid == 0) {
      ha[r] = fmax(redd[0] + redd[1] + redd[2] + redd[3], 0.0);
      hm[r] = fmax(redd[4] + redd[5] + redd[6] + redd[7], 0.0);
    }
    __syncthreads();
  }
  double ya = 0.0, ym = 0.0;
  for (int r = 0; r < 16; ++r) {
    double wv = (double)w2[tid * 16 + r];
    ya += ha[r] * wv;
    ym += hm[r] * wv;
  }
  double y = 1.0 / (1.0 + exp(-(ya + ym)));
  ymn[tid] = y; ymx[tid] = y;
  __syncthreads();
  for (int off = 128; off; off >>= 1) {
    if (tid < off) {
      ymn[tid] = fmin(ymn[tid], ymn[tid + off]);
      ymx[tid] = fmax(ymx[tid], ymx[tid + off]);
    }
    __syncthreads();
  }
  double yc = (y - ymn[0]) / (ymx[0] - ymn[0] + 1e-20);
  int kv = kvp[0];
  int k = (int)floor(256.0 * (double)kv * yc);
  int mode = (k <= 0) ? 0 : ((k >= 256) ? 1 : 2);
  int* ip = (int*)small;
  ip[OFF_K + tid] = k;
  ip[OFF_MODE + tid] = mode;
}

// ---------------------------------------------------------------------------
// GEMM core: 128x128 tile, 256 threads, 8x8 micro-tile (2x2 quadrants of 4)
// ---------------------------------------------------------------------------
#define GEMM128_VARS                                                           \
  int tid = threadIdx.x;                                                       \
  int tx4 = (tid & 15) * 4, ty4 = (tid >> 4) * 4;                              \
  int lm = tid >> 1, lq = (tid & 1) * 2;                                       \
  int lk = tid >> 4, lc = (tid & 15) * 2;                                      \
  (void)lk; (void)lc;

#define STORE_T128(Ls, v0, v1)                                                 \
  Ls[lq * 4 + 0][lm] = v0.x; Ls[lq * 4 + 1][lm] = v0.y;                        \
  Ls[lq * 4 + 2][lm] = v0.z; Ls[lq * 4 + 3][lm] = v0.w;                        \
  Ls[lq * 4 + 4][lm] = v1.x; Ls[lq * 4 + 5][lm] = v1.y;                        \
  Ls[lq * 4 + 6][lm] = v1.z; Ls[lq * 4 + 7][lm] = v1.w;

#define GEMM128_INNER(AsM, BsM)                                                \
  _Pragma("unroll") for (int kk = 0; kk < 16; ++kk) {                          \
    float4 a0 = *(const float4*)&AsM[kk][ty4];                                 \
    float4 a1 = *(const float4*)&AsM[kk][64 + ty4];                            \
    float4 b0 = *(const float4*)&BsM[kk][tx4];                                 \
    float4 b1 = *(const float4*)&BsM[kk][64 + tx4];                            \
    float av[8] = {a0.x, a0.y, a0.z, a0.w, a1.x, a1.y, a1.z, a1.w};            \
    float bv[8] = {b0.x, b0.y, b0.z, b0.w, b1.x, b1.y, b1.z, b1.w};            \
    _Pragma("unroll") for (int rr = 0; rr < 8; ++rr)                           \
      _Pragma("unroll") for (int cc2 = 0; cc2 < 8; ++cc2)                      \
        acc[rr][cc2] += av[rr] * bv[cc2];                                      \
  }

#define WRITE_TILE_NORM(Cc)                                                    \
  _Pragma("unroll") for (int rh = 0; rh < 2; ++rh)                             \
  _Pragma("unroll") for (int rr = 0; rr < 4; ++rr) {                           \
    int rI = rh * 4 + rr;                                                      \
    float* rowp = (Cc) + (size_t)(i0 + rh * 64 + ty4 + rr) * N + j0;           \
    *(float4*)(rowp + tx4) =                                                   \
        make_float4(acc[rI][0], acc[rI][1], acc[rI][2], acc[rI][3]);           \
    *(float4*)(rowp + 64 + tx4) =                                              \
        make_float4(acc[rI][4], acc[rI][5], acc[rI][6], acc[rI][7]);           \
  }

#define WRITE_TILE_MIRROR(Cc)                                                  \
  _Pragma("unroll") for (int ch = 0; ch < 2; ++ch)                             \
  _Pragma("unroll") for (int cc2 = 0; cc2 < 4; ++cc2) {                        \
    int cI = ch * 4 + cc2;                                                     \
    float* rowp = (Cc) + (size_t)(j0 + ch * 64 + tx4 + cc2) * N + i0;          \
    *(float4*)(rowp + ty4) =                                                   \
        make_float4(acc[0][cI], acc[1][cI], acc[2][cI], acc[3][cI]);           \
    *(float4*)(rowp + 64 + ty4) =                                              \
        make_float4(acc[4][cI], acc[5][cI], acc[6][cI], acc[7][cI]);           \
  }

// sym block map: bx 0,1,2 -> (0,0),(1,0),(1,1)
#define SYM_MAP                                                                \
  int bx = blockIdx.x;                                                         \
  int i0 = (bx >= 1) ? 128 : 0, j0 = (bx == 2) ? 128 : 0;

// 3) G = A*A^T per channel (lower tiles + mirror)
__global__ __launch_bounds__(256) void k_gram(const float* __restrict__ x,
                                              float* __restrict__ bufA, int base) {
  __shared__ float As[16][132], Bs[16][132];
  GEMM128_VARS; SYM_MAP;
  const float* A = x + (size_t)(base + blockIdx.z) * NN;
  float acc[8][8] = {};
  const float* Ap = A + (size_t)(i0 + lm) * N + lq * 4;
  const float* Bp = A + (size_t)(j0 + lm) * N + lq * 4;
  float4 va0 = *(const float4*)Ap, va1 = *(const float4*)(Ap + 4);
  float4 vb0 = *(const float4*)Bp, vb1 = *(const float4*)(Bp + 4);
  for (int kt = 0; kt < 16; ++kt) {
    __syncthreads();
    STORE_T128(As, va0, va1); STORE_T128(Bs, vb0, vb1);
    __syncthreads();
    if (kt < 15) {
      va0 = *(const float4*)(Ap + (kt + 1) * 16);
      va1 = *(const float4*)(Ap + (kt + 1) * 16 + 4);
      vb0 = *(const float4*)(Bp + (kt + 1) * 16);
      vb1 = *(const float4*)(Bp + (kt + 1) * 16 + 4);
    }
    GEMM128_INNER(As, Bs);
  }
  float* Cc = bufA + (size_t)blockIdx.z * NN;
  WRITE_TILE_NORM(Cc);
  if (bx == 1) { WRITE_TILE_MIRROR(Cc); }
}

// ---------------------------------------------------------------------------
// tridiag helpers: per-chunk matvec (f64 acc) and rank-2 update (f32, with
// fused column-(j+1) extraction for group 0). c0 is 64-aligned and
// wave-uniform; R0 is the wave's row-block base.
// ---------------------------------------------------------------------------
__device__ __forceinline__ double mv_chunk(const float* __restrict__ P, int c0,
                                           int j, int r, int R0, int triR,
                                           float ureg) {
  double pi0 = 0.0, pi1 = 0.0, pi2 = 0.0, pi3 = 0.0;
  if (c0 < N) {
    int lbeg = (c0 > j + 1) ? c0 : (j + 1);
    int lend = c0 + 64;
    if (lbeg < lend) {
      if (c0 + 64 <= R0) {
        // class A: all l < r -> row-contiguous triR+lmv (no select)
        int lmv = lbeg;
        for (; lmv + 3 < lend; lmv += 4) {
          float uv0 = rdlane(ureg, lmv - c0), uv1 = rdlane(ureg, lmv + 1 - c0);
          float uv2 = rdlane(ureg, lmv + 2 - c0), uv3 = rdlane(ureg, lmv + 3 - c0);
          float v0 = P[triR + lmv], v1 = P[triR + lmv + 1];
          float v2 = P[triR + lmv + 2], v3 = P[triR + lmv + 3];
          pi0 += (double)v0 * (double)uv0;
          pi1 += (double)v1 * (double)uv1;
          pi2 += (double)v2 * (double)uv2;
          pi3 += (double)v3 * (double)uv3;
        }
        for (; lmv < lend; ++lmv)
          pi0 += (double)P[triR + lmv] * (double)rdlane(ureg, lmv - c0);
      } else if (c0 >= R0 + 64) {
        // class C: all l > r -> s(l)+r, incremental s (no select)
        int lmv = lbeg;
        int s = (lmv * (lmv + 1)) >> 1;
        for (; lmv + 3 < lend; lmv += 4) {
          int s0 = s, s1 = s0 + lmv + 1, s2 = s1 + lmv + 2, s3 = s2 + lmv + 3;
          s = s3 + lmv + 4;
          float uv0 = rdlane(ureg, lmv - c0), uv1 = rdlane(ureg, lmv + 1 - c0);
          float uv2 = rdlane(ureg, lmv + 2 - c0), uv3 = rdlane(ureg, lmv + 3 - c0);
          pi0 += (double)P[s0 + r] * (double)uv0;
          pi1 += (double)P[s1 + r] * (double)uv1;
          pi2 += (double)P[s2 + r] * (double)uv2;
          pi3 += (double)P[s3 + r] * (double)uv3;
        }
        for (; lmv < lend; ++lmv) {
          pi0 += (double)P[s + r] * (double)rdlane(ureg, lmv - c0);
          s += lmv + 1;
        }
      } else {
        // class B: diagonal chunk, per-element select
        int lmv = lbeg;
        int s = (lmv * (lmv + 1)) >> 1;
        for (; lmv < lend; ++lmv) {
          float uv = rdlane(ureg, lmv - c0);
          float v = P[(lmv <= r) ? (triR + lmv) : (s + r)];
          pi0 += (double)v * (double)uv;
          s += lmv + 1;
        }
      }
    }
  }
  return (pi0 + pi1) + (pi2 + pi3);
}

// rank-2 update with fused extraction: colB != nullptr only for group 0
// (c0 == cbase <= j+1 < c0+64), whose first update element is l == j+1.
// That peeled value is bitwise the next step's column entry.
__device__ __forceinline__ void upd_chunk_x(float* __restrict__ P, int c0, int j,
                                            int r, int R0, int triR, float ureg,
                                            float wreg, float urf, float wrf,
                                            float* __restrict__ colB) {
  if (c0 >= N) return;
  int lbeg = (c0 > j + 1) ? c0 : (j + 1);
  int lend = c0 + 64;
  int lcap = (r | 63) + 1; // wave-uniform cap
  if (lend > lcap) lend = lcap;
  if (c0 + 64 <= R0) {
    // class A: full range, all l < r, contiguous
    int lmv = lbeg;
    if (colB) { // lbeg == j+1 for group 0; peel and extract
      float uv = rdlane(ureg, lmv - c0), wv = rdlane(wreg, lmv - c0);
      float v = fmaf(-wrf, uv, fmaf(-urf, wv, P[triR + lmv]));
      P[triR + lmv] = v;
      colB[r] = v;
      ++lmv;
    }
    for (; lmv + 1 < lend; lmv += 2) {
      float uv0 = rdlane(ureg, lmv - c0), wv0 = rdlane(wreg, lmv - c0);
      float uv1 = rdlane(ureg, lmv + 1 - c0), wv1 = rdlane(wreg, lmv + 1 - c0);
      P[triR + lmv] = fmaf(-wrf, uv0, fmaf(-urf, wv0, P[triR + lmv]));
      P[triR + lmv + 1] = fmaf(-wrf, uv1, fmaf(-urf, wv1, P[triR + lmv + 1]));
    }
    if (lmv < lend) {
      float uv0 = rdlane(ureg, lmv - c0), wv0 = rdlane(wreg, lmv - c0);
      P[triR + lmv] = fmaf(-wrf, uv0, fmaf(-urf, wv0, P[triR + lmv]));
    }
  } else if (c0 == R0) {
    // class B: diagonal chunk, per-lane cap
    int lmv = lbeg;
    if (colB) { // peel l == j+1 (l <= r guaranteed: r >= j+1)
      float uv = rdlane(ureg, lmv - c0), wv = rdlane(wreg, lmv - c0);
      float v = fmaf(-wrf, uv, fmaf(-urf, wv, P[triR + lmv]));
      P[triR + lmv] = v;
      colB[r] = v;
      ++lmv;
    }
    for (; lmv < lend; ++lmv) {
      float uv = rdlane(ureg, lmv - c0), wv = rdlane(wreg, lmv - c0);
      if (lmv <= r)
        P[triR + lmv] = fmaf(-wrf, uv, fmaf(-urf, wv, P[triR + lmv]));
    }
  }
  // c0 >= R0+64: lend <= lcap = R0+64 <= c0 < lbeg -> empty
}

// ---------------------------------------------------------------------------
// 4) Householder tridiag: 1024 threads = 4 column-groups x 256 rows, 4
//    barriers/step: {matvec + sigma partials -> B2 -> pi + kpart reduction
//    (EXACT R16 arithmetic) -> B3 -> K, w store -> B4 -> rank-2 update with
//    fused column-(j+1) extraction into double-buffered uf -> B5}. f64
//    matvec, f32 rank-2 update. (R19 verified: 3013 us, absmax 0.01171875.)
// ---------------------------------------------------------------------------
__global__ __launch_bounds__(1024) void k_tridiag(const float* __restrict__ Gall,
                                                  float* __restrict__ small, int base) {
  extern __shared__ double dls[];
  double* redd = dls;              // 16 (sigma partials)
  double* redd2 = dls + 16;        // 16 (K partials)
  double* pip = dls + 32;          // 1024
  float* P = (float*)(dls + 1056); // 32896 packed lower triangle
  float* uf0 = P + 32896;          // 256 (column ping)
  float* uf1 = uf0 + 256;          // 256 (column pong)
  float* wf = uf1 + 256;           // 256 (f32 w for the update)
  int tid = threadIdx.x, lane = tid & 63;
  int r = tid & 255, g = tid >> 8; // g in {0..3}
  int wid = tid >> 6;              // 0..15
  int R0 = (wid & 3) << 6;         // wave row-block base (r = R0 + lane)
  int c = base + blockIdx.x;
  const int* ip = (const int*)small;
  if (ip[OFF_MODE + c] != 2) return;
  const float* G = Gall + (size_t)blockIdx.x * NN;
  double* aq = (double*)(small + OFF_AQ) + (size_t)c * 256;
  double* bq = (double*)(small + OFF_BQ) + (size_t)c * 256;
  const int triR = (r * (r + 1)) >> 1;

  for (int i = g; i < N; i += 4)
    if (r <= i) P[((i * (i + 1)) >> 1) + r] = G[i * N + r];
  __syncthreads(); // init must complete before the column-0 read (R19 fix)
  // prologue: column 0 into uf0
  if (g == 0) uf0[r] = P[triR + 0];
  __syncthreads();

  float* ufA = uf0;
  float* ufB = uf1;
  for (int j = 0; j + 2 < N; ++j) {
    int jj = j + 1;
    float x_r = ufA[r];                // valid for r >= j+1
    double x0 = (double)ufA[jj];
    int cbase = jj & ~63;
    int c0 = cbase + 64 * g;           // wave-uniform
    float ureg = 0.f;
    if (c0 < N) ureg = ufA[c0 + lane]; // uniform cond: rdlane source
    bool act = (r >= jj);
    // merged phase: sigma partial + matvec p' = P*x (raw column)
    double sp = (g == 0 && r >= j + 2) ? (double)x_r * (double)x_r : 0.0;
    double myp = mv_chunk(P, c0, j, r, R0, triR, ureg);
    pip[tid] = act ? myp : 0.0;
    for (int off = 32; off; off >>= 1) sp += __shfl_down(sp, off, 64);
    if (lane == 0) redd[wid] = sp;
    __syncthreads(); // B2
    double sigma = (((redd[0] + redd[1]) + (redd[2] + redd[3])) +
                    ((redd[4] + redd[5]) + (redd[6] + redd[7]))) +
                   (((redd[8] + redd[9]) + (redd[10] + redd[11])) +
                    ((redd[12] + redd[13]) + (redd[14] + redd[15])));
    if (sigma <= 1e-40) { // column already tridiagonal (rare)
      if (tid == 0) bq[j] = x0;
      if (g == 0 && r >= j + 2) ufB[r] = P[triR + jj];
      __syncthreads();
      { float* t = ufA; ufA = ufB; ufB = t; }
      continue;
    }
    double nu = sqrt(x0 * x0 + sigma);
    double bsub = (x0 >= 0.0) ? -nu : nu;
    double beta = 1.0 / (nu * (nu + fabs(x0)));
    // patch u register at the column-(j+1) slot (self-register write)
    if (c0 <= jj && jj < c0 + 64 && lane == jj - c0)
      ureg = (float)(x0 - bsub);
    // phase: pi with fixup (all groups redundantly) + K partial (= R16)
    double pi = 0.0, u_r = 0.0, kp = 0.0;
    if (act) {
      double fix = -bsub * (double)P[triR + jj];
      pi = (pip[r] + pip[256 + r] + pip[512 + r] + pip[768 + r] + fix) * beta;
      u_r = (r == jj) ? (x0 - bsub) : (double)x_r;
      kp = u_r * pi * 0.25; // 0.25: four groups quadruple-count
    }
    for (int off = 32; off; off >>= 1) kp += __shfl_down(kp, off, 64);
    if (lane == 0) redd2[wid] = kp;
    __syncthreads(); // B3
    double K = ((((redd2[0] + redd2[1]) + (redd2[2] + redd2[3])) +
                 ((redd2[4] + redd2[5]) + (redd2[6] + redd2[7]))) +
                (((redd2[8] + redd2[9]) + (redd2[10] + redd2[11])) +
                 ((redd2[12] + redd2[13]) + (redd2[14] + redd2[15])))) *
               beta * 0.5;
    if (g == 0 && act) wf[r] = (float)(pi - K * u_r);
    if (tid == 0) bq[j] = bsub;
    __syncthreads(); // B4
    float wreg = 0.f;
    if (c0 < N) wreg = wf[c0 + lane]; // uniform cond: rdlane source
    // rank-2 update (f32) with fused column extraction (group 0)
    if (act) {
      float urf = (float)u_r;
      float wrf = wf[r];
      upd_chunk_x(P, c0, j, r, R0, triR, ureg, wreg, urf, wrf,
                  (g == 0) ? ufB : (float*)nullptr);
    }
    __syncthreads(); // B5
    { float* t = ufA; ufA = ufB; ufB = t; }
  }
  if (g == 0) aq[r] = (double)P[triR + r];
  if (tid == 0) bq[N - 2] = (double)P[(((N - 1) * N) >> 1) + N - 2];
}

// ---------------------------------------------------------------------------
// 5) fp64 Sturm 64-way multisection -> t, alpha, polar-express schedule,
//    and per-channel it_sw (first iteration with margin l >= 0.02, safe for
//    f16 MFMA: f16 spectral perturbation ~5e-4, 20-40x margin).
// ---------------------------------------------------------------------------
__device__ __forceinline__ int sturm_count_lds(const double* a, const double* b,
                                               double t) {
  double d = a[0] - t;
  int cnt = (d < 0.0);
  for (int i = 1; i < N; ++i) {
    double den = d;
    if (fabs(den) < 1e-20) den = (den < 0.0) ? -1e-20 : 1e-20;
    double bb = b[i - 1];
    d = (a[i] - t) - bb * bb / den;
    cnt += (d < 0.0);
  }
  return cnt; // #{eig < t}
}

__global__ __launch_bounds__(64) void k_bisect(float* __restrict__ small,
                                               int base, int cc) {
  int ci = blockIdx.x;
  if (ci >= cc) return;
  int c = base + ci, lane = threadIdx.x;
  int* ip = (int*)small;
  if (ip[OFF_MODE + c] != 2) {
    if (lane == 0) { ip[OFF_MC + c] = 0; ip[OFF_ITSW + c] = 0; }
    return;
  }
  int k = ip[OFF_K + c];
  const double* a = (const double*)(small + OFF_AQ) + (size_t)c * 256;
  const double* b = (const double*)(small + OFF_BQ) + (size_t)c * 256;
  __shared__ double sa[256], sb[256];
  for (int i = lane; i < N; i += 64) {
    sa[i] = a[i];
    if (i < N - 1) sb[i] = b[i];
  }
  __syncthreads();
  // Gershgorin bounds (wave-parallel)
  double lo = 1e300, hi = -1e300;
  for (int i = lane; i < N; i += 64) {
    double rr = (i > 0 ? fabs(sb[i - 1]) : 0.0) + (i < N - 1 ? fabs(sb[i]) : 0.0);
    lo = fmin(lo, sa[i] - rr);
    hi = fmax(hi, sa[i] + rr);
  }
  for (int off = 32; off; off >>= 1) {
    lo = fmin(lo, __shfl_xor(lo, off, 64));
    hi = fmax(hi, __shfl_xor(hi, off, 64));
  }
  double lamk = 0.0, lamk1 = 0.0;
  for (int which = 0; which < 2; ++which) {
    int j = (which == 0) ? (N - k + 1) : (N - k); // ascending index of mu_j
    double l0 = lo, h0 = hi;
    for (int pass = 0; pass < 10; ++pass) {
      double step = (h0 - l0) * (1.0 / 65.0);
      double t = l0 + step * (double)(lane + 1);
      int cnt = sturm_count_lds(sa, sb, t);
      unsigned long long mask = __ballot(cnt >= j);
      if (mask == 0ull) {
        l0 = l0 + step * 64.0; // mu_j above all probes
      } else {
        int bpos = __ffsll((long long)mask) - 1; // first probe with cnt>=j
        double nl = (bpos == 0) ? l0 : (l0 + step * (double)bpos);
        h0 = l0 + step * (double)(bpos + 1);
        l0 = nl;
      }
    }
    double v = 0.5 * (l0 + h0);
    if (which == 0) lamk = v; else lamk1 = v;
  }
  if (lane == 0) {
    double t = 0.5 * (lamk + lamk1);
    double gap = fmax(lamk - lamk1, 0.0);
    double alpha = 1.002 * fmax(hi - t, t - lo) + 1e-30;
    double g0 = fmax(gap / (2.0 * alpha), 2e-6);
    // polar-express schedule: equioscillation cubic per iteration
    float* cf = small + OFF_COEF + (size_t)c * (2 * NS_MAX);
    double l = fmin(g0, 0.99);
    int m = 0, isw = NS_MAX;
    while (m < NS_MAX - 2 && l < 0.9999) {
      if (isw == NS_MAX && l >= 0.02) isw = m;
      double aa = sqrt(27.0 / (4.0 * (1.0 + l + l * l)));
      double bb = (4.0 / 27.0) * aa * aa * aa;
      cf[2 * m] = (float)aa;
      cf[2 * m + 1] = (float)bb;
      double pl = aa * l - bb * l * l * l;
      double p1 = aa - bb;
      l = fmin(pl, p1);
      m++;
    }
    for (int e = 0; e < 2; ++e) {
      if (isw == NS_MAX && l >= 0.02) isw = m;
      cf[2 * m] = 1.5f; cf[2 * m + 1] = 0.5f; m++;
    }
    if (isw > m) isw = m;
    ip[OFF_MC + c] = m;
    ip[OFF_ITSW + c] = isw;
    ((double*)(small + OFF_T))[c] = t;
    ((double*)(small + OFF_ALPHA))[c] = alpha;
  }
}

// 6) X0 = (G - t*I)/alpha (in place on bufA, fp64 scale; R20: cc blocks x
//    256 threads grid-stride -- per-element arithmetic bitwise identical)
__global__ __launch_bounds__(256) void k_x0(const float* __restrict__ small,
                                            float* __restrict__ bufA, int base) {
  int ci = blockIdx.x, c = base + ci;
  const int* ip = (const int*)small;
  if (ip[OFF_MODE + c] != 2) return;
  double t = ((const double*)(small + OFF_T))[c];
  double inva = 1.0 / ((const double*)(small + OFF_ALPHA))[c];
  float* X = bufA + (size_t)ci * NN;
  for (int i = threadIdx.x; i < NN; i += 256) {
    int r = i >> 8, col = i & 255;
    double gg = (double)X[i];
    if (col == r) gg -= t;
    X[i] = (float)(gg * inva);
  }
}

// 7a) S = X*X (X symmetric; lower tiles + mirror) -- fp32 path (it < it_sw)
__global__ __launch_bounds__(256) void k_ns1(const float* __restrict__ src,
                                             float* __restrict__ Sb,
                                             const float* __restrict__ small,
                                             int base, int it) {
  const int* ip = (const int*)small;
  int c = base + blockIdx.z;
  if (ip[OFF_MODE + c] != 2 || it >= ip[OFF_ITSW + c]) return;
  __shared__ float As[16][132], Bs[16][132];
  GEMM128_VARS; SYM_MAP;
  const float* X = src + (size_t)blockIdx.z * NN;
  float acc[8][8] = {};
  const float* Ap = X + (size_t)(i0 + lm) * N + lq * 4;
  const float* Bp = X + (size_t)(j0 + lm) * N + lq * 4;
  float4 va0 = *(const float4*)Ap, va1 = *(const float4*)(Ap + 4);
  float4 vb0 = *(const float4*)Bp, vb1 = *(const float4*)(Bp + 4);
  for (int kt = 0; kt < 16; ++kt) {
    __syncthreads();
    STORE_T128(As, va0, va1); STORE_T128(Bs, vb0, vb1);
    __syncthreads();
    if (kt < 15) {
      va0 = *(const float4*)(Ap + (kt + 1) * 16);
      va1 = *(const float4*)(Ap + (kt + 1) * 16 + 4);
      vb0 = *(const float4*)(Bp + (kt + 1) * 16);
      vb1 = *(const float4*)(Bp + (kt + 1) * 16 + 4);
    }
    GEMM128_INNER(As, Bs);
  }
  float* Cc = Sb + (size_t)blockIdx.z * NN;
  WRITE_TILE_NORM(Cc);
  if (bx == 1) { WRITE_TILE_MIRROR(Cc); }
}

// 7b) Y = a*X - b*X*S (commuting symmetric -> Y symmetric; tiles + mirror)
__global__ __launch_bounds__(256) void k_ns2(const float* __restrict__ src,
                                             const float* __restrict__ Sb,
                                             float* __restrict__ dst,
                                             const float* __restrict__ small,
                                             int base, int it) {
  const int* ip = (const int*)small;
  int c = base + blockIdx.z;
  if (ip[OFF_MODE + c] != 2 || it >= ip[OFF_ITSW + c]) return;
  float ca = small[OFF_COEF + (size_t)c * (2 * NS_MAX) + 2 * it];
  float cb = small[OFF_COEF + (size_t)c * (2 * NS_MAX) + 2 * it + 1];
  __shared__ float As[16][132], Bs[16][132];
  GEMM128_VARS; SYM_MAP;
  const float* X = src + (size_t)blockIdx.z * NN;
  const float* S = Sb + (size_t)blockIdx.z * NN;
  float acc[8][8] = {};
  const float* Ap = X + (size_t)(i0 + lm) * N + lq * 4;
  const float* Bp = S + (size_t)(j0 + lm) * N + lq * 4;
  float4 va0 = *(const float4*)Ap, va1 = *(const float4*)(Ap + 4);
  float4 vb0 = *(const float4*)Bp, vb1 = *(const float4*)(Bp + 4);
  for (int kt = 0; kt < 16; ++kt) {
    __syncthreads();
    STORE_T128(As, va0, va1); STORE_T128(Bs, vb0, vb1);
    __syncthreads();
    if (kt < 15) {
      va0 = *(const float4*)(Ap + (kt + 1) * 16);
      va1 = *(const float4*)(Ap + (kt + 1) * 16 + 4);
      vb0 = *(const float4*)(Bp + (kt + 1) * 16);
      vb1 = *(const float4*)(Bp + (kt + 1) * 16 + 4);
    }
    GEMM128_INNER(As, Bs);
  }
  // acc <- ca*X - cb*acc (transform in place, then write norm + mirror)
#pragma unroll
  for (int rh = 0; rh < 2; ++rh)
#pragma unroll
    for (int rr = 0; rr < 4; ++rr) {
      int rI = rh * 4 + rr;
      const float* rowp = X + (size_t)(i0 + rh * 64 + ty4 + rr) * N + j0;
      float4 x0 = *(const float4*)(rowp + tx4);
      float4 x1 = *(const float4*)(rowp + 64 + tx4);
      acc[rI][0] = ca * x0.x - cb * acc[rI][0];
      acc[rI][1] = ca * x0.y - cb * acc[rI][1];
      acc[rI][2] = ca * x0.z - cb * acc[rI][2];
      acc[rI][3] = ca * x0.w - cb * acc[rI][3];
      acc[rI][4] = ca * x1.x - cb * acc[rI][4];
      acc[rI][5] = ca * x1.y - cb * acc[rI][5];
      acc[rI][6] = ca * x1.z - cb * acc[rI][6];
      acc[rI][7] = ca * x1.w - cb * acc[rI][7];
    }
  float* Y = dst + (size_t)blockIdx.z * NN;
  WRITE_TILE_NORM(Y);
  if (bx == 1) { WRITE_TILE_MIRROR(Y); }
}

// ---------------------------------------------------------------------------
// panel staging helpers: 128x256 f16 panel in LDS, 264-elem padded rows
// (16B pad per 512B row -> bank rotation). Source either f16 image or fp32
// (converted in-flight at it == it_sw).
// ---------------------------------------------------------------------------
__device__ __forceinline__ void stage_h(u16* pan, const u16* g16, int tid) {
#pragma unroll
  for (int i = 0; i < 16; ++i) {
    int g = tid * 16 + i * 4096;          // byte offset in 64KB panel
    int lo = g + ((g >> 9) << 4);
    *(uint4*)((char*)pan + lo) = *(const uint4*)((const char*)g16 + g);
  }
}
__device__ __forceinline__ void stage_f(u16* pan, const float* gF, int tid) {
#pragma unroll
  for (int i = 0; i < 16; ++i) {
    int e = tid * 8 + i * 2048;           // f16-element offset
    float4 v0 = *(const float4*)(gF + e);
    float4 v1 = *(const float4*)(gF + e + 4);
    h8 hv;
    hv[0] = (_Float16)v0.x; hv[1] = (_Float16)v0.y;
    hv[2] = (_Float16)v0.z; hv[3] = (_Float16)v0.w;
    hv[4] = (_Float16)v1.x; hv[5] = (_Float16)v1.y;
    hv[6] = (_Float16)v1.z; hv[7] = (_Float16)v1.w;
    int b = e * 2;
    int lo = b + ((b >> 9) << 4);
    *(h8*)((char*)pan + lo) = hv;
  }
}

// ---------------------------------------------------------------------------
// 7d) f16 MFMA NS step (it_sw <= it < mc). phase 0: S = X*X -> f16 alias of
//     the channel's Sf slot. phase 1: Y = ca*X - cb*X*S -> f16 alias of the
//     dst slot (final iteration writes full fp32 Y instead; race-free).
// ---------------------------------------------------------------------------
__global__ __launch_bounds__(256) void k_nsh(const float* __restrict__ srcF,
                                             float* __restrict__ Sf,
                                             float* __restrict__ dstF,
                                             const float* __restrict__ small,
                                             int base, int it, int phase) {
  const int* ip = (const int*)small;
  int ci = blockIdx.z, c = base + ci;
  if (ip[OFF_MODE + c] != 2) return;
  int isw = ip[OFF_ITSW + c], mc = ip[OFF_MC + c];
  if (it < isw || it >= mc) return;
  SYM_MAP;
  extern __shared__ char ldsraw[];
  u16* Apan = (u16*)ldsraw;
  u16* Bpan = Apan + F16_PANEL;
  int tid = threadIdx.x;
  bool cvtA = (it == isw);                 // stage X from fp32, convert
  bool sameP = (phase == 0) && (bx != 1);  // diag block of S=X*X: one panel
  const float* XF = srcF + (size_t)ci * NN;
  const u16* XH = (const u16*)XF;          // f16 alias (first half of slot)
  if (cvtA) stage_f(Apan, XF + (size_t)i0 * N, tid);
  else      stage_h(Apan, XH + (size_t)i0 * N, tid);
  if (!sameP) {
    if (phase == 0) {
      if (cvtA) stage_f(Bpan, XF + (size_t)j0 * N, tid);
      else      stage_h(Bpan, XH + (size_t)j0 * N, tid);
    } else {
      const u16* SH = (const u16*)(Sf + (size_t)ci * NN);
      stage_h(Bpan, SH + (size_t)j0 * N, tid);
    }
  }
  const u16* Bb = sameP ? Apan : Bpan;
  __syncthreads();

  int l = tid & 63, wid = tid >> 6;
  int wr = (wid >> 1) * 64, wc = (wid & 1) * 64; // wave's 64x64 sub-tile
  int rA = wr + (l & 15), rB = wc + (l & 15);
  int kB = (l >> 4) << 3;
  f32x4 zero = {0.f, 0.f, 0.f, 0.f};
  f32x4 acc[4][4];
#pragma unroll
  for (int mi = 0; mi < 4; ++mi)
#pragma unroll
    for (int ni = 0; ni < 4; ++ni) acc[mi][ni] = zero;

#pragma unroll
  for (int kc = 0; kc < 8; ++kc) {
    int kof = kc * 32 + kB; // f16 element offset within row
    h8 af[4], bf[4];
#pragma unroll
    for (int mi = 0; mi < 4; ++mi)
      af[mi] = *(const h8*)((const char*)Apan +
                            ((size_t)(rA + mi * 16) * 264 + kof) * 2);
#pragma unroll
    for (int ni = 0; ni < 4; ++ni)
      bf[ni] = *(const h8*)((const char*)Bb +
                            ((size_t)(rB + ni * 16) * 264 + kof) * 2);
#pragma unroll
    for (int mi = 0; mi < 4; ++mi)
#pragma unroll
      for (int ni = 0; ni < 4; ++ni)
        acc[mi][ni] = __builtin_amdgcn_mfma_f32_16x16x32_f16(
            af[mi], bf[ni], acc[mi][ni], 0, 0, 0);
  }

  float cav = 0.f, cbv = 0.f;
  bool last = false;
  if (phase) {
    cav = small[OFF_COEF + (size_t)c * (2 * NS_MAX) + 2 * it];
    cbv = small[OFF_COEF + (size_t)c * (2 * NS_MAX) + 2 * it + 1];
    last = (it == mc - 1);
  }
  float* oF = dstF + (size_t)ci * NN;
  u16* oH = phase ? (u16*)oF : (u16*)(Sf + (size_t)ci * NN);
  int lr4 = (l >> 4) << 2, lcn = l & 15;
  // C/D layout (m89-verified): col = lane&15, row = (lane>>4)*4 + reg
#pragma unroll
  for (int mi = 0; mi < 4; ++mi)
#pragma unroll
    for (int ni = 0; ni < 4; ++ni)
#pragma unroll
      for (int rg = 0; rg < 4; ++rg) {
        int gr = i0 + wr + mi * 16 + lr4 + rg;
        int gc = j0 + wc + ni * 16 + lcn;
        float v = acc[mi][ni][rg];
        if (phase) {
          float xv = h2f(Apan[(size_t)(gr - i0) * 264 + gc]);
          v = cav * xv - cbv * v;
        }
        if (!last) { // f16 store (skipped on final iter: aliases oF region)
          u16 hv = f2h(v);
          oH[(size_t)gr * N + gc] = hv;
          if (bx == 1) oH[(size_t)gc * N + gr] = hv;
        } else {
          oF[(size_t)gr * N + gc] = v;
          if (bx == 1) oF[(size_t)gc * N + gr] = v;
        }
      }
}

// 8) A_k = 0.5*(sign(X)*A + A) (modes: 0 -> zeros, 1 -> copy A)
__global__ __launch_bounds__(256) void k_proj(const float* __restrict__ bufA,
                                              const float* __restrict__ bufB,
                                              const float* __restrict__ x,
                                              float* __restrict__ bufC,
                                              const float* __restrict__ small,
                                              int base) {
  const int* ip = (const int*)small;
  int ci = blockIdx.z, c = base + ci;
  int mode = ip[OFF_MODE + c];
  GEMM128_VARS;
  int i0 = blockIdx.x * 128, j0 = blockIdx.y * 128;
  float* Cc = bufC + (size_t)ci * NN;
  const float* xc = x + (size_t)c * NN;
  if (mode != 2) {
#pragma unroll
    for (int rh = 0; rh < 2; ++rh)
#pragma unroll
      for (int rr = 0; rr < 4; ++rr) {
        size_t ro = (size_t)(i0 + rh * 64 + ty4 + rr) * N + j0;
        if (mode == 0) {
          *(float4*)(Cc + ro + tx4) = make_float4(0.f, 0.f, 0.f, 0.f);
          *(float4*)(Cc + ro + 64 + tx4) = make_float4(0.f, 0.f, 0.f, 0.f);
        } else {
          *(float4*)(Cc + ro + tx4) = *(const float4*)(xc + ro + tx4);
          *(float4*)(Cc + ro + 64 + tx4) = *(const float4*)(xc + ro + 64 + tx4);
        }
      }
    return;
  }
  int mc = ip[OFF_MC + c];
  const float* Xh = ((mc & 1) ? bufB : bufA) + (size_t)ci * NN;
  __shared__ float As[16][132], Bs[16][132];
  float acc[8][8] = {};
  const float* Ap = Xh + (size_t)(i0 + lm) * N + lq * 4;
  const float* Bp = xc + (size_t)lk * N + j0 + lc * 4;
  float4 va0 = *(const float4*)Ap, va1 = *(const float4*)(Ap + 4);
  float4 vb0 = *(const float4*)Bp, vb1 = *(const float4*)(Bp + 4);
  for (int kt = 0; kt < 16; ++kt) {
    __syncthreads();
    STORE_T128(As, va0, va1);
    *(float4*)&Bs[lk][lc * 4] = vb0;
    *(float4*)&Bs[lk][(lc + 1) * 4] = vb1;
    __syncthreads();
    if (kt < 15) {
      va0 = *(const float4*)(Ap + (kt + 1) * 16);
      va1 = *(const float4*)(Ap + (kt + 1) * 16 + 4);
      const float* Bp2 = xc + (size_t)((kt + 1) * 16 + lk) * N + j0 + lc * 4;
      vb0 = *(const float4*)Bp2;
      vb1 = *(const float4*)(Bp2 + 4);
    }
    GEMM128_INNER(As, Bs);
  }
#pragma unroll
  for (int rh = 0; rh < 2; ++rh)
#pragma unroll
    for (int rr = 0; rr < 4; ++rr) {
      int rI = rh * 4 + rr;
      const float* rowp = xc + (size_t)(i0 + rh * 64 + ty4 + rr) * N + j0;
      float4 x0 = *(const float4*)(rowp + tx4);
      float4 x1 = *(const float4*)(rowp + 64 + tx4);
      acc[rI][0] = 0.5f * (acc[rI][0] + x0.x);
      acc[rI][1] = 0.5f * (acc[rI][1] + x0.y);
      acc[rI][2] = 0.5f * (acc[rI][2] + x0.z);
      acc[rI][3] = 0.5f * (acc[rI][3] + x0.w);
      acc[rI][4] = 0.5f * (acc[rI][4] + x1.x);
      acc[rI][5] = 0.5f * (acc[rI][5] + x1.y);
      acc[rI][6] = 0.5f * (acc[rI][6] + x1.z);
      acc[rI][7] = 0.5f * (acc[rI][7] + x1.w);
    }
  WRITE_TILE_NORM(Cc);
}

// 9) accumulate sum & max over channels
__global__ void k_accum(const float* __restrict__ bufC, float* __restrict__ sum_hw,
                        float* __restrict__ max_hw, int cc, int first) {
  int p = blockIdx.x * 256 + threadIdx.x;
  float s = first ? 0.f : sum_hw[p];
  float m = first ? -1e30f : max_hw[p];
  for (int ci = 0; ci < cc; ++ci) {
    float v = bufC[(size_t)ci * NN + p];
    s += v;
    m = fmaxf(m, v);
  }
  sum_hw[p] = s;
  max_hw[p] = m;
}

// 10) 7x7 conv (pad 3) on [avg, max] -> clamp EPS -> sigmoid
__global__ void k_conv(const float* __restrict__ sum_hw, const float* __restrict__ max_hw,
                       const float* __restrict__ cw, float* __restrict__ out) {
  int p = blockIdx.x * 256 + threadIdx.x;
  int h = p >> 8, w = p & 255;
  float acc = 0.f;
  for (int dy = 0; dy < 7; ++dy) {
    int hy = h + dy - 3;
    if (hy < 0 || hy > 255) continue;
    for (int dx = 0; dx < 7; ++dx) {
      int wx = w + dx - 3;
      if (wx < 0 || wx > 255) continue;
      int q = hy * 256 + wx;
      acc += cw[dy * 7 + dx] * (sum_hw[q] * (1.f / 256.f)) +
             cw[49 + dy * 7 + dx] * max_hw[q];
    }
  }
  acc = fmaxf(acc, EPSF);
  out[p] = 1.f / (1.f + expf(-acc));
}

// ---------------------------------------------------------------------------
extern "C" void kernel_launch(void* const* d_in, const int* in_sizes, int n_in,
                              void* d_out, int out_size, void* d_ws, size_t ws_size,
                              hipStream_t stream) {
  const float* x = (const float*)d_in[0];
  const float* w1 = (const float*)d_in[1];
  const float* w2 = (const float*)d_in[2];
  const float* cw = (const float*)d_in[3];
  const int* kv = (const int*)d_in[4];
  float* out = (float*)d_out;
  float* small = (float*)d_ws;

  size_t small_bytes = (size_t)SMALL_FLOATS * 4;
  size_t avail = ws_size > small_bytes ? ws_size - small_bytes : 0;
  long chunk = (long)(avail / (3ull * NN * 4)); // 3 fp32 matrices per channel
  if (chunk > NCH) chunk = NCH;
  if (chunk < 1) chunk = 1;
  float* bufA = small + SMALL_FLOATS;
  float* bufB = bufA + (size_t)chunk * NN;
  float* bufC = bufB + (size_t)chunk * NN;

  const int tridiag_lds = 1056 * 8 + 32896 * 4 + 768 * 4; // 143104 B
  hipFuncSetAttribute((const void*)k_tridiag,
                      hipFuncAttributeMaxDynamicSharedMemorySize, tridiag_lds);
  hipFuncSetAttribute((const void*)k_nsh,
                      hipFuncAttributeMaxDynamicSharedMemorySize, NSH_LDS);

  k_chan_stats<<<NCH, 256, 0, stream>>>(x, small);
  k_attention<<<1, 256, 0, stream>>>(w1, w2, kv, small);

  const int IT32 = 12; // isw <= 10 provably (growth >= 2.49x/iter from 2e-6)

  for (int base = 0; base < NCH; base += (int)chunk) {
    int cc = (NCH - base < (int)chunk) ? (NCH - base) : (int)chunk;
    dim3 gsym(3, 1, cc);
    dim3 gproj(2, 2, cc);
    k_gram<<<gsym, 256, 0, stream>>>(x, bufA, base);
    k_tridiag<<<cc, 1024, tridiag_lds, stream>>>(bufA, small, base);
    k_bisect<<<cc, 64, 0, stream>>>(small, base, cc);
    k_x0<<<cc, 256, 0, stream>>>(small, bufA, base);
    for (int it = 0; it < NS_MAX; ++it) {
      const float* src = (it & 1) ? bufB : bufA;
      float* dst = (it & 1) ? bufA : bufB;
      if (it < IT32) {
        k_ns1<<<gsym, 256, 0, stream>>>(src, bufC, small, base, it);
        k_ns2<<<gsym, 256, 0, stream>>>(src, bufC, dst, small, base, it);
      }
      k_nsh<<<gsym, 256, NSH_LDS, stream>>>(src, bufC, dst, small, base, it, 0);
      k_nsh<<<gsym, 256, NSH_LDS, stream>>>(src, bufC, dst, small, base, it, 1);
    }
    k_proj<<<gproj, 256, 0, stream>>>(bufA, bufB, x, bufC, small, base);
    k_accum<<<256, 256, 0, stream>>>(bufC, small + OFF_SUM, small + OFF_MAXHW, cc,
                                     base == 0 ? 1 : 0);
  }
  k_conv<<<256, 256, 0, stream>>>(small + OFF_SUM, small + OFF_MAXHW, cw, out);
}